// Round 3
// baseline (17673.399 us; speedup 1.0000x reference)
//
#include <hip/hip_runtime.h>
#include <math.h>

// ---------------- problem constants ----------------
#define NB     64
#define SL     2048
#define NTOK   (NB*SL)
#define EMB_D  128
#define DMODEL 128
#define DIN    256
#define DST    16
#define NLAYER 4

// fixed small region (floats): w2 49152 | pl 131072 | pm 1024 | pd 8192 | h1 32768 | h2 32768
#define FIX_W2 ((size_t)0)
#define FIX_PL (FIX_W2 + 49152)
#define FIX_PM (FIX_PL + 131072)
#define FIX_PD (FIX_PM + 1024)
#define FIX_H1 (FIX_PD + 8192)
#define FIX_H2 (FIX_H1 + 32768)
#define FIX_END (FIX_H2 + 32768)          // 254,976 floats

__device__ __forceinline__ float siluf(float v){ return v / (1.f + expf(-v)); }

// ---------------- front-conv weight repack: W2[d][k*128+e] = conv_w[d][e][k] ----------------
__global__ void k_w2(const float* __restrict__ cw, float* __restrict__ w2){
  int g = blockIdx.x*256 + threadIdx.x;
  if (g >= 128*384) return;
  int d = g / 384, j = g % 384;
  int k = j >> 7, e = j & 127;
  w2[g] = cw[d*384 + e*3 + k];
}

// ---------------- embed + BN into padded chunk buffer: xp[b][t+1][e]; rows 0, L+1 zero -----
__global__ void k_embed(const int* __restrict__ tok, const float* __restrict__ emb,
                        const float* __restrict__ bnw, const float* __restrict__ bnb,
                        float* __restrict__ xp){
  int r = blockIdx.x;                 // CB*2050 rows
  int e = threadIdx.x;                // 128
  int b = r / 2050, tp = r % 2050;
  float v = 0.f;
  if (tp != 0 && tp != 2049){
    int t = tp - 1;
    int id = tok[(size_t)b*SL + t];
    float s = bnw[e] * rsqrtf(1.0f + 1e-5f);
    v = emb[(size_t)id*EMB_D + e] * s + bnb[e];
  }
  xp[(size_t)r*EMB_D + e] = v;
}

// ---------------- rmsnorm scale only: rs[tok] = rsqrt(mean(x^2)+eps) ----------------
__global__ __launch_bounds__(256) void k_rmsscale(const float* __restrict__ x,
                                                  float* __restrict__ rs){
  int wv = threadIdx.x>>6, lane = threadIdx.x&63;
  size_t tok = (size_t)blockIdx.x*4 + wv;
  float2 v = *(const float2*)(x + tok*128 + lane*2);
  float ss = v.x*v.x + v.y*v.y;
  #pragma unroll
  for (int m=1;m<64;m<<=1) ss += __shfl_xor(ss, m);
  float r = rsqrtf(ss*(1.f/128.f) + 1e-5f);
  if (lane == 0) rs[tok] = r;
}

// ---------------- tiled fp32 GEMM  out[M,N] = A[M,K] @ W[N,K]^T -------------------
// MODE 0: front conv (A = padded im2col rows, contiguous 384-float slices), epi relu(+bias)
// MODE 1: in_proj, A staged as x*rs[m]*nw[k]; epi split cols -> out(xi) / out2(z)
// MODE 2: out_proj, A = gated y; epi: out(x) += acc (residual)
template<int MODE, int K, int N>
__global__ __launch_bounds__(256) void k_gemm(
    const float* __restrict__ A, const float* __restrict__ W,
    const float* __restrict__ bias, const float* __restrict__ rsp,
    const float* __restrict__ nwp,
    float* __restrict__ out, float* __restrict__ out2){
  const int tid = threadIdx.x;
  const int m0 = blockIdx.y * 64;
  const int n0 = blockIdx.x * 128;
  __shared__ float As[32][68];
  __shared__ float Bs[32][132];
  float acc[4][8];
  #pragma unroll
  for (int i=0;i<4;i++)
    #pragma unroll
    for (int j=0;j<8;j++) acc[i][j]=0.f;
  const int row0 = (tid>>4)*4;
  const int col0 = (tid&15)*8;

  size_t abase;
  if constexpr(MODE==0){
    int bb = m0 >> 11, tloc = m0 & 2047;
    abase = ((size_t)bb*2050 + tloc) * 128;
  } else {
    abase = (size_t)m0 * K;
  }

  for (int k0 = 0; k0 < K; k0 += 32){
    #pragma unroll
    for (int i=0;i<2;i++){
      int idx = tid + i*256;
      int m = idx>>3, kq = idx&7;
      int kk = kq*4;
      float4 v;
      if constexpr(MODE==0){
        v = *(const float4*)(A + abase + (size_t)m*128 + k0 + kk);
      } else if constexpr(MODE==1){
        float4 x4 = *(const float4*)(A + abase + (size_t)m*K + k0 + kk);
        float4 w4 = *(const float4*)(nwp + k0 + kk);
        float s = rsp[m0 + m];
        v.x = x4.x*s*w4.x; v.y = x4.y*s*w4.y; v.z = x4.z*s*w4.z; v.w = x4.w*s*w4.w;
      } else {
        v = *(const float4*)(A + abase + (size_t)m*K + k0 + kk);
      }
      As[kk  ][m]=v.x; As[kk+1][m]=v.y; As[kk+2][m]=v.z; As[kk+3][m]=v.w;
    }
    #pragma unroll
    for (int i=0;i<4;i++){
      int idx = tid + i*256;
      int n = idx>>3, kq = idx&7;
      int kk = kq*4;
      float4 v = *(const float4*)(W + (size_t)(n0+n)*K + k0 + kk);
      Bs[kk  ][n]=v.x; Bs[kk+1][n]=v.y; Bs[kk+2][n]=v.z; Bs[kk+3][n]=v.w;
    }
    __syncthreads();
    #pragma unroll
    for (int k=0;k<32;k++){
      float4 a  = *(const float4*)&As[k][row0];
      float4 b0 = *(const float4*)&Bs[k][col0];
      float4 b1 = *(const float4*)&Bs[k][col0+4];
      float av[4] = {a.x,a.y,a.z,a.w};
      float bv[8] = {b0.x,b0.y,b0.z,b0.w,b1.x,b1.y,b1.z,b1.w};
      #pragma unroll
      for (int i=0;i<4;i++)
        #pragma unroll
        for (int j=0;j<8;j++) acc[i][j] = fmaf(av[i], bv[j], acc[i][j]);
    }
    __syncthreads();
  }

  #pragma unroll
  for (int i=0;i<4;i++){
    int m = m0 + row0 + i;
    #pragma unroll
    for (int j=0;j<8;j++){
      int n = n0 + col0 + j;
      float c = acc[i][j];
      if constexpr(MODE==0){
        out[(size_t)m*DMODEL + n] = fmaxf(c + bias[n], 0.f);
      } else if constexpr(MODE==1){
        if (n < DIN) out [(size_t)m*DIN + n]       = c;
        else         out2[(size_t)m*DIN + n - DIN] = c;
      } else {
        float* p = out + (size_t)m*DMODEL + n;
        *p = *p + c;
      }
    }
  }
}

// ---------------- depthwise causal conv (k=4) + silu ----------------
__global__ __launch_bounds__(256) void k_dwconv(const float* __restrict__ xi,
    const float* __restrict__ w, const float* __restrict__ cb, float* __restrict__ xc){
  int m = blockIdx.x;  int d = threadIdx.x;
  int t = m & 2047;
  const float* wd = w + d*4;
  float acc = cb[d];
  const float* base = xi + (size_t)m*DIN + d;
  if (t>=3) acc = fmaf(wd[0], base[-3*DIN], acc);
  if (t>=2) acc = fmaf(wd[1], base[-2*DIN], acc);
  if (t>=1) acc = fmaf(wd[2], base[-1*DIN], acc);
  acc = fmaf(wd[3], base[0], acc);
  xc[(size_t)m*DIN + d] = siluf(acc);
}

// ---------------- fused x_proj + dt_proj(+softplus) + B/C scatter ----------------
__global__ __launch_bounds__(256) void k_xdbl(const float* __restrict__ xc,
    const float* __restrict__ xpw, const float* __restrict__ dtw,
    const float* __restrict__ dtb, float* __restrict__ dta, float* __restrict__ bc){
  __shared__ float xcl[16][260];
  __shared__ float vl[16][44];
  const int tid = threadIdx.x;
  const int row0 = blockIdx.x * 16;
  #pragma unroll
  for (int i=0;i<4;i++){
    int q = tid + i*256;
    int tk = q>>6, kq = q&63;
    float4 v = *(const float4*)(xc + (size_t)(row0+tk)*DIN + kq*4);
    *(float4*)&xcl[tk][kq*4] = v;
  }
  __syncthreads();
  for (int j = tid; j < 640; j += 256){
    int tk = j / 40, c = j % 40;
    const float4* wp = (const float4*)(xpw + (size_t)c*DIN);
    float acc = 0.f;
    #pragma unroll
    for (int kk=0;kk<64;kk++){
      float4 xv = *(const float4*)&xcl[tk][kk*4];
      float4 wv = wp[kk];
      acc = fmaf(xv.x,wv.x, fmaf(xv.y,wv.y, fmaf(xv.z,wv.z, fmaf(xv.w,wv.w, acc))));
    }
    vl[tk][c] = acc;
  }
  __syncthreads();
  // bc[row*32 + 4j+{0,1,2,3}] = {B2j, C2j, B2j+1, C2j+1}
  for (int j = tid; j < 512; j += 256){
    int tk = j>>5, i = j&31;
    int s = i>>1;
    bc[(size_t)(row0+tk)*32 + i] = vl[tk][8 + ((i&1)<<4) + s];
  }
  #pragma unroll
  for (int it=0; it<16; it++){
    int j = tid + it*256;
    int tk = j>>8, d = j&255;
    float4 v0 = *(const float4*)&vl[tk][0];
    float4 v1 = *(const float4*)&vl[tk][4];
    const float4* wp = (const float4*)(dtw + (size_t)d*8);
    float4 w0 = wp[0], w1 = wp[1];
    float acc = dtb[d];
    acc = fmaf(v0.x,w0.x, fmaf(v0.y,w0.y, fmaf(v0.z,w0.z, fmaf(v0.w,w0.w, acc))));
    acc = fmaf(v1.x,w1.x, fmaf(v1.y,w1.y, fmaf(v1.z,w1.z, fmaf(v1.w,w1.w, acc))));
    float dt = (acc > 0.f) ? (acc + log1pf(expf(-acc))) : log1pf(expf(acc));
    dta[(size_t)(row0+tk)*DIN + d] = dt;
  }
}

// ---------------- selective scan, gate fused, in-place into xc ----------------
__global__ __launch_bounds__(256) void k_scan(const float* __restrict__ dta,
    float* xcio, const float* __restrict__ bc, const float* __restrict__ z,
    const float* __restrict__ alog, const float* __restrict__ Dpar){
  const int tid = threadIdx.x;
  const int j  = tid & 7;
  const int dl = tid >> 3;
  const int b  = blockIdx.x >> 3;          // chunk-local sequence
  const int d  = ((blockIdx.x & 7) << 5) + dl;
  const float LOG2E = 1.4426950408889634f;
  float a0 = -expf(alog[d*DST + 2*j    ]) * LOG2E;
  float a1 = -expf(alog[d*DST + 2*j + 1]) * LOG2E;
  float Dv = Dpar[d];
  float h0 = 0.f, h1 = 0.f;
  size_t rowbase = (size_t)b * SL;
  const float* pdt = dta + rowbase*DIN + d;
  float*       pux = xcio + rowbase*DIN + d;
  const float* pbc = bc  + rowbase*32  + j*4;
  const float* pz  = z   + rowbase*DIN + d;
  #pragma unroll 4
  for (int t=0;t<SL;t++){
    float dt = *pdt;
    float u  = *pux;
    float4 q = *(const float4*)pbc;   // {B0,C0,B1,C1}
    float du = dt*u;
    h0 = fmaf(exp2f(dt*a0), h0, du*q.x);
    h1 = fmaf(exp2f(dt*a1), h1, du*q.z);
    float p = fmaf(h0, q.y, h1*q.w);
    p += __shfl_xor(p, 1);
    p += __shfl_xor(p, 2);
    p += __shfl_xor(p, 4);
    if (j == 0){
      float zv = *pz;
      *pux = (p + u*Dv) * (zv / (1.f + expf(-zv)));
    }
    pdt += DIN; pux += DIN; pbc += 32; pz += DIN;
  }
}

// ---------------- masked mean pool over a chunk (writes global partials) ----------------
__global__ __launch_bounds__(256) void k_pool1(const float* __restrict__ x,
    const float* __restrict__ mask, float* __restrict__ part, float* __restrict__ pmask){
  int b = blockIdx.y, seg = blockIdx.x;       // chunk-local b
  int d = threadIdx.x & 127, half = threadIdx.x >> 7;
  int t0 = seg*128 + half*64;
  float acc = 0.f, macc = 0.f;
  for (int i=0;i<64;i++){
    int t = t0 + i;
    float mv = mask[(size_t)b*SL + t];
    acc = fmaf(x[((size_t)b*SL + t)*DMODEL + d], mv, acc);
    macc += mv;
  }
  __shared__ float sm[256];
  __shared__ float smm[2];
  sm[threadIdx.x] = acc;
  if (d == 0) smm[half] = macc;
  __syncthreads();
  if (half == 0){
    part[((size_t)b*16 + seg)*128 + d] = sm[d] + sm[128+d];
    if (d == 0) pmask[b*16 + seg] = smm[0] + smm[1];
  }
}

__global__ void k_pool2(const float* __restrict__ part, const float* __restrict__ pmask,
                        float* __restrict__ pooled){
  int b = blockIdx.x, d = threadIdx.x;
  float acc = 0.f, ms = 0.f;
  for (int s=0;s<16;s++){ acc += part[((size_t)b*16+s)*128 + d]; ms += pmask[b*16+s]; }
  pooled[(size_t)b*128 + d] = acc / fmaxf(ms, 1e-9f);
}

// ---------------- tiny MLP ----------------
__global__ void k_mlp_a(const float* __restrict__ in, const float* __restrict__ w,
                        const float* __restrict__ bias, float* __restrict__ out, int K){
  int b = blockIdx.y;
  int n = blockIdx.x*128 + threadIdx.x;
  const float4* pw = (const float4*)(w + (size_t)n*K);
  const float4* pi = (const float4*)(in + (size_t)b*K);
  float acc = 0.f;
  for (int k=0;k<K/4;k++){
    float4 a = pi[k], ww = pw[k];
    acc = fmaf(a.x,ww.x, fmaf(a.y,ww.y, fmaf(a.z,ww.z, fmaf(a.w,ww.w, acc))));
  }
  out[(size_t)b*512 + n] = fmaxf(acc + bias[n], 0.f);
}

__global__ void k_mlp3(const float* __restrict__ h, const float* __restrict__ w,
                       const float* __restrict__ bias, float* __restrict__ out){
  int b = blockIdx.x;
  int n = threadIdx.x >> 6, lane = threadIdx.x & 63;
  if (n >= 3) return;
  float acc = 0.f;
  for (int k=lane; k<512; k+=64) acc = fmaf(h[(size_t)b*512+k], w[(size_t)n*512+k], acc);
  #pragma unroll
  for (int m=1;m<64;m<<=1) acc += __shfl_xor(acc, m);
  if (lane == 0) out[(size_t)b*3 + n] = acc + bias[n];
}

// ---------------- launch ----------------
extern "C" void kernel_launch(void* const* d_in, const int* in_sizes, int n_in,
                              void* d_out, int out_size, void* d_ws, size_t ws_size,
                              hipStream_t stream){
  const int*   tokens = (const int*)  d_in[0];
  const float* mask   = (const float*)d_in[1];
  const float* emb    = (const float*)d_in[2];
  const float* bn_w   = (const float*)d_in[3];
  const float* bn_b   = (const float*)d_in[4];
  const float* conv_w = (const float*)d_in[5];
  const float* conv_b = (const float*)d_in[6];
  const float* in_w   = (const float*)d_in[7];
  const float* c1_w   = (const float*)d_in[8];
  const float* c1_b   = (const float*)d_in[9];
  const float* xp_w   = (const float*)d_in[10];
  const float* dtp_w  = (const float*)d_in[11];
  const float* dtp_b  = (const float*)d_in[12];
  const float* A_log  = (const float*)d_in[13];
  const float* D_par  = (const float*)d_in[14];
  const float* out_w  = (const float*)d_in[15];
  const float* nrm_w  = (const float*)d_in[16];
  const float* l1w = (const float*)d_in[17]; const float* l1b = (const float*)d_in[18];
  const float* l2w = (const float*)d_in[19]; const float* l2b = (const float*)d_in[20];
  const float* l3w = (const float*)d_in[21]; const float* l3b = (const float*)d_in[22];
  float* dout = (float*)d_out;

  // ---- adaptive chunk size from ws_size (constant across calls -> identical work) ----
  // per-token floats: x 128 + rs 1 + xi 256 + z 256 + xc 256 + bc 32 = 929
  int CB = 64;
  while (CB > 1 && ((size_t)CB*SL*929 + FIX_END)*4 > ws_size) CB >>= 1;
  if (((size_t)CB*SL*929 + FIX_END)*4 > ws_size) return;   // diagnostic: clean absmax fail
  const size_t CTOK = (size_t)CB*SL;

  float* ws  = (float*)d_ws;
  float* w2  = ws + FIX_W2;
  float* pl  = ws + FIX_PL;
  float* pm  = ws + FIX_PM;
  float* pd  = ws + FIX_PD;
  float* h1  = ws + FIX_H1;
  float* h2  = ws + FIX_H2;
  float* xcb = ws + FIX_END;                 // x chunk:  CTOK*128
  float* rs  = xcb + CTOK*128;               // CTOK
  float* xi  = rs  + CTOK;                   // CTOK*256 (embed pad / x-branch / dta)
  float* z   = xi  + CTOK*256;               // CTOK*256
  float* xc  = z   + CTOK*256;               // CTOK*256
  float* bcb = xc  + CTOK*256;               // CTOK*32

  k_w2<<<192, 256, 0, stream>>>(conv_w, w2);

  const int nchunks = NB / CB;
  for (int c = 0; c < nchunks; c++){
    const int* tok_c = tokens + (size_t)c*CTOK;

    k_embed<<<CB*2050, 128, 0, stream>>>(tok_c, emb, bn_w, bn_b, xi);
    k_gemm<0,384,128><<<dim3(1, CTOK/64), 256, 0, stream>>>(
        xi, w2, conv_b, nullptr, nullptr, xcb, nullptr);

    for (int layer = 0; layer < NLAYER; layer++){
      const float* lin  = in_w  + (size_t)layer*512*128;
      const float* lcw  = c1_w  + (size_t)layer*DIN*4;
      const float* lcb  = c1_b  + (size_t)layer*DIN;
      const float* lxp  = xp_w  + (size_t)layer*40*DIN;
      const float* ldw  = dtp_w + (size_t)layer*DIN*8;
      const float* ldb  = dtp_b + (size_t)layer*DIN;
      const float* lal  = A_log + (size_t)layer*DIN*DST;
      const float* lD   = D_par + (size_t)layer*DIN;
      const float* low  = out_w + (size_t)layer*128*256;
      const float* lnw  = nrm_w + (size_t)layer*128;

      k_rmsscale<<<CTOK/4, 256, 0, stream>>>(xcb, rs);
      k_gemm<1,128,512><<<dim3(4, CTOK/64), 256, 0, stream>>>(
          xcb, lin, nullptr, rs, lnw, xi, z);
      k_dwconv<<<(int)CTOK, 256, 0, stream>>>(xi, lcw, lcb, xc);
      k_xdbl<<<(int)(CTOK/16), 256, 0, stream>>>(xc, lxp, ldw, ldb, xi /*dta*/, bcb);
      k_scan<<<CB*8, 256, 0, stream>>>(xi /*dta*/, xc, bcb, z, lal, lD);
      k_gemm<2,256,128><<<dim3(1, CTOK/64), 256, 0, stream>>>(
          xc, low, nullptr, nullptr, nullptr, xcb, nullptr);
    }

    k_pool1<<<dim3(16, CB), 256, 0, stream>>>(
        xcb, mask + (size_t)c*CTOK, pl + (size_t)c*CB*16*128, pm + (size_t)c*CB*16);
  }

  k_pool2<<<NB, 128, 0, stream>>>(pl, pm, pd);
  k_mlp_a<<<dim3(4, NB), 128, 0, stream>>>(pd, l1w, l1b, h1, 128);
  k_mlp_a<<<dim3(4, NB), 128, 0, stream>>>(h1, l2w, l2b, h2, 512);
  k_mlp3<<<NB, 256, 0, stream>>>(h2, l3w, l3b, dout);
}

// Round 4
// 9511.318 us; speedup vs baseline: 1.8581x; 1.8581x over previous
//
#include <hip/hip_runtime.h>
#include <math.h>

// ---------------- problem constants ----------------
#define NB     64
#define SL     2048
#define NTOK   (NB*SL)
#define EMB_D  128
#define DMODEL 128
#define DIN    256
#define DST    16
#define NLAYER 4

// fixed small region (floats)
#define FIX_W2 ((size_t)0)
#define FIX_PL (FIX_W2 + 49152)
#define FIX_PM (FIX_PL + 131072)
#define FIX_PD (FIX_PM + 1024)
#define FIX_H1 (FIX_PD + 8192)
#define FIX_H2 (FIX_H1 + 32768)
#define FIX_END (FIX_H2 + 32768)          // 254,976 floats

__device__ __forceinline__ float siluf(float v){ return v / (1.f + expf(-v)); }

// ---------------- front-conv weight repack: W2[d][k*128+e] = conv_w[d][e][k] ----------------
__global__ void k_w2(const float* __restrict__ cw, float* __restrict__ w2){
  int g = blockIdx.x*256 + threadIdx.x;
  if (g >= 128*384) return;
  int d = g / 384, j = g % 384;
  int k = j >> 7, e = j & 127;
  w2[g] = cw[d*384 + e*3 + k];
}

// ---------------- embed + BN into padded chunk buffer ----------------
__global__ void k_embed(const int* __restrict__ tok, const float* __restrict__ emb,
                        const float* __restrict__ bnw, const float* __restrict__ bnb,
                        float* __restrict__ xp){
  int r = blockIdx.x;                 // CB*2050 rows
  int e = threadIdx.x;                // 128
  int b = r / 2050, tp = r % 2050;
  float v = 0.f;
  if (tp != 0 && tp != 2049){
    int t = tp - 1;
    int id = tok[(size_t)b*SL + t];
    float s = bnw[e] * rsqrtf(1.0f + 1e-5f);
    v = emb[(size_t)id*EMB_D + e] * s + bnb[e];
  }
  xp[(size_t)r*EMB_D + e] = v;
}

// ---------------- rmsnorm scale only ----------------
__global__ __launch_bounds__(256) void k_rmsscale(const float* __restrict__ x,
                                                  float* __restrict__ rs){
  int wv = threadIdx.x>>6, lane = threadIdx.x&63;
  size_t tok = (size_t)blockIdx.x*4 + wv;
  float2 v = *(const float2*)(x + tok*128 + lane*2);
  float ss = v.x*v.x + v.y*v.y;
  #pragma unroll
  for (int m=1;m<64;m<<=1) ss += __shfl_xor(ss, m);
  float r = rsqrtf(ss*(1.f/128.f) + 1e-5f);
  if (lane == 0) rs[tok] = r;
}

// ---------------- tiled fp32 GEMM  out[M,N] = A[M,K] @ W[N,K]^T -------------------
template<int MODE, int K, int N>
__global__ __launch_bounds__(256) void k_gemm(
    const float* __restrict__ A, const float* __restrict__ W,
    const float* __restrict__ bias, const float* __restrict__ rsp,
    const float* __restrict__ nwp,
    float* __restrict__ out, float* __restrict__ out2){
  const int tid = threadIdx.x;
  const int m0 = blockIdx.y * 64;
  const int n0 = blockIdx.x * 128;
  __shared__ float As[32][68];
  __shared__ float Bs[32][132];
  float acc[4][8];
  #pragma unroll
  for (int i=0;i<4;i++)
    #pragma unroll
    for (int j=0;j<8;j++) acc[i][j]=0.f;
  const int row0 = (tid>>4)*4;
  const int col0 = (tid&15)*8;

  size_t abase;
  if constexpr(MODE==0){
    int bb = m0 >> 11, tloc = m0 & 2047;
    abase = ((size_t)bb*2050 + tloc) * 128;
  } else {
    abase = (size_t)m0 * K;
  }

  for (int k0 = 0; k0 < K; k0 += 32){
    #pragma unroll
    for (int i=0;i<2;i++){
      int idx = tid + i*256;
      int m = idx>>3, kq = idx&7;
      int kk = kq*4;
      float4 v;
      if constexpr(MODE==0){
        v = *(const float4*)(A + abase + (size_t)m*128 + k0 + kk);
      } else if constexpr(MODE==1){
        float4 x4 = *(const float4*)(A + abase + (size_t)m*K + k0 + kk);
        float4 w4 = *(const float4*)(nwp + k0 + kk);
        float s = rsp[m0 + m];
        v.x = x4.x*s*w4.x; v.y = x4.y*s*w4.y; v.z = x4.z*s*w4.z; v.w = x4.w*s*w4.w;
      } else {
        v = *(const float4*)(A + abase + (size_t)m*K + k0 + kk);
      }
      As[kk  ][m]=v.x; As[kk+1][m]=v.y; As[kk+2][m]=v.z; As[kk+3][m]=v.w;
    }
    #pragma unroll
    for (int i=0;i<4;i++){
      int idx = tid + i*256;
      int n = idx>>3, kq = idx&7;
      int kk = kq*4;
      float4 v = *(const float4*)(W + (size_t)(n0+n)*K + k0 + kk);
      Bs[kk  ][n]=v.x; Bs[kk+1][n]=v.y; Bs[kk+2][n]=v.z; Bs[kk+3][n]=v.w;
    }
    __syncthreads();
    #pragma unroll
    for (int k=0;k<32;k++){
      float4 a  = *(const float4*)&As[k][row0];
      float4 b0 = *(const float4*)&Bs[k][col0];
      float4 b1 = *(const float4*)&Bs[k][col0+4];
      float av[4] = {a.x,a.y,a.z,a.w};
      float bv[8] = {b0.x,b0.y,b0.z,b0.w,b1.x,b1.y,b1.z,b1.w};
      #pragma unroll
      for (int i=0;i<4;i++)
        #pragma unroll
        for (int j=0;j<8;j++) acc[i][j] = fmaf(av[i], bv[j], acc[i][j]);
    }
    __syncthreads();
  }

  #pragma unroll
  for (int i=0;i<4;i++){
    int m = m0 + row0 + i;
    #pragma unroll
    for (int j=0;j<8;j++){
      int n = n0 + col0 + j;
      float c = acc[i][j];
      if constexpr(MODE==0){
        out[(size_t)m*DMODEL + n] = fmaxf(c + bias[n], 0.f);
      } else if constexpr(MODE==1){
        if (n < DIN) out [(size_t)m*DIN + n]       = c;
        else         out2[(size_t)m*DIN + n - DIN] = c;
      } else {
        float* p = out + (size_t)m*DMODEL + n;
        *p = *p + c;
      }
    }
  }
}

// ---------------- depthwise causal conv (k=4) + silu ----------------
__global__ __launch_bounds__(256) void k_dwconv(const float* __restrict__ xi,
    const float* __restrict__ w, const float* __restrict__ cb, float* __restrict__ xc){
  int m = blockIdx.x;  int d = threadIdx.x;
  int t = m & 2047;
  const float* wd = w + d*4;
  float acc = cb[d];
  const float* base = xi + (size_t)m*DIN + d;
  if (t>=3) acc = fmaf(wd[0], base[-3*DIN], acc);
  if (t>=2) acc = fmaf(wd[1], base[-2*DIN], acc);
  if (t>=1) acc = fmaf(wd[2], base[-1*DIN], acc);
  acc = fmaf(wd[3], base[0], acc);
  xc[(size_t)m*DIN + d] = siluf(acc);
}

// ---------------- fused x_proj + dt_proj(+softplus) + B/C scatter ----------------
__global__ __launch_bounds__(256) void k_xdbl(const float* __restrict__ xc,
    const float* __restrict__ xpw, const float* __restrict__ dtw,
    const float* __restrict__ dtb, float* __restrict__ dta, float* __restrict__ bc){
  __shared__ float xcl[16][260];
  __shared__ float vl[16][44];
  const int tid = threadIdx.x;
  const int row0 = blockIdx.x * 16;
  #pragma unroll
  for (int i=0;i<4;i++){
    int q = tid + i*256;
    int tk = q>>6, kq = q&63;
    float4 v = *(const float4*)(xc + (size_t)(row0+tk)*DIN + kq*4);
    *(float4*)&xcl[tk][kq*4] = v;
  }
  __syncthreads();
  for (int j = tid; j < 640; j += 256){
    int tk = j / 40, c = j % 40;
    const float4* wp = (const float4*)(xpw + (size_t)c*DIN);
    float acc = 0.f;
    #pragma unroll
    for (int kk=0;kk<64;kk++){
      float4 xv = *(const float4*)&xcl[tk][kk*4];
      float4 wv = wp[kk];
      acc = fmaf(xv.x,wv.x, fmaf(xv.y,wv.y, fmaf(xv.z,wv.z, fmaf(xv.w,wv.w, acc))));
    }
    vl[tk][c] = acc;
  }
  __syncthreads();
  // bc[row*32 + 4j+{0,1,2,3}] = {B2j, C2j, B2j+1, C2j+1}
  for (int j = tid; j < 512; j += 256){
    int tk = j>>5, i = j&31;
    int s = i>>1;
    bc[(size_t)(row0+tk)*32 + i] = vl[tk][8 + ((i&1)<<4) + s];
  }
  #pragma unroll
  for (int it=0; it<16; it++){
    int j = tid + it*256;
    int tk = j>>8, d = j&255;
    float4 v0 = *(const float4*)&vl[tk][0];
    float4 v1 = *(const float4*)&vl[tk][4];
    const float4* wp = (const float4*)(dtw + (size_t)d*8);
    float4 w0 = wp[0], w1 = wp[1];
    float acc = dtb[d];
    acc = fmaf(v0.x,w0.x, fmaf(v0.y,w0.y, fmaf(v0.z,w0.z, fmaf(v0.w,w0.w, acc))));
    acc = fmaf(v1.x,w1.x, fmaf(v1.y,w1.y, fmaf(v1.z,w1.z, fmaf(v1.w,w1.w, acc))));
    float dt = (acc > 0.f) ? (acc + log1pf(expf(-acc))) : log1pf(expf(acc));
    dta[(size_t)(row0+tk)*DIN + d] = dt;
  }
}

// ---------------- selective scan, LDS tile-staged, gate fused, in-place into xc ----------
// block = (seq b, 32 channels d0..d0+31); 256 thr: j=tid&7 (state pair), dl=tid>>3 (channel)
// tiles of T=64 steps: bulk stage dt/u (interleaved), bc, z -> LDS; serial scan from LDS;
// gated store (y+u*D)*silu(z) back to xc.
#define SCT 64
__global__ __launch_bounds__(256) void k_scan(const float* __restrict__ dta,
    float* xcio, const float* __restrict__ bc, const float* __restrict__ z,
    const float* __restrict__ alog, const float* __restrict__ Dpar){
  __shared__ float sdu[SCT][68];   // [t][2*dl]={dt}, [t][2*dl+1]={u}
  __shared__ float sbc[SCT][36];   // [t][4j..4j+3]={B2j,C2j,B2j+1,C2j+1}
  __shared__ float szs[SCT][36];
  __shared__ float sys[SCT][36];
  const int tid = threadIdx.x;
  const int j  = tid & 7;
  const int dl = tid >> 3;
  const int b  = blockIdx.x >> 3;
  const int d0 = (blockIdx.x & 7) << 5;
  const int d  = d0 + dl;
  const float LOG2E = 1.4426950408889634f;
  const float a0 = -expf(alog[d*DST + 2*j    ]) * LOG2E;
  const float a1 = -expf(alog[d*DST + 2*j + 1]) * LOG2E;
  // staging-lane coords
  const int sr = tid >> 3;          // 0..31 (row within half-tile)
  const int sc = (tid & 7) * 4;     // 0..28 (col group)
  const float4 D4 = *(const float4*)(Dpar + d0 + sc);
  float h0 = 0.f, h1 = 0.f;
  const size_t rowbase = (size_t)b * SL;

  for (int tile = 0; tile < SL/SCT; tile++){
    const int row0 = tile * SCT;
    __syncthreads();   // protect LDS from previous tile's store phase
    // ---- stage dt/u interleaved + z ----
    #pragma unroll
    for (int p=0;p<2;p++){
      int r = p*32 + sr;
      size_t go = (rowbase + row0 + r)*DIN + d0 + sc;
      float4 dv = *(const float4*)(dta  + go);
      float4 uv = *(const float4*)(xcio + go);
      float4 zv = *(const float4*)(z    + go);
      sdu[r][2*sc  ]=dv.x; sdu[r][2*sc+1]=uv.x;
      sdu[r][2*sc+2]=dv.y; sdu[r][2*sc+3]=uv.y;
      sdu[r][2*sc+4]=dv.z; sdu[r][2*sc+5]=uv.z;
      sdu[r][2*sc+6]=dv.w; sdu[r][2*sc+7]=uv.w;
      *(float4*)&szs[r][sc] = zv;
    }
    // ---- stage bc (tile slice is contiguous) ----
    #pragma unroll
    for (int p=0;p<2;p++){
      int idx = p*256 + tid;               // 512 float4s
      float4 bv = *(const float4*)(bc + (rowbase + row0)*32 + (size_t)idx*4);
      *(float4*)&sbc[idx>>3][(idx&7)*4] = bv;
    }
    __syncthreads();
    // ---- serial scan from LDS ----
    #pragma unroll 8
    for (int t=0;t<SCT;t++){
      float2 duv = *(const float2*)&sdu[t][2*dl];
      float4 q   = *(const float4*)&sbc[t][4*j];
      float du = duv.x * duv.y;
      h0 = fmaf(exp2f(duv.x*a0), h0, du*q.x);
      h1 = fmaf(exp2f(duv.x*a1), h1, du*q.z);
      float p = fmaf(h0, q.y, h1*q.w);
      p += __shfl_xor(p, 1);
      p += __shfl_xor(p, 2);
      p += __shfl_xor(p, 4);
      if (j == 0) sys[t][dl] = p;
    }
    __syncthreads();
    // ---- gated store phase ----
    #pragma unroll
    for (int p=0;p<2;p++){
      int r = p*32 + sr;
      float4 yv = *(const float4*)&sys[r][sc];
      float4 zv = *(const float4*)&szs[r][sc];
      float u0 = sdu[r][2*sc+1], u1 = sdu[r][2*sc+3];
      float u2 = sdu[r][2*sc+5], u3 = sdu[r][2*sc+7];
      float4 o;
      o.x = (yv.x + u0*D4.x) * siluf(zv.x);
      o.y = (yv.y + u1*D4.y) * siluf(zv.y);
      o.z = (yv.z + u2*D4.z) * siluf(zv.z);
      o.w = (yv.w + u3*D4.w) * siluf(zv.w);
      *(float4*)(xcio + (rowbase + row0 + r)*DIN + d0 + sc) = o;
    }
  }
}

// ---------------- masked mean pool over a chunk ----------------
__global__ __launch_bounds__(256) void k_pool1(const float* __restrict__ x,
    const float* __restrict__ mask, float* __restrict__ part, float* __restrict__ pmask){
  int b = blockIdx.y, seg = blockIdx.x;
  int d = threadIdx.x & 127, half = threadIdx.x >> 7;
  int t0 = seg*128 + half*64;
  float acc = 0.f, macc = 0.f;
  for (int i=0;i<64;i++){
    int t = t0 + i;
    float mv = mask[(size_t)b*SL + t];
    acc = fmaf(x[((size_t)b*SL + t)*DMODEL + d], mv, acc);
    macc += mv;
  }
  __shared__ float sm[256];
  __shared__ float smm[2];
  sm[threadIdx.x] = acc;
  if (d == 0) smm[half] = macc;
  __syncthreads();
  if (half == 0){
    part[((size_t)b*16 + seg)*128 + d] = sm[d] + sm[128+d];
    if (d == 0) pmask[b*16 + seg] = smm[0] + smm[1];
  }
}

__global__ void k_pool2(const float* __restrict__ part, const float* __restrict__ pmask,
                        float* __restrict__ pooled){
  int b = blockIdx.x, d = threadIdx.x;
  float acc = 0.f, ms = 0.f;
  for (int s=0;s<16;s++){ acc += part[((size_t)b*16+s)*128 + d]; ms += pmask[b*16+s]; }
  pooled[(size_t)b*128 + d] = acc / fmaxf(ms, 1e-9f);
}

// ---------------- tiny MLP ----------------
__global__ void k_mlp_a(const float* __restrict__ in, const float* __restrict__ w,
                        const float* __restrict__ bias, float* __restrict__ out, int K){
  int b = blockIdx.y;
  int n = blockIdx.x*128 + threadIdx.x;
  const float4* pw = (const float4*)(w + (size_t)n*K);
  const float4* pi = (const float4*)(in + (size_t)b*K);
  float acc = 0.f;
  for (int k=0;k<K/4;k++){
    float4 a = pi[k], ww = pw[k];
    acc = fmaf(a.x,ww.x, fmaf(a.y,ww.y, fmaf(a.z,ww.z, fmaf(a.w,ww.w, acc))));
  }
  out[(size_t)b*512 + n] = fmaxf(acc + bias[n], 0.f);
}

__global__ void k_mlp3(const float* __restrict__ h, const float* __restrict__ w,
                       const float* __restrict__ bias, float* __restrict__ out){
  int b = blockIdx.x;
  int n = threadIdx.x >> 6, lane = threadIdx.x & 63;
  if (n >= 3) return;
  float acc = 0.f;
  for (int k=lane; k<512; k+=64) acc = fmaf(h[(size_t)b*512+k], w[(size_t)n*512+k], acc);
  #pragma unroll
  for (int m=1;m<64;m<<=1) acc += __shfl_xor(acc, m);
  if (lane == 0) out[(size_t)b*3 + n] = acc + bias[n];
}

// ---------------- launch ----------------
extern "C" void kernel_launch(void* const* d_in, const int* in_sizes, int n_in,
                              void* d_out, int out_size, void* d_ws, size_t ws_size,
                              hipStream_t stream){
  const int*   tokens = (const int*)  d_in[0];
  const float* mask   = (const float*)d_in[1];
  const float* emb    = (const float*)d_in[2];
  const float* bn_w   = (const float*)d_in[3];
  const float* bn_b   = (const float*)d_in[4];
  const float* conv_w = (const float*)d_in[5];
  const float* conv_b = (const float*)d_in[6];
  const float* in_w   = (const float*)d_in[7];
  const float* c1_w   = (const float*)d_in[8];
  const float* c1_b   = (const float*)d_in[9];
  const float* xp_w   = (const float*)d_in[10];
  const float* dtp_w  = (const float*)d_in[11];
  const float* dtp_b  = (const float*)d_in[12];
  const float* A_log  = (const float*)d_in[13];
  const float* D_par  = (const float*)d_in[14];
  const float* out_w  = (const float*)d_in[15];
  const float* nrm_w  = (const float*)d_in[16];
  const float* l1w = (const float*)d_in[17]; const float* l1b = (const float*)d_in[18];
  const float* l2w = (const float*)d_in[19]; const float* l2b = (const float*)d_in[20];
  const float* l3w = (const float*)d_in[21]; const float* l3b = (const float*)d_in[22];
  float* dout = (float*)d_out;

  // ---- adaptive chunk size from ws_size (constant across calls) ----
  // per-token floats: x 128 + rs 1 + xi 256 + z 256 + xc 256 + bc 32 = 929
  int CB = 64;
  while (CB > 1 && ((size_t)CB*SL*929 + FIX_END)*4 > ws_size) CB >>= 1;
  if (((size_t)CB*SL*929 + FIX_END)*4 > ws_size) return;
  const size_t CTOK = (size_t)CB*SL;

  float* ws  = (float*)d_ws;
  float* w2  = ws + FIX_W2;
  float* pl  = ws + FIX_PL;
  float* pm  = ws + FIX_PM;
  float* pd  = ws + FIX_PD;
  float* h1  = ws + FIX_H1;
  float* h2  = ws + FIX_H2;
  float* xcb = ws + FIX_END;
  float* rs  = xcb + CTOK*128;
  float* xi  = rs  + CTOK;
  float* z   = xi  + CTOK*256;
  float* xc  = z   + CTOK*256;
  float* bcb = xc  + CTOK*256;

  k_w2<<<192, 256, 0, stream>>>(conv_w, w2);

  const int nchunks = NB / CB;
  for (int c = 0; c < nchunks; c++){
    const int* tok_c = tokens + (size_t)c*CTOK;

    k_embed<<<CB*2050, 128, 0, stream>>>(tok_c, emb, bn_w, bn_b, xi);
    k_gemm<0,384,128><<<dim3(1, CTOK/64), 256, 0, stream>>>(
        xi, w2, conv_b, nullptr, nullptr, xcb, nullptr);

    for (int layer = 0; layer < NLAYER; layer++){
      const float* lin  = in_w  + (size_t)layer*512*128;
      const float* lcw  = c1_w  + (size_t)layer*DIN*4;
      const float* lcb  = c1_b  + (size_t)layer*DIN;
      const float* lxp  = xp_w  + (size_t)layer*40*DIN;
      const float* ldw  = dtp_w + (size_t)layer*DIN*8;
      const float* ldb  = dtp_b + (size_t)layer*DIN;
      const float* lal  = A_log + (size_t)layer*DIN*DST;
      const float* lD   = D_par + (size_t)layer*DIN;
      const float* low  = out_w + (size_t)layer*128*256;
      const float* lnw  = nrm_w + (size_t)layer*128;

      k_rmsscale<<<CTOK/4, 256, 0, stream>>>(xcb, rs);
      k_gemm<1,128,512><<<dim3(4, CTOK/64), 256, 0, stream>>>(
          xcb, lin, nullptr, rs, lnw, xi, z);
      k_dwconv<<<(int)CTOK, 256, 0, stream>>>(xi, lcw, lcb, xc);
      k_xdbl<<<(int)(CTOK/16), 256, 0, stream>>>(xc, lxp, ldw, ldb, xi /*dta*/, bcb);
      k_scan<<<CB*8, 256, 0, stream>>>(xi /*dta*/, xc, bcb, z, lal, lD);
      k_gemm<2,256,128><<<dim3(1, CTOK/64), 256, 0, stream>>>(
          xc, low, nullptr, nullptr, nullptr, xcb, nullptr);
    }

    k_pool1<<<dim3(16, CB), 256, 0, stream>>>(
        xcb, mask + (size_t)c*CTOK, pl + (size_t)c*CB*16*128, pm + (size_t)c*CB*16);
  }

  k_pool2<<<NB, 128, 0, stream>>>(pl, pm, pd);
  k_mlp_a<<<dim3(4, NB), 128, 0, stream>>>(pd, l1w, l1b, h1, 128);
  k_mlp_a<<<dim3(4, NB), 128, 0, stream>>>(h1, l2w, l2b, h2, 512);
  k_mlp3<<<NB, 256, 0, stream>>>(h2, l3w, l3b, dout);
}

// Round 5
// 7510.323 us; speedup vs baseline: 2.3532x; 1.2664x over previous
//
#include <hip/hip_runtime.h>
#include <math.h>

// ---------------- problem constants ----------------
#define NB     64
#define SL     2048
#define NTOK   (NB*SL)
#define EMB_D  128
#define DMODEL 128
#define DIN    256
#define DST    16
#define NLAYER 4
#define SEG    64
#define NSEG   (SL/SEG)        // 32

// fixed small region (floats)
#define FIX_W2 ((size_t)0)
#define FIX_PL (FIX_W2 + 49152)
#define FIX_PM (FIX_PL + 131072)
#define FIX_PD (FIX_PM + 1024)
#define FIX_H1 (FIX_PD + 8192)
#define FIX_H2 (FIX_H1 + 32768)
#define FIX_END (FIX_H2 + 32768)          // 254,976 floats

__device__ __forceinline__ float siluf(float v){ return v / (1.f + expf(-v)); }

// ---------------- front-conv weight repack: W2[d][k*128+e] = conv_w[d][e][k] ----------------
__global__ void k_w2(const float* __restrict__ cw, float* __restrict__ w2){
  int g = blockIdx.x*256 + threadIdx.x;
  if (g >= 128*384) return;
  int d = g / 384, j = g % 384;
  int k = j >> 7, e = j & 127;
  w2[g] = cw[d*384 + e*3 + k];
}

// ---------------- embed + BN into padded chunk buffer ----------------
__global__ void k_embed(const int* __restrict__ tok, const float* __restrict__ emb,
                        const float* __restrict__ bnw, const float* __restrict__ bnb,
                        float* __restrict__ xp){
  int r = blockIdx.x;                 // CB*2050 rows
  int e = threadIdx.x;                // 128
  int b = r / 2050, tp = r % 2050;
  float v = 0.f;
  if (tp != 0 && tp != 2049){
    int t = tp - 1;
    int id = tok[(size_t)b*SL + t];
    float s = bnw[e] * rsqrtf(1.0f + 1e-5f);
    v = emb[(size_t)id*EMB_D + e] * s + bnb[e];
  }
  xp[(size_t)r*EMB_D + e] = v;
}

// ---------------- rmsnorm scale only ----------------
__global__ __launch_bounds__(256) void k_rmsscale(const float* __restrict__ x,
                                                  float* __restrict__ rs){
  int wv = threadIdx.x>>6, lane = threadIdx.x&63;
  size_t tok = (size_t)blockIdx.x*4 + wv;
  float2 v = *(const float2*)(x + tok*128 + lane*2);
  float ss = v.x*v.x + v.y*v.y;
  #pragma unroll
  for (int m=1;m<64;m<<=1) ss += __shfl_xor(ss, m);
  float r = rsqrtf(ss*(1.f/128.f) + 1e-5f);
  if (lane == 0) rs[tok] = r;
}

// ---------------- tiled fp32 GEMM  out[M,N] = A[M,K] @ W[N,K]^T -------------------
template<int MODE, int K, int N>
__global__ __launch_bounds__(256) void k_gemm(
    const float* __restrict__ A, const float* __restrict__ W,
    const float* __restrict__ bias, const float* __restrict__ rsp,
    const float* __restrict__ nwp,
    float* __restrict__ out, float* __restrict__ out2){
  const int tid = threadIdx.x;
  const int m0 = blockIdx.y * 64;
  const int n0 = blockIdx.x * 128;
  __shared__ float As[32][68];
  __shared__ float Bs[32][132];
  float acc[4][8];
  #pragma unroll
  for (int i=0;i<4;i++)
    #pragma unroll
    for (int j=0;j<8;j++) acc[i][j]=0.f;
  const int row0 = (tid>>4)*4;
  const int col0 = (tid&15)*8;

  size_t abase;
  if constexpr(MODE==0){
    int bb = m0 >> 11, tloc = m0 & 2047;
    abase = ((size_t)bb*2050 + tloc) * 128;
  } else {
    abase = (size_t)m0 * K;
  }

  for (int k0 = 0; k0 < K; k0 += 32){
    #pragma unroll
    for (int i=0;i<2;i++){
      int idx = tid + i*256;
      int m = idx>>3, kq = idx&7;
      int kk = kq*4;
      float4 v;
      if constexpr(MODE==0){
        v = *(const float4*)(A + abase + (size_t)m*128 + k0 + kk);
      } else if constexpr(MODE==1){
        float4 x4 = *(const float4*)(A + abase + (size_t)m*K + k0 + kk);
        float4 w4 = *(const float4*)(nwp + k0 + kk);
        float s = rsp[m0 + m];
        v.x = x4.x*s*w4.x; v.y = x4.y*s*w4.y; v.z = x4.z*s*w4.z; v.w = x4.w*s*w4.w;
      } else {
        v = *(const float4*)(A + abase + (size_t)m*K + k0 + kk);
      }
      As[kk  ][m]=v.x; As[kk+1][m]=v.y; As[kk+2][m]=v.z; As[kk+3][m]=v.w;
    }
    #pragma unroll
    for (int i=0;i<4;i++){
      int idx = tid + i*256;
      int n = idx>>3, kq = idx&7;
      int kk = kq*4;
      float4 v = *(const float4*)(W + (size_t)(n0+n)*K + k0 + kk);
      Bs[kk  ][n]=v.x; Bs[kk+1][n]=v.y; Bs[kk+2][n]=v.z; Bs[kk+3][n]=v.w;
    }
    __syncthreads();
    #pragma unroll
    for (int k=0;k<32;k++){
      float4 a  = *(const float4*)&As[k][row0];
      float4 b0 = *(const float4*)&Bs[k][col0];
      float4 b1 = *(const float4*)&Bs[k][col0+4];
      float av[4] = {a.x,a.y,a.z,a.w};
      float bv[8] = {b0.x,b0.y,b0.z,b0.w,b1.x,b1.y,b1.z,b1.w};
      #pragma unroll
      for (int i=0;i<4;i++)
        #pragma unroll
        for (int j=0;j<8;j++) acc[i][j] = fmaf(av[i], bv[j], acc[i][j]);
    }
    __syncthreads();
  }

  #pragma unroll
  for (int i=0;i<4;i++){
    int m = m0 + row0 + i;
    #pragma unroll
    for (int j=0;j<8;j++){
      int n = n0 + col0 + j;
      float c = acc[i][j];
      if constexpr(MODE==0){
        out[(size_t)m*DMODEL + n] = fmaxf(c + bias[n], 0.f);
      } else if constexpr(MODE==1){
        if (n < DIN) out [(size_t)m*DIN + n]       = c;
        else         out2[(size_t)m*DIN + n - DIN] = c;
      } else {
        float* p = out + (size_t)m*DMODEL + n;
        *p = *p + c;
      }
    }
  }
}

// ---------------- depthwise causal conv (k=4) + silu ----------------
__global__ __launch_bounds__(256) void k_dwconv(const float* __restrict__ xi,
    const float* __restrict__ w, const float* __restrict__ cb, float* __restrict__ xc){
  int m = blockIdx.x;  int d = threadIdx.x;
  int t = m & 2047;
  const float* wd = w + d*4;
  float acc = cb[d];
  const float* base = xi + (size_t)m*DIN + d;
  if (t>=3) acc = fmaf(wd[0], base[-3*DIN], acc);
  if (t>=2) acc = fmaf(wd[1], base[-2*DIN], acc);
  if (t>=1) acc = fmaf(wd[2], base[-1*DIN], acc);
  acc = fmaf(wd[3], base[0], acc);
  xc[(size_t)m*DIN + d] = siluf(acc);
}

// ---------------- fused x_proj + dt_proj(+softplus) + B/C scatter ----------------
__global__ __launch_bounds__(256) void k_xdbl(const float* __restrict__ xc,
    const float* __restrict__ xpw, const float* __restrict__ dtw,
    const float* __restrict__ dtb, float* __restrict__ dta, float* __restrict__ bc){
  __shared__ float xcl[16][260];
  __shared__ float vl[16][44];
  const int tid = threadIdx.x;
  const int row0 = blockIdx.x * 16;
  #pragma unroll
  for (int i=0;i<4;i++){
    int q = tid + i*256;
    int tk = q>>6, kq = q&63;
    float4 v = *(const float4*)(xc + (size_t)(row0+tk)*DIN + kq*4);
    *(float4*)&xcl[tk][kq*4] = v;
  }
  __syncthreads();
  for (int j = tid; j < 640; j += 256){
    int tk = j / 40, c = j % 40;
    const float4* wp = (const float4*)(xpw + (size_t)c*DIN);
    float acc = 0.f;
    #pragma unroll
    for (int kk=0;kk<64;kk++){
      float4 xv = *(const float4*)&xcl[tk][kk*4];
      float4 wv = wp[kk];
      acc = fmaf(xv.x,wv.x, fmaf(xv.y,wv.y, fmaf(xv.z,wv.z, fmaf(xv.w,wv.w, acc))));
    }
    vl[tk][c] = acc;
  }
  __syncthreads();
  // bc[row*32 + 4j+{0,1,2,3}] = {B2j, C2j, B2j+1, C2j+1}
  for (int j = tid; j < 512; j += 256){
    int tk = j>>5, i = j&31;
    int s = i>>1;
    bc[(size_t)(row0+tk)*32 + i] = vl[tk][8 + ((i&1)<<4) + s];
  }
  #pragma unroll
  for (int it=0; it<16; it++){
    int j = tid + it*256;
    int tk = j>>8, d = j&255;
    float4 v0 = *(const float4*)&vl[tk][0];
    float4 v1 = *(const float4*)&vl[tk][4];
    const float4* wp = (const float4*)(dtw + (size_t)d*8);
    float4 w0 = wp[0], w1 = wp[1];
    float acc = dtb[d];
    acc = fmaf(v0.x,w0.x, fmaf(v0.y,w0.y, fmaf(v0.z,w0.z, fmaf(v0.w,w0.w, acc))));
    acc = fmaf(v1.x,w1.x, fmaf(v1.y,w1.y, fmaf(v1.z,w1.z, fmaf(v1.w,w1.w, acc))));
    float dt = (acc > 0.f) ? (acc + log1pf(expf(-acc))) : log1pf(expf(acc));
    dta[(size_t)(row0+tk)*DIN + d] = dt;
  }
}

// ======== segment-parallel selective scan ========
// Phase A: per (b, d-group, seg): c_seg = h after SEG steps from h=0; sdt = sum(dt).
// Phase B: serial combine over NSEG segments per (b,d,s); writes h_in into cseg in place.
// Phase C: per segment: h from cseg, y-reduction, fused gate, write into xc in place.

__global__ __launch_bounds__(256) void k_scanA(const float* __restrict__ dta,
    const float* __restrict__ u_, const float* __restrict__ bc,
    const float* __restrict__ alog, float* __restrict__ cseg, float* __restrict__ sdtb){
  __shared__ float sdt[SEG][33];
  __shared__ float su [SEG][33];
  __shared__ float sbc[SEG][36];
  const int tid = threadIdx.x;
  const int g = blockIdx.x, dg = blockIdx.y, b = blockIdx.z;
  const int j = tid & 7, dl = tid >> 3;
  const int d0 = dg << 5, d = d0 + dl;
  const float LOG2E = 1.4426950408889634f;
  const float a0 = -expf(alog[d*DST + 2*j    ]) * LOG2E;
  const float a1 = -expf(alog[d*DST + 2*j + 1]) * LOG2E;
  const int sr = tid >> 3, sc = (tid & 7) * 4;
  const size_t rowbase = (size_t)b*SL + (size_t)g*SEG;
  #pragma unroll
  for (int p=0;p<2;p++){
    int r = p*32 + sr;
    size_t go = (rowbase + r)*DIN + d0 + sc;
    float4 dv = *(const float4*)(dta + go);
    float4 uv = *(const float4*)(u_  + go);
    sdt[r][sc]=dv.x; sdt[r][sc+1]=dv.y; sdt[r][sc+2]=dv.z; sdt[r][sc+3]=dv.w;
    su [r][sc]=uv.x; su [r][sc+1]=uv.y; su [r][sc+2]=uv.z; su [r][sc+3]=uv.w;
  }
  #pragma unroll
  for (int p=0;p<2;p++){
    int idx = p*256 + tid;
    float4 bv = *(const float4*)(bc + rowbase*32 + (size_t)idx*4);
    *(float4*)&sbc[idx>>3][(idx&7)*4] = bv;
  }
  __syncthreads();
  float h0 = 0.f, h1 = 0.f, ssum = 0.f;
  #pragma unroll 8
  for (int t=0;t<SEG;t++){
    float dt = sdt[t][dl];
    float uu = su [t][dl];
    float4 q = *(const float4*)&sbc[t][4*j];
    float du = dt*uu;
    h0 = fmaf(exp2f(dt*a0), h0, du*q.x);
    h1 = fmaf(exp2f(dt*a1), h1, du*q.z);
    ssum += dt;
  }
  size_t cb = (((size_t)b*NSEG + g)*DIN + d)*DST;
  cseg[cb + 2*j    ] = h0;
  cseg[cb + 2*j + 1] = h1;
  if (j == 0) sdtb[((size_t)b*NSEG + g)*DIN + d] = ssum;
}

__global__ __launch_bounds__(256) void k_scanB(float* __restrict__ cseg,
    const float* __restrict__ sdtb, const float* __restrict__ alog){
  int gl = blockIdx.x*256 + threadIdx.x;   // CB*4096 lanes
  int b   = gl >> 12;
  int rem = gl & 4095;
  int d = rem >> 4, s = rem & 15;
  const float LOG2E = 1.4426950408889634f;
  const float a = -expf(alog[d*DST + s]) * LOG2E;
  float h = 0.f;
  for (int g=0; g<NSEG; g++){
    size_t base = ((size_t)b*NSEG + g)*DIN;
    float sd = sdtb[base + d];
    size_t ci = (base + d)*DST + s;
    float c = cseg[ci];
    cseg[ci] = h;                       // h_in for segment g
    h = fmaf(exp2f(a*sd), h, c);
  }
}

__global__ __launch_bounds__(256) void k_scanC(const float* __restrict__ dta,
    float* xcio, const float* __restrict__ bc, const float* __restrict__ z,
    const float* __restrict__ alog, const float* __restrict__ Dpar,
    const float* __restrict__ cseg){
  __shared__ float sdt[SEG][33];
  __shared__ float su [SEG][33];
  __shared__ float sbc[SEG][36];
  __shared__ float szs[SEG][36];
  __shared__ float sys[SEG][33];
  const int tid = threadIdx.x;
  const int g = blockIdx.x, dg = blockIdx.y, b = blockIdx.z;
  const int j = tid & 7, dl = tid >> 3;
  const int d0 = dg << 5, d = d0 + dl;
  const float LOG2E = 1.4426950408889634f;
  const float a0 = -expf(alog[d*DST + 2*j    ]) * LOG2E;
  const float a1 = -expf(alog[d*DST + 2*j + 1]) * LOG2E;
  const int sr = tid >> 3, sc = (tid & 7) * 4;
  const float4 D4 = *(const float4*)(Dpar + d0 + sc);
  const size_t rowbase = (size_t)b*SL + (size_t)g*SEG;
  size_t cb = (((size_t)b*NSEG + g)*DIN + d)*DST;
  float h0 = cseg[cb + 2*j];
  float h1 = cseg[cb + 2*j + 1];
  #pragma unroll
  for (int p=0;p<2;p++){
    int r = p*32 + sr;
    size_t go = (rowbase + r)*DIN + d0 + sc;
    float4 dv = *(const float4*)(dta  + go);
    float4 uv = *(const float4*)(xcio + go);
    float4 zv = *(const float4*)(z    + go);
    sdt[r][sc]=dv.x; sdt[r][sc+1]=dv.y; sdt[r][sc+2]=dv.z; sdt[r][sc+3]=dv.w;
    su [r][sc]=uv.x; su [r][sc+1]=uv.y; su [r][sc+2]=uv.z; su [r][sc+3]=uv.w;
    *(float4*)&szs[r][sc] = zv;
  }
  #pragma unroll
  for (int p=0;p<2;p++){
    int idx = p*256 + tid;
    float4 bv = *(const float4*)(bc + rowbase*32 + (size_t)idx*4);
    *(float4*)&sbc[idx>>3][(idx&7)*4] = bv;
  }
  __syncthreads();
  #pragma unroll 8
  for (int t=0;t<SEG;t++){
    float dt = sdt[t][dl];
    float uu = su [t][dl];
    float4 q = *(const float4*)&sbc[t][4*j];
    float du = dt*uu;
    h0 = fmaf(exp2f(dt*a0), h0, du*q.x);
    h1 = fmaf(exp2f(dt*a1), h1, du*q.z);
    float p = fmaf(h0, q.y, h1*q.w);
    p += __shfl_xor(p, 1);
    p += __shfl_xor(p, 2);
    p += __shfl_xor(p, 4);
    if (j == 0) sys[t][dl] = p;
  }
  __syncthreads();
  #pragma unroll
  for (int p=0;p<2;p++){
    int r = p*32 + sr;
    float4 zv = *(const float4*)&szs[r][sc];
    float4 o;
    o.x = (sys[r][sc  ] + su[r][sc  ]*D4.x) * siluf(zv.x);
    o.y = (sys[r][sc+1] + su[r][sc+1]*D4.y) * siluf(zv.y);
    o.z = (sys[r][sc+2] + su[r][sc+2]*D4.z) * siluf(zv.z);
    o.w = (sys[r][sc+3] + su[r][sc+3]*D4.w) * siluf(zv.w);
    *(float4*)(xcio + (rowbase + r)*DIN + d0 + sc) = o;
  }
}

// ---------------- masked mean pool over a chunk ----------------
__global__ __launch_bounds__(256) void k_pool1(const float* __restrict__ x,
    const float* __restrict__ mask, float* __restrict__ part, float* __restrict__ pmask){
  int b = blockIdx.y, seg = blockIdx.x;
  int d = threadIdx.x & 127, half = threadIdx.x >> 7;
  int t0 = seg*128 + half*64;
  float acc = 0.f, macc = 0.f;
  for (int i=0;i<64;i++){
    int t = t0 + i;
    float mv = mask[(size_t)b*SL + t];
    acc = fmaf(x[((size_t)b*SL + t)*DMODEL + d], mv, acc);
    macc += mv;
  }
  __shared__ float sm[256];
  __shared__ float smm[2];
  sm[threadIdx.x] = acc;
  if (d == 0) smm[half] = macc;
  __syncthreads();
  if (half == 0){
    part[((size_t)b*16 + seg)*128 + d] = sm[d] + sm[128+d];
    if (d == 0) pmask[b*16 + seg] = smm[0] + smm[1];
  }
}

__global__ void k_pool2(const float* __restrict__ part, const float* __restrict__ pmask,
                        float* __restrict__ pooled){
  int b = blockIdx.x, d = threadIdx.x;
  float acc = 0.f, ms = 0.f;
  for (int s=0;s<16;s++){ acc += part[((size_t)b*16+s)*128 + d]; ms += pmask[b*16+s]; }
  pooled[(size_t)b*128 + d] = acc / fmaxf(ms, 1e-9f);
}

// ---------------- tiny MLP ----------------
__global__ void k_mlp_a(const float* __restrict__ in, const float* __restrict__ w,
                        const float* __restrict__ bias, float* __restrict__ out, int K){
  int b = blockIdx.y;
  int n = blockIdx.x*128 + threadIdx.x;
  const float4* pw = (const float4*)(w + (size_t)n*K);
  const float4* pi = (const float4*)(in + (size_t)b*K);
  float acc = 0.f;
  for (int k=0;k<K/4;k++){
    float4 a = pi[k], ww = pw[k];
    acc = fmaf(a.x,ww.x, fmaf(a.y,ww.y, fmaf(a.z,ww.z, fmaf(a.w,ww.w, acc))));
  }
  out[(size_t)b*512 + n] = fmaxf(acc + bias[n], 0.f);
}

__global__ void k_mlp3(const float* __restrict__ h, const float* __restrict__ w,
                       const float* __restrict__ bias, float* __restrict__ out){
  int b = blockIdx.x;
  int n = threadIdx.x >> 6, lane = threadIdx.x & 63;
  if (n >= 3) return;
  float acc = 0.f;
  for (int k=lane; k<512; k+=64) acc = fmaf(h[(size_t)b*512+k], w[(size_t)n*512+k], acc);
  #pragma unroll
  for (int m=1;m<64;m<<=1) acc += __shfl_xor(acc, m);
  if (lane == 0) out[(size_t)b*3 + n] = acc + bias[n];
}

// ---------------- launch ----------------
extern "C" void kernel_launch(void* const* d_in, const int* in_sizes, int n_in,
                              void* d_out, int out_size, void* d_ws, size_t ws_size,
                              hipStream_t stream){
  const int*   tokens = (const int*)  d_in[0];
  const float* mask   = (const float*)d_in[1];
  const float* emb    = (const float*)d_in[2];
  const float* bn_w   = (const float*)d_in[3];
  const float* bn_b   = (const float*)d_in[4];
  const float* conv_w = (const float*)d_in[5];
  const float* conv_b = (const float*)d_in[6];
  const float* in_w   = (const float*)d_in[7];
  const float* c1_w   = (const float*)d_in[8];
  const float* c1_b   = (const float*)d_in[9];
  const float* xp_w   = (const float*)d_in[10];
  const float* dtp_w  = (const float*)d_in[11];
  const float* dtp_b  = (const float*)d_in[12];
  const float* A_log  = (const float*)d_in[13];
  const float* D_par  = (const float*)d_in[14];
  const float* out_w  = (const float*)d_in[15];
  const float* nrm_w  = (const float*)d_in[16];
  const float* l1w = (const float*)d_in[17]; const float* l1b = (const float*)d_in[18];
  const float* l2w = (const float*)d_in[19]; const float* l2b = (const float*)d_in[20];
  const float* l3w = (const float*)d_in[21]; const float* l3b = (const float*)d_in[22];
  float* dout = (float*)d_out;

  // ---- adaptive chunk size from ws_size (constant across calls) ----
  // per-token floats: x 128 + rs 1 + xi 256 + z 256 + xc 256 + bc 32 + cseg 64 + sdt 4 = 997
  int CB = 64;
  while (CB > 1 && ((size_t)CB*SL*997 + FIX_END)*4 > ws_size) CB >>= 1;
  if (((size_t)CB*SL*997 + FIX_END)*4 > ws_size) return;
  const size_t CTOK = (size_t)CB*SL;

  float* ws  = (float*)d_ws;
  float* w2  = ws + FIX_W2;
  float* pl  = ws + FIX_PL;
  float* pm  = ws + FIX_PM;
  float* pd  = ws + FIX_PD;
  float* h1  = ws + FIX_H1;
  float* h2  = ws + FIX_H2;
  float* xcb = ws + FIX_END;                 // CTOK*128
  float* rs  = xcb + CTOK*128;               // CTOK
  float* xi  = rs  + CTOK;                   // CTOK*256 (embed pad / x-branch / dta)
  float* z   = xi  + CTOK*256;               // CTOK*256
  float* xc  = z   + CTOK*256;               // CTOK*256
  float* bcb = xc  + CTOK*256;               // CTOK*32
  float* csg = bcb + CTOK*32;                // CTOK*64  (segment summaries / h_in)
  float* sdt = csg + CTOK*64;                // CTOK*4   (segment dt sums)

  k_w2<<<192, 256, 0, stream>>>(conv_w, w2);

  const int nchunks = NB / CB;
  for (int c = 0; c < nchunks; c++){
    const int* tok_c = tokens + (size_t)c*CTOK;

    k_embed<<<CB*2050, 128, 0, stream>>>(tok_c, emb, bn_w, bn_b, xi);
    k_gemm<0,384,128><<<dim3(1, CTOK/64), 256, 0, stream>>>(
        xi, w2, conv_b, nullptr, nullptr, xcb, nullptr);

    for (int layer = 0; layer < NLAYER; layer++){
      const float* lin  = in_w  + (size_t)layer*512*128;
      const float* lcw  = c1_w  + (size_t)layer*DIN*4;
      const float* lcb  = c1_b  + (size_t)layer*DIN;
      const float* lxp  = xp_w  + (size_t)layer*40*DIN;
      const float* ldw  = dtp_w + (size_t)layer*DIN*8;
      const float* ldb  = dtp_b + (size_t)layer*DIN;
      const float* lal  = A_log + (size_t)layer*DIN*DST;
      const float* lD   = D_par + (size_t)layer*DIN;
      const float* low  = out_w + (size_t)layer*128*256;
      const float* lnw  = nrm_w + (size_t)layer*128;

      k_rmsscale<<<CTOK/4, 256, 0, stream>>>(xcb, rs);
      k_gemm<1,128,512><<<dim3(4, CTOK/64), 256, 0, stream>>>(
          xcb, lin, nullptr, rs, lnw, xi, z);
      k_dwconv<<<(int)CTOK, 256, 0, stream>>>(xi, lcw, lcb, xc);
      k_xdbl<<<(int)(CTOK/16), 256, 0, stream>>>(xc, lxp, ldw, ldb, xi /*dta*/, bcb);
      k_scanA<<<dim3(NSEG, 8, CB), 256, 0, stream>>>(xi, xc, bcb, lal, csg, sdt);
      k_scanB<<<CB*16, 256, 0, stream>>>(csg, sdt, lal);
      k_scanC<<<dim3(NSEG, 8, CB), 256, 0, stream>>>(xi, xc, bcb, z, lal, lD, csg);
      k_gemm<2,256,128><<<dim3(1, CTOK/64), 256, 0, stream>>>(
          xc, low, nullptr, nullptr, nullptr, xcb, nullptr);
    }

    k_pool1<<<dim3(16, CB), 256, 0, stream>>>(
        xcb, mask + (size_t)c*CTOK, pl + (size_t)c*CB*16*128, pm + (size_t)c*CB*16);
  }

  k_pool2<<<NB, 128, 0, stream>>>(pl, pm, pd);
  k_mlp_a<<<dim3(4, NB), 128, 0, stream>>>(pd, l1w, l1b, h1, 128);
  k_mlp_a<<<dim3(4, NB), 128, 0, stream>>>(h1, l2w, l2b, h2, 512);
  k_mlp3<<<NB, 256, 0, stream>>>(h2, l3w, l3b, dout);
}

// Round 6
// 5795.782 us; speedup vs baseline: 3.0494x; 1.2958x over previous
//
#include <hip/hip_runtime.h>
#include <math.h>

// ---------------- problem constants ----------------
#define NB     64
#define SL     2048
#define NTOK   (NB*SL)
#define EMB_D  128
#define DMODEL 128
#define DIN    256
#define DST    16
#define NLAYER 4
#define SEG    64
#define NSEG   (SL/SEG)        // 32

// fixed small region (floats)
#define FIX_W2 ((size_t)0)
#define FIX_PL (FIX_W2 + 49152)
#define FIX_PM (FIX_PL + 131072)
#define FIX_PD (FIX_PM + 1024)
#define FIX_H1 (FIX_PD + 8192)
#define FIX_H2 (FIX_H1 + 32768)
#define FIX_WP (FIX_H2 + 32768)           // 4 layers x 64 x 256 combined x_proj weight
#define FIX_END (FIX_WP + 65536)          // 320,512 floats

__device__ __forceinline__ float siluf(float v){ return v / (1.f + expf(-v)); }

// ---------------- front-conv weight repack: W2[d][k*128+e] = conv_w[d][e][k] ----------------
__global__ void k_w2(const float* __restrict__ cw, float* __restrict__ w2){
  int g = blockIdx.x*256 + threadIdx.x;
  if (g >= 128*384) return;
  int d = g / 384, j = g % 384;
  int k = j >> 7, e = j & 127;
  w2[g] = cw[d*384 + e*3 + k];
}

// ---------------- x_proj weight prep: Wp[l][64][256], bc-interleave baked in ----------------
__global__ void k_wprep(const float* __restrict__ xpw, float* __restrict__ wp){
  int g = blockIdx.x*256 + threadIdx.x;      // 4*64*256 = 65536
  int l = g >> 14, rem = g & 16383;
  int n = rem >> 8, k = rem & 255;
  float v = 0.f;
  if (n < 8){
    v = xpw[(size_t)l*40*256 + n*256 + k];
  } else if (n < 40){
    int i = n - 8;
    int row = 8 + ((i&1)<<4) + (i>>1);       // B_s / C_s interleaved pairs
    v = xpw[(size_t)l*40*256 + row*256 + k];
  }
  wp[g] = v;
}

// ---------------- embed + BN into padded chunk buffer ----------------
__global__ void k_embed(const int* __restrict__ tok, const float* __restrict__ emb,
                        const float* __restrict__ bnw, const float* __restrict__ bnb,
                        float* __restrict__ xp){
  int r = blockIdx.x;                 // CB*2050 rows
  int e = threadIdx.x;                // 128
  int b = r / 2050, tp = r % 2050;
  float v = 0.f;
  if (tp != 0 && tp != 2049){
    int t = tp - 1;
    int id = tok[(size_t)b*SL + t];
    float s = bnw[e] * rsqrtf(1.0f + 1e-5f);
    v = emb[(size_t)id*EMB_D + e] * s + bnb[e];
  }
  xp[(size_t)r*EMB_D + e] = v;
}

// ---------------- rmsnorm scale only ----------------
__global__ __launch_bounds__(256) void k_rmsscale(const float* __restrict__ x,
                                                  float* __restrict__ rs){
  int wv = threadIdx.x>>6, lane = threadIdx.x&63;
  size_t tok = (size_t)blockIdx.x*4 + wv;
  float2 v = *(const float2*)(x + tok*128 + lane*2);
  float ss = v.x*v.x + v.y*v.y;
  #pragma unroll
  for (int m=1;m<64;m<<=1) ss += __shfl_xor(ss, m);
  float r = rsqrtf(ss*(1.f/128.f) + 1e-5f);
  if (lane == 0) rs[tok] = r;
}

// ---------------- tiled fp32 GEMM  out[M,N] = A[M,K] @ W[N,K]^T -------------------
template<int MODE, int K, int N>
__global__ __launch_bounds__(256) void k_gemm(
    const float* __restrict__ A, const float* __restrict__ W,
    const float* __restrict__ bias, const float* __restrict__ rsp,
    const float* __restrict__ nwp,
    float* __restrict__ out, float* __restrict__ out2){
  const int tid = threadIdx.x;
  const int m0 = blockIdx.y * 64;
  const int n0 = blockIdx.x * 128;
  __shared__ float As[32][68];
  __shared__ float Bs[32][132];
  float acc[4][8];
  #pragma unroll
  for (int i=0;i<4;i++)
    #pragma unroll
    for (int j=0;j<8;j++) acc[i][j]=0.f;
  const int row0 = (tid>>4)*4;
  const int col0 = (tid&15)*8;

  size_t abase;
  if constexpr(MODE==0){
    int bb = m0 >> 11, tloc = m0 & 2047;
    abase = ((size_t)bb*2050 + tloc) * 128;
  } else {
    abase = (size_t)m0 * K;
  }

  for (int k0 = 0; k0 < K; k0 += 32){
    #pragma unroll
    for (int i=0;i<2;i++){
      int idx = tid + i*256;
      int m = idx>>3, kq = idx&7;
      int kk = kq*4;
      float4 v;
      if constexpr(MODE==0){
        v = *(const float4*)(A + abase + (size_t)m*128 + k0 + kk);
      } else if constexpr(MODE==1){
        float4 x4 = *(const float4*)(A + abase + (size_t)m*K + k0 + kk);
        float4 w4 = *(const float4*)(nwp + k0 + kk);
        float s = rsp[m0 + m];
        v.x = x4.x*s*w4.x; v.y = x4.y*s*w4.y; v.z = x4.z*s*w4.z; v.w = x4.w*s*w4.w;
      } else {
        v = *(const float4*)(A + abase + (size_t)m*K + k0 + kk);
      }
      As[kk  ][m]=v.x; As[kk+1][m]=v.y; As[kk+2][m]=v.z; As[kk+3][m]=v.w;
    }
    #pragma unroll
    for (int i=0;i<4;i++){
      int idx = tid + i*256;
      int n = idx>>3, kq = idx&7;
      int kk = kq*4;
      float4 v = *(const float4*)(W + (size_t)(n0+n)*K + k0 + kk);
      Bs[kk  ][n]=v.x; Bs[kk+1][n]=v.y; Bs[kk+2][n]=v.z; Bs[kk+3][n]=v.w;
    }
    __syncthreads();
    #pragma unroll
    for (int k=0;k<32;k++){
      float4 a  = *(const float4*)&As[k][row0];
      float4 b0 = *(const float4*)&Bs[k][col0];
      float4 b1 = *(const float4*)&Bs[k][col0+4];
      float av[4] = {a.x,a.y,a.z,a.w};
      float bv[8] = {b0.x,b0.y,b0.z,b0.w,b1.x,b1.y,b1.z,b1.w};
      #pragma unroll
      for (int i=0;i<4;i++)
        #pragma unroll
        for (int j=0;j<8;j++) acc[i][j] = fmaf(av[i], bv[j], acc[i][j]);
    }
    __syncthreads();
  }

  #pragma unroll
  for (int i=0;i<4;i++){
    int m = m0 + row0 + i;
    #pragma unroll
    for (int j=0;j<8;j++){
      int n = n0 + col0 + j;
      float c = acc[i][j];
      if constexpr(MODE==0){
        out[(size_t)m*DMODEL + n] = fmaxf(c + bias[n], 0.f);
      } else if constexpr(MODE==1){
        if (n < DIN) out [(size_t)m*DIN + n]       = c;
        else         out2[(size_t)m*DIN + n - DIN] = c;
      } else {
        float* p = out + (size_t)m*DMODEL + n;
        *p = *p + c;
      }
    }
  }
}

// ---------------- depthwise causal conv (k=4) + silu ----------------
__global__ __launch_bounds__(256) void k_dwconv(const float* __restrict__ xi,
    const float* __restrict__ w, const float* __restrict__ cb, float* __restrict__ xc){
  int m = blockIdx.x;  int d = threadIdx.x;
  int t = m & 2047;
  const float* wd = w + d*4;
  float acc = cb[d];
  const float* base = xi + (size_t)m*DIN + d;
  if (t>=3) acc = fmaf(wd[0], base[-3*DIN], acc);
  if (t>=2) acc = fmaf(wd[1], base[-2*DIN], acc);
  if (t>=1) acc = fmaf(wd[2], base[-1*DIN], acc);
  acc = fmaf(wd[3], base[0], acc);
  xc[(size_t)m*DIN + d] = siluf(acc);
}

// ---------------- fused x_proj GEMM + dt_proj(+softplus) + bc copy ----------------
// Per block: 64 tokens. GEMM vls[64][64] = xc[64x256] @ Wp[64x256]^T (rows 0..7 = rank,
// 8..39 = bc pre-interleaved, 40..63 = 0). Epilogue: bc contiguous copy; dt = softplus(
// v8 . dtp_w[d] + dtb[d]) for all 256 d.
__global__ __launch_bounds__(256) void k_xdbl2(const float* __restrict__ xc,
    const float* __restrict__ wp, const float* __restrict__ dtw,
    const float* __restrict__ dtb, float* __restrict__ dta, float* __restrict__ bc){
  __shared__ float As[32][68];
  __shared__ float Bs[32][68];
  __shared__ float vls[64][68];
  __shared__ float sdtw[256][8];
  __shared__ float sdtb[256];
  const int tid = threadIdx.x;
  const size_t m0 = (size_t)blockIdx.x * 64;
  const int row0 = (tid>>4)*4;
  const int col0 = (tid&15)*4;
  float acc[4][4];
  #pragma unroll
  for (int i=0;i<4;i++)
    #pragma unroll
    for (int j=0;j<4;j++) acc[i][j]=0.f;

  // stage dtp_w (256x8) and dtb
  {
    const float4* src = (const float4*)dtw;
    float4 v0 = src[tid], v1 = src[tid+256];
    *(float4*)&sdtw[tid>>1][(tid&1)*4] = v0;
    *(float4*)&sdtw[(tid+256)>>1][(tid&1)*4] = v1;
    sdtb[tid] = dtb[tid];
  }

  for (int k0 = 0; k0 < 256; k0 += 32){
    #pragma unroll
    for (int i=0;i<2;i++){
      int idx = tid + i*256;
      int m = idx>>3, kq = idx&7;
      int kk = kq*4;
      float4 va = *(const float4*)(xc + (m0+m)*DIN + k0 + kk);
      As[kk  ][m]=va.x; As[kk+1][m]=va.y; As[kk+2][m]=va.z; As[kk+3][m]=va.w;
      float4 vb = *(const float4*)(wp + (size_t)m*256 + k0 + kk);
      Bs[kk  ][m]=vb.x; Bs[kk+1][m]=vb.y; Bs[kk+2][m]=vb.z; Bs[kk+3][m]=vb.w;
    }
    __syncthreads();
    #pragma unroll
    for (int k=0;k<32;k++){
      float4 a = *(const float4*)&As[k][row0];
      float4 b = *(const float4*)&Bs[k][col0];
      float av[4]={a.x,a.y,a.z,a.w}, bv[4]={b.x,b.y,b.z,b.w};
      #pragma unroll
      for (int i=0;i<4;i++)
        #pragma unroll
        for (int j=0;j<4;j++) acc[i][j] = fmaf(av[i], bv[j], acc[i][j]);
    }
    __syncthreads();
  }

  #pragma unroll
  for (int i=0;i<4;i++)
    #pragma unroll
    for (int j=0;j<4;j++) vls[row0+i][col0+j] = acc[i][j];
  __syncthreads();

  // bc copy-out (pre-interleaved): 64 tokens x 32
  #pragma unroll
  for (int p=0;p<8;p++){
    int j = tid + p*256;
    int tok = j>>5, i = j&31;
    bc[(m0+tok)*32 + i] = vls[tok][8+i];
  }

  // dt: tok = tid>>2 (4 lanes per token), d = 4*i + (tid&3)
  {
    const int tok = tid>>2, dq = tid&3;
    float4 v0 = *(const float4*)&vls[tok][0];
    float4 v1 = *(const float4*)&vls[tok][4];
    float* drow = dta + (m0+tok)*DIN;
    #pragma unroll 4
    for (int i=0;i<64;i++){
      int d = 4*i + dq;
      float4 w0 = *(const float4*)&sdtw[d][0];
      float4 w1 = *(const float4*)&sdtw[d][4];
      float a = sdtb[d];
      a = fmaf(v0.x,w0.x, fmaf(v0.y,w0.y, fmaf(v0.z,w0.z, fmaf(v0.w,w0.w, a))));
      a = fmaf(v1.x,w1.x, fmaf(v1.y,w1.y, fmaf(v1.z,w1.z, fmaf(v1.w,w1.w, a))));
      float dt = (a > 0.f) ? (a + log1pf(expf(-a))) : log1pf(expf(a));
      drow[d] = dt;
    }
  }
}

// ======== segment-parallel selective scan ========
__global__ __launch_bounds__(256) void k_scanA(const float* __restrict__ dta,
    const float* __restrict__ u_, const float* __restrict__ bc,
    const float* __restrict__ alog, float* __restrict__ cseg, float* __restrict__ sdtb){
  __shared__ float sdt[SEG][33];
  __shared__ float su [SEG][33];
  __shared__ float sbc[SEG][36];
  const int tid = threadIdx.x;
  const int g = blockIdx.x, dg = blockIdx.y, b = blockIdx.z;
  const int j = tid & 7, dl = tid >> 3;
  const int d0 = dg << 5, d = d0 + dl;
  const float LOG2E = 1.4426950408889634f;
  const float a0 = -expf(alog[d*DST + 2*j    ]) * LOG2E;
  const float a1 = -expf(alog[d*DST + 2*j + 1]) * LOG2E;
  const int sr = tid >> 3, sc = (tid & 7) * 4;
  const size_t rowbase = (size_t)b*SL + (size_t)g*SEG;
  #pragma unroll
  for (int p=0;p<2;p++){
    int r = p*32 + sr;
    size_t go = (rowbase + r)*DIN + d0 + sc;
    float4 dv = *(const float4*)(dta + go);
    float4 uv = *(const float4*)(u_  + go);
    sdt[r][sc]=dv.x; sdt[r][sc+1]=dv.y; sdt[r][sc+2]=dv.z; sdt[r][sc+3]=dv.w;
    su [r][sc]=uv.x; su [r][sc+1]=uv.y; su [r][sc+2]=uv.z; su [r][sc+3]=uv.w;
  }
  #pragma unroll
  for (int p=0;p<2;p++){
    int idx = p*256 + tid;
    float4 bv = *(const float4*)(bc + rowbase*32 + (size_t)idx*4);
    *(float4*)&sbc[idx>>3][(idx&7)*4] = bv;
  }
  __syncthreads();
  float h0 = 0.f, h1 = 0.f, ssum = 0.f;
  #pragma unroll 8
  for (int t=0;t<SEG;t++){
    float dt = sdt[t][dl];
    float uu = su [t][dl];
    float4 q = *(const float4*)&sbc[t][4*j];
    float du = dt*uu;
    h0 = fmaf(exp2f(dt*a0), h0, du*q.x);
    h1 = fmaf(exp2f(dt*a1), h1, du*q.z);
    ssum += dt;
  }
  size_t cb = (((size_t)b*NSEG + g)*DIN + d)*DST;
  cseg[cb + 2*j    ] = h0;
  cseg[cb + 2*j + 1] = h1;
  if (j == 0) sdtb[((size_t)b*NSEG + g)*DIN + d] = ssum;
}

__global__ __launch_bounds__(256) void k_scanB(float* __restrict__ cseg,
    const float* __restrict__ sdtb, const float* __restrict__ alog){
  int gl = blockIdx.x*256 + threadIdx.x;   // CB*4096 lanes
  int b   = gl >> 12;
  int rem = gl & 4095;
  int d = rem >> 4, s = rem & 15;
  const float LOG2E = 1.4426950408889634f;
  const float a = -expf(alog[d*DST + s]) * LOG2E;
  float h = 0.f;
  for (int g=0; g<NSEG; g++){
    size_t base = ((size_t)b*NSEG + g)*DIN;
    float sd = sdtb[base + d];
    size_t ci = (base + d)*DST + s;
    float c = cseg[ci];
    cseg[ci] = h;                       // h_in for segment g
    h = fmaf(exp2f(a*sd), h, c);
  }
}

__global__ __launch_bounds__(256) void k_scanC(const float* __restrict__ dta,
    float* xcio, const float* __restrict__ bc, const float* __restrict__ z,
    const float* __restrict__ alog, const float* __restrict__ Dpar,
    const float* __restrict__ cseg){
  __shared__ float sdt[SEG][33];
  __shared__ float su [SEG][33];
  __shared__ float sbc[SEG][36];
  __shared__ float szs[SEG][36];
  __shared__ float sys[SEG][33];
  const int tid = threadIdx.x;
  const int g = blockIdx.x, dg = blockIdx.y, b = blockIdx.z;
  const int j = tid & 7, dl = tid >> 3;
  const int d0 = dg << 5, d = d0 + dl;
  const float LOG2E = 1.4426950408889634f;
  const float a0 = -expf(alog[d*DST + 2*j    ]) * LOG2E;
  const float a1 = -expf(alog[d*DST + 2*j + 1]) * LOG2E;
  const int sr = tid >> 3, sc = (tid & 7) * 4;
  const float4 D4 = *(const float4*)(Dpar + d0 + sc);
  const size_t rowbase = (size_t)b*SL + (size_t)g*SEG;
  size_t cb = (((size_t)b*NSEG + g)*DIN + d)*DST;
  float h0 = cseg[cb + 2*j];
  float h1 = cseg[cb + 2*j + 1];
  #pragma unroll
  for (int p=0;p<2;p++){
    int r = p*32 + sr;
    size_t go = (rowbase + r)*DIN + d0 + sc;
    float4 dv = *(const float4*)(dta  + go);
    float4 uv = *(const float4*)(xcio + go);
    float4 zv = *(const float4*)(z    + go);
    sdt[r][sc]=dv.x; sdt[r][sc+1]=dv.y; sdt[r][sc+2]=dv.z; sdt[r][sc+3]=dv.w;
    su [r][sc]=uv.x; su [r][sc+1]=uv.y; su [r][sc+2]=uv.z; su [r][sc+3]=uv.w;
    *(float4*)&szs[r][sc] = zv;
  }
  #pragma unroll
  for (int p=0;p<2;p++){
    int idx = p*256 + tid;
    float4 bv = *(const float4*)(bc + rowbase*32 + (size_t)idx*4);
    *(float4*)&sbc[idx>>3][(idx&7)*4] = bv;
  }
  __syncthreads();
  #pragma unroll 8
  for (int t=0;t<SEG;t++){
    float dt = sdt[t][dl];
    float uu = su [t][dl];
    float4 q = *(const float4*)&sbc[t][4*j];
    float du = dt*uu;
    h0 = fmaf(exp2f(dt*a0), h0, du*q.x);
    h1 = fmaf(exp2f(dt*a1), h1, du*q.z);
    float p = fmaf(h0, q.y, h1*q.w);
    p += __shfl_xor(p, 1);
    p += __shfl_xor(p, 2);
    p += __shfl_xor(p, 4);
    if (j == 0) sys[t][dl] = p;
  }
  __syncthreads();
  #pragma unroll
  for (int p=0;p<2;p++){
    int r = p*32 + sr;
    float4 zv = *(const float4*)&szs[r][sc];
    float4 o;
    o.x = (sys[r][sc  ] + su[r][sc  ]*D4.x) * siluf(zv.x);
    o.y = (sys[r][sc+1] + su[r][sc+1]*D4.y) * siluf(zv.y);
    o.z = (sys[r][sc+2] + su[r][sc+2]*D4.z) * siluf(zv.z);
    o.w = (sys[r][sc+3] + su[r][sc+3]*D4.w) * siluf(zv.w);
    *(float4*)(xcio + (rowbase + r)*DIN + d0 + sc) = o;
  }
}

// ---------------- masked mean pool over a chunk ----------------
__global__ __launch_bounds__(256) void k_pool1(const float* __restrict__ x,
    const float* __restrict__ mask, float* __restrict__ part, float* __restrict__ pmask){
  int b = blockIdx.y, seg = blockIdx.x;
  int d = threadIdx.x & 127, half = threadIdx.x >> 7;
  int t0 = seg*128 + half*64;
  float acc = 0.f, macc = 0.f;
  for (int i=0;i<64;i++){
    int t = t0 + i;
    float mv = mask[(size_t)b*SL + t];
    acc = fmaf(x[((size_t)b*SL + t)*DMODEL + d], mv, acc);
    macc += mv;
  }
  __shared__ float sm[256];
  __shared__ float smm[2];
  sm[threadIdx.x] = acc;
  if (d == 0) smm[half] = macc;
  __syncthreads();
  if (half == 0){
    part[((size_t)b*16 + seg)*128 + d] = sm[d] + sm[128+d];
    if (d == 0) pmask[b*16 + seg] = smm[0] + smm[1];
  }
}

__global__ void k_pool2(const float* __restrict__ part, const float* __restrict__ pmask,
                        float* __restrict__ pooled){
  int b = blockIdx.x, d = threadIdx.x;
  float acc = 0.f, ms = 0.f;
  for (int s=0;s<16;s++){ acc += part[((size_t)b*16+s)*128 + d]; ms += pmask[b*16+s]; }
  pooled[(size_t)b*128 + d] = acc / fmaxf(ms, 1e-9f);
}

// ---------------- tiny MLP ----------------
__global__ void k_mlp_a(const float* __restrict__ in, const float* __restrict__ w,
                        const float* __restrict__ bias, float* __restrict__ out, int K){
  int b = blockIdx.y;
  int n = blockIdx.x*128 + threadIdx.x;
  const float4* pw = (const float4*)(w + (size_t)n*K);
  const float4* pi = (const float4*)(in + (size_t)b*K);
  float acc = 0.f;
  for (int k=0;k<K/4;k++){
    float4 a = pi[k], ww = pw[k];
    acc = fmaf(a.x,ww.x, fmaf(a.y,ww.y, fmaf(a.z,ww.z, fmaf(a.w,ww.w, acc))));
  }
  out[(size_t)b*512 + n] = fmaxf(acc + bias[n], 0.f);
}

__global__ void k_mlp3(const float* __restrict__ h, const float* __restrict__ w,
                       const float* __restrict__ bias, float* __restrict__ out){
  int b = blockIdx.x;
  int n = threadIdx.x >> 6, lane = threadIdx.x & 63;
  if (n >= 3) return;
  float acc = 0.f;
  for (int k=lane; k<512; k+=64) acc = fmaf(h[(size_t)b*512+k], w[(size_t)n*512+k], acc);
  #pragma unroll
  for (int m=1;m<64;m<<=1) acc += __shfl_xor(acc, m);
  if (lane == 0) out[(size_t)b*3 + n] = acc + bias[n];
}

// ---------------- launch ----------------
extern "C" void kernel_launch(void* const* d_in, const int* in_sizes, int n_in,
                              void* d_out, int out_size, void* d_ws, size_t ws_size,
                              hipStream_t stream){
  const int*   tokens = (const int*)  d_in[0];
  const float* mask   = (const float*)d_in[1];
  const float* emb    = (const float*)d_in[2];
  const float* bn_w   = (const float*)d_in[3];
  const float* bn_b   = (const float*)d_in[4];
  const float* conv_w = (const float*)d_in[5];
  const float* conv_b = (const float*)d_in[6];
  const float* in_w   = (const float*)d_in[7];
  const float* c1_w   = (const float*)d_in[8];
  const float* c1_b   = (const float*)d_in[9];
  const float* xp_w   = (const float*)d_in[10];
  const float* dtp_w  = (const float*)d_in[11];
  const float* dtp_b  = (const float*)d_in[12];
  const float* A_log  = (const float*)d_in[13];
  const float* D_par  = (const float*)d_in[14];
  const float* out_w  = (const float*)d_in[15];
  const float* nrm_w  = (const float*)d_in[16];
  const float* l1w = (const float*)d_in[17]; const float* l1b = (const float*)d_in[18];
  const float* l2w = (const float*)d_in[19]; const float* l2b = (const float*)d_in[20];
  const float* l3w = (const float*)d_in[21]; const float* l3b = (const float*)d_in[22];
  float* dout = (float*)d_out;

  // ---- adaptive chunk size from ws_size (constant across calls) ----
  // per-token floats: x 128 + rs 1 + xi 256 + z 256 + xc 256 + bc 32 + cseg 64 + sdt 4 = 997
  int CB = 64;
  while (CB > 1 && ((size_t)CB*SL*997 + FIX_END)*4 > ws_size) CB >>= 1;
  if (((size_t)CB*SL*997 + FIX_END)*4 > ws_size) return;
  const size_t CTOK = (size_t)CB*SL;

  float* ws  = (float*)d_ws;
  float* w2  = ws + FIX_W2;
  float* pl  = ws + FIX_PL;
  float* pm  = ws + FIX_PM;
  float* pd  = ws + FIX_PD;
  float* h1  = ws + FIX_H1;
  float* h2  = ws + FIX_H2;
  float* wpf = ws + FIX_WP;
  float* xcb = ws + FIX_END;                 // CTOK*128
  float* rs  = xcb + CTOK*128;               // CTOK
  float* xi  = rs  + CTOK;                   // CTOK*256 (embed pad / x-branch / dta)
  float* z   = xi  + CTOK*256;               // CTOK*256
  float* xc  = z   + CTOK*256;               // CTOK*256
  float* bcb = xc  + CTOK*256;               // CTOK*32
  float* csg = bcb + CTOK*32;                // CTOK*64
  float* sdt = csg + CTOK*64;                // CTOK*4

  k_w2<<<192, 256, 0, stream>>>(conv_w, w2);
  k_wprep<<<256, 256, 0, stream>>>(xp_w, wpf);

  const int nchunks = NB / CB;
  for (int c = 0; c < nchunks; c++){
    const int* tok_c = tokens + (size_t)c*CTOK;

    k_embed<<<CB*2050, 128, 0, stream>>>(tok_c, emb, bn_w, bn_b, xi);
    k_gemm<0,384,128><<<dim3(1, CTOK/64), 256, 0, stream>>>(
        xi, w2, conv_b, nullptr, nullptr, xcb, nullptr);

    for (int layer = 0; layer < NLAYER; layer++){
      const float* lin  = in_w  + (size_t)layer*512*128;
      const float* lcw  = c1_w  + (size_t)layer*DIN*4;
      const float* lcb  = c1_b  + (size_t)layer*DIN;
      const float* ldw  = dtp_w + (size_t)layer*DIN*8;
      const float* ldb  = dtp_b + (size_t)layer*DIN;
      const float* lal  = A_log + (size_t)layer*DIN*DST;
      const float* lD   = D_par + (size_t)layer*DIN;
      const float* low  = out_w + (size_t)layer*128*256;
      const float* lnw  = nrm_w + (size_t)layer*128;

      k_rmsscale<<<CTOK/4, 256, 0, stream>>>(xcb, rs);
      k_gemm<1,128,512><<<dim3(4, CTOK/64), 256, 0, stream>>>(
          xcb, lin, nullptr, rs, lnw, xi, z);
      k_dwconv<<<(int)CTOK, 256, 0, stream>>>(xi, lcw, lcb, xc);
      k_xdbl2<<<(int)(CTOK/64), 256, 0, stream>>>(
          xc, wpf + (size_t)layer*64*256, ldw, ldb, xi /*dta*/, bcb);
      k_scanA<<<dim3(NSEG, 8, CB), 256, 0, stream>>>(xi, xc, bcb, lal, csg, sdt);
      k_scanB<<<CB*16, 256, 0, stream>>>(csg, sdt, lal);
      k_scanC<<<dim3(NSEG, 8, CB), 256, 0, stream>>>(xi, xc, bcb, z, lal, lD, csg);
      k_gemm<2,256,128><<<dim3(1, CTOK/64), 256, 0, stream>>>(
          xc, low, nullptr, nullptr, nullptr, xcb, nullptr);
    }

    k_pool1<<<dim3(16, CB), 256, 0, stream>>>(
        xcb, mask + (size_t)c*CTOK, pl + (size_t)c*CB*16*128, pm + (size_t)c*CB*16);
  }

  k_pool2<<<NB, 128, 0, stream>>>(pl, pm, pd);
  k_mlp_a<<<dim3(4, NB), 128, 0, stream>>>(pd, l1w, l1b, h1, 128);
  k_mlp_a<<<dim3(4, NB), 128, 0, stream>>>(h1, l2w, l2b, h2, 512);
  k_mlp3<<<NB, 256, 0, stream>>>(h2, l3w, l3b, dout);
}

// Round 7
// 4620.697 us; speedup vs baseline: 3.8248x; 1.2543x over previous
//
#include <hip/hip_runtime.h>
#include <math.h>

// ---------------- problem constants ----------------
#define NB     64
#define SL     2048
#define NTOK   (NB*SL)
#define EMB_D  128
#define DMODEL 128
#define DIN    256
#define DST    16
#define NLAYER 4
#define SEG    64
#define NSEG   (SL/SEG)        // 32

typedef __bf16 bf16x8 __attribute__((ext_vector_type(8)));
typedef __bf16 bf16x4 __attribute__((ext_vector_type(4)));
typedef float  f32x4  __attribute__((ext_vector_type(4)));

// fixed small region (floats)
#define FIX_PL   ((size_t)0)
#define FIX_PM   (FIX_PL + 131072)
#define FIX_PD   (FIX_PM + 1024)
#define FIX_H1   (FIX_PD + 8192)
#define FIX_H2   (FIX_H1 + 32768)
#define FIX_WP   (FIX_H2 + 32768)          // 4*64*256 x_proj combined (fp32)
#define FIX_W2B  (FIX_WP + 65536)          // 128*384 bf16 front conv w  (24576 floats)
#define FIX_WINB (FIX_W2B + 24576)         // 4*512*128 bf16 in_proj     (131072 floats)
#define FIX_WOUTB (FIX_WINB + 131072)      // 4*128*256 bf16 out_proj    (65536 floats)
#define FIX_END  (FIX_WOUTB + 65536)       // 492,544 floats ~1.97 MB

__device__ __forceinline__ float siluf(float v){ return v / (1.f + expf(-v)); }

// ---------------- weight prep ----------------
// front conv: w2b[d][k*128+e] = bf16(conv_w[d][e][k])
__global__ void k_w2b(const float* __restrict__ cw, __bf16* __restrict__ w2){
  int g = blockIdx.x*256 + threadIdx.x;
  if (g >= 128*384) return;
  int d = g / 384, j = g % 384;
  int k = j >> 7, e = j & 127;
  w2[d*384 + k*128 + e] = (__bf16)cw[d*384 + e*3 + k];
}

__global__ void k_cvt(const float* __restrict__ src, __bf16* __restrict__ dst, int n){
  int i = blockIdx.x*256 + threadIdx.x;
  if (i < n) dst[i] = (__bf16)src[i];
}

// x_proj weight prep: Wp[l][64][256] fp32, bc-interleave baked in
__global__ void k_wprep(const float* __restrict__ xpw, float* __restrict__ wp){
  int g = blockIdx.x*256 + threadIdx.x;      // 65536
  int l = g >> 14, rem = g & 16383;
  int n = rem >> 8, k = rem & 255;
  float v = 0.f;
  if (n < 8){
    v = xpw[(size_t)l*40*256 + n*256 + k];
  } else if (n < 40){
    int i = n - 8;
    int row = 8 + ((i&1)<<4) + (i>>1);
    v = xpw[(size_t)l*40*256 + row*256 + k];
  }
  wp[g] = v;
}

// ---------------- embed + BN into padded chunk buffer ----------------
__global__ void k_embed(const int* __restrict__ tok, const float* __restrict__ emb,
                        const float* __restrict__ bnw, const float* __restrict__ bnb,
                        float* __restrict__ xp){
  int r = blockIdx.x;                 // CB*2050 rows
  int e = threadIdx.x;                // 128
  int b = r / 2050, tp = r % 2050;
  float v = 0.f;
  if (tp != 0 && tp != 2049){
    int t = tp - 1;
    int id = tok[(size_t)b*SL + t];
    float s = bnw[e] * rsqrtf(1.0f + 1e-5f);
    v = emb[(size_t)id*EMB_D + e] * s + bnb[e];
  }
  xp[(size_t)r*EMB_D + e] = v;
}

// ---------------- rmsnorm scale only ----------------
__global__ __launch_bounds__(256) void k_rmsscale(const float* __restrict__ x,
                                                  float* __restrict__ rs){
  int wv = threadIdx.x>>6, lane = threadIdx.x&63;
  size_t tok = (size_t)blockIdx.x*4 + wv;
  float2 v = *(const float2*)(x + tok*128 + lane*2);
  float ss = v.x*v.x + v.y*v.y;
  #pragma unroll
  for (int m=1;m<64;m<<=1) ss += __shfl_xor(ss, m);
  float r = rsqrtf(ss*(1.f/128.f) + 1e-5f);
  if (lane == 0) rs[tok] = r;
}

// ---------------- bf16 MFMA GEMM  out[M,N] = A[M,K] @ W[N,K]^T ----------------
// 128x128 block tile, BK=32, 4 waves (2x2), wave = 64x64 via 4x4 mfma_16x16x32_bf16.
// MODE 0: front conv (A = padded im2col rows), epi relu(+bias) -> out
// MODE 1: in_proj, A staged as x*rs[m]*nw[k]; epi split n<256 -> out(xi) else out2(z)
// MODE 2: out_proj, A = gated y fp32; epi: out += acc (residual)
template<int MODE, int K, int N>
__global__ __launch_bounds__(256) void k_mgemm(
    const float* __restrict__ A, const __bf16* __restrict__ Wb,
    const float* __restrict__ bias, const float* __restrict__ rsp,
    const float* __restrict__ nwp,
    float* __restrict__ out, float* __restrict__ out2){
  __shared__ __bf16 As[128][40];
  __shared__ __bf16 Bs[128][40];
  const int tid  = threadIdx.x;
  const int wave = tid >> 6;
  const int lane = tid & 63;
  const int col  = lane & 15;
  const int quad = lane >> 4;
  const int wm = (wave & 1) * 64;
  const int wn = (wave >> 1) * 64;
  const int m0 = blockIdx.y * 128;
  const int n0 = blockIdx.x * 128;

  f32x4 acc[4][4];
  #pragma unroll
  for (int i=0;i<4;i++)
    #pragma unroll
    for (int j=0;j<4;j++) acc[i][j] = (f32x4){0.f,0.f,0.f,0.f};

  size_t abase;
  if constexpr(MODE==0){
    int bb = m0 >> 11, tloc = m0 & 2047;
    abase = ((size_t)bb*2050 + tloc) * 128;
  } else {
    abase = (size_t)m0 * K;
  }

  const int sm = tid >> 3;          // 0..31 (A staging row in pass)
  const int sk4 = (tid & 7) * 4;    // A staging k group
  const int bn = tid >> 2;          // 0..63 (B staging row in pass)
  const int bk8 = (tid & 3) * 8;    // B staging k group

  for (int k0 = 0; k0 < K; k0 += 32){
    // ---- stage A (128 rows x 32 k), fp32 -> bf16 ----
    #pragma unroll
    for (int p=0;p<4;p++){
      int m = p*32 + sm;
      float4 v;
      if constexpr(MODE==0){
        v = *(const float4*)(A + abase + (size_t)m*128 + k0 + sk4);
      } else if constexpr(MODE==1){
        float4 x4 = *(const float4*)(A + abase + (size_t)m*K + k0 + sk4);
        float4 w4 = *(const float4*)(nwp + k0 + sk4);
        float s = rsp[m0 + m];
        v.x = x4.x*s*w4.x; v.y = x4.y*s*w4.y; v.z = x4.z*s*w4.z; v.w = x4.w*s*w4.w;
      } else {
        v = *(const float4*)(A + abase + (size_t)m*K + k0 + sk4);
      }
      bf16x4 o;
      o[0] = (__bf16)v.x; o[1] = (__bf16)v.y; o[2] = (__bf16)v.z; o[3] = (__bf16)v.w;
      *(bf16x4*)&As[m][sk4] = o;
    }
    // ---- stage B (128 n x 32 k), already bf16 ----
    #pragma unroll
    for (int p=0;p<2;p++){
      int n = p*64 + bn;
      bf16x8 w = *(const bf16x8*)(Wb + (size_t)(n0+n)*K + k0 + bk8);
      *(bf16x8*)&Bs[n][bk8] = w;
    }
    __syncthreads();
    // ---- frags + mfma ----
    bf16x8 af[4], bfr[4];
    const int fq = quad*8;
    #pragma unroll
    for (int i=0;i<4;i++) af[i]  = *(const bf16x8*)&As[wm + i*16 + col][fq];
    #pragma unroll
    for (int j=0;j<4;j++) bfr[j] = *(const bf16x8*)&Bs[wn + j*16 + col][fq];
    #pragma unroll
    for (int i=0;i<4;i++)
      #pragma unroll
      for (int j=0;j<4;j++)
        acc[i][j] = __builtin_amdgcn_mfma_f32_16x16x32_bf16(af[i], bfr[j], acc[i][j], 0, 0, 0);
    __syncthreads();
  }

  // ---- epilogue: C/D layout col=lane&15, row=quad*4+reg ----
  #pragma unroll
  for (int i=0;i<4;i++){
    #pragma unroll
    for (int j=0;j<4;j++){
      int n_l = wn + j*16 + col;
      #pragma unroll
      for (int r=0;r<4;r++){
        int m = m0 + wm + i*16 + quad*4 + r;
        float c = acc[i][j][r];
        if constexpr(MODE==0){
          int n = n0 + n_l;
          out[(size_t)m*DMODEL + n] = fmaxf(c + bias[n], 0.f);
        } else if constexpr(MODE==1){
          int n = n0 + n_l;
          if (n < DIN) out [(size_t)m*DIN + n]       = c;
          else         out2[(size_t)m*DIN + n - DIN] = c;
        } else {
          float* p = out + (size_t)m*DMODEL + n0 + n_l;
          *p = *p + c;
        }
      }
    }
  }
}

// ---------------- depthwise causal conv (k=4) + silu ----------------
__global__ __launch_bounds__(256) void k_dwconv(const float* __restrict__ xi,
    const float* __restrict__ w, const float* __restrict__ cb, float* __restrict__ xc){
  int m = blockIdx.x;  int d = threadIdx.x;
  int t = m & 2047;
  const float* wd = w + d*4;
  float acc = cb[d];
  const float* base = xi + (size_t)m*DIN + d;
  if (t>=3) acc = fmaf(wd[0], base[-3*DIN], acc);
  if (t>=2) acc = fmaf(wd[1], base[-2*DIN], acc);
  if (t>=1) acc = fmaf(wd[2], base[-1*DIN], acc);
  acc = fmaf(wd[3], base[0], acc);
  xc[(size_t)m*DIN + d] = siluf(acc);
}

// ---------------- fused x_proj GEMM + dt_proj(+softplus) + bc copy ----------------
__global__ __launch_bounds__(256) void k_xdbl2(const float* __restrict__ xc,
    const float* __restrict__ wp, const float* __restrict__ dtw,
    const float* __restrict__ dtb, float* __restrict__ dta, float* __restrict__ bc){
  __shared__ float As[32][68];
  __shared__ float Bs[32][68];
  __shared__ float vls[64][68];
  __shared__ float sdtw[256][8];
  __shared__ float sdtb[256];
  const int tid = threadIdx.x;
  const size_t m0 = (size_t)blockIdx.x * 64;
  const int row0 = (tid>>4)*4;
  const int col0 = (tid&15)*4;
  float acc[4][4];
  #pragma unroll
  for (int i=0;i<4;i++)
    #pragma unroll
    for (int j=0;j<4;j++) acc[i][j]=0.f;

  {
    const float4* src = (const float4*)dtw;
    float4 v0 = src[tid], v1 = src[tid+256];
    *(float4*)&sdtw[tid>>1][(tid&1)*4] = v0;
    *(float4*)&sdtw[(tid+256)>>1][(tid&1)*4] = v1;
    sdtb[tid] = dtb[tid];
  }

  for (int k0 = 0; k0 < 256; k0 += 32){
    #pragma unroll
    for (int i=0;i<2;i++){
      int idx = tid + i*256;
      int m = idx>>3, kq = idx&7;
      int kk = kq*4;
      float4 va = *(const float4*)(xc + (m0+m)*DIN + k0 + kk);
      As[kk  ][m]=va.x; As[kk+1][m]=va.y; As[kk+2][m]=va.z; As[kk+3][m]=va.w;
      float4 vb = *(const float4*)(wp + (size_t)m*256 + k0 + kk);
      Bs[kk  ][m]=vb.x; Bs[kk+1][m]=vb.y; Bs[kk+2][m]=vb.z; Bs[kk+3][m]=vb.w;
    }
    __syncthreads();
    #pragma unroll
    for (int k=0;k<32;k++){
      float4 a = *(const float4*)&As[k][row0];
      float4 b = *(const float4*)&Bs[k][col0];
      float av[4]={a.x,a.y,a.z,a.w}, bv[4]={b.x,b.y,b.z,b.w};
      #pragma unroll
      for (int i=0;i<4;i++)
        #pragma unroll
        for (int j=0;j<4;j++) acc[i][j] = fmaf(av[i], bv[j], acc[i][j]);
    }
    __syncthreads();
  }

  #pragma unroll
  for (int i=0;i<4;i++)
    #pragma unroll
    for (int j=0;j<4;j++) vls[row0+i][col0+j] = acc[i][j];
  __syncthreads();

  #pragma unroll
  for (int p=0;p<8;p++){
    int j = tid + p*256;
    int tok = j>>5, i = j&31;
    bc[(m0+tok)*32 + i] = vls[tok][8+i];
  }

  {
    const int tok = tid>>2, dq = tid&3;
    float4 v0 = *(const float4*)&vls[tok][0];
    float4 v1 = *(const float4*)&vls[tok][4];
    float* drow = dta + (m0+tok)*DIN;
    #pragma unroll 4
    for (int i=0;i<64;i++){
      int d = 4*i + dq;
      float4 w0 = *(const float4*)&sdtw[d][0];
      float4 w1 = *(const float4*)&sdtw[d][4];
      float a = sdtb[d];
      a = fmaf(v0.x,w0.x, fmaf(v0.y,w0.y, fmaf(v0.z,w0.z, fmaf(v0.w,w0.w, a))));
      a = fmaf(v1.x,w1.x, fmaf(v1.y,w1.y, fmaf(v1.z,w1.z, fmaf(v1.w,w1.w, a))));
      float dt = (a > 0.f) ? (a + log1pf(expf(-a))) : log1pf(expf(a));
      drow[d] = dt;
    }
  }
}

// ======== segment-parallel selective scan ========
__global__ __launch_bounds__(256) void k_scanA(const float* __restrict__ dta,
    const float* __restrict__ u_, const float* __restrict__ bc,
    const float* __restrict__ alog, float* __restrict__ cseg, float* __restrict__ sdtb){
  __shared__ float sdt[SEG][33];
  __shared__ float su [SEG][33];
  __shared__ float sbc[SEG][36];
  const int tid = threadIdx.x;
  const int g = blockIdx.x, dg = blockIdx.y, b = blockIdx.z;
  const int j = tid & 7, dl = tid >> 3;
  const int d0 = dg << 5, d = d0 + dl;
  const float LOG2E = 1.4426950408889634f;
  const float a0 = -expf(alog[d*DST + 2*j    ]) * LOG2E;
  const float a1 = -expf(alog[d*DST + 2*j + 1]) * LOG2E;
  const int sr = tid >> 3, sc = (tid & 7) * 4;
  const size_t rowbase = (size_t)b*SL + (size_t)g*SEG;
  #pragma unroll
  for (int p=0;p<2;p++){
    int r = p*32 + sr;
    size_t go = (rowbase + r)*DIN + d0 + sc;
    float4 dv = *(const float4*)(dta + go);
    float4 uv = *(const float4*)(u_  + go);
    sdt[r][sc]=dv.x; sdt[r][sc+1]=dv.y; sdt[r][sc+2]=dv.z; sdt[r][sc+3]=dv.w;
    su [r][sc]=uv.x; su [r][sc+1]=uv.y; su [r][sc+2]=uv.z; su [r][sc+3]=uv.w;
  }
  #pragma unroll
  for (int p=0;p<2;p++){
    int idx = p*256 + tid;
    float4 bv = *(const float4*)(bc + rowbase*32 + (size_t)idx*4);
    *(float4*)&sbc[idx>>3][(idx&7)*4] = bv;
  }
  __syncthreads();
  float h0 = 0.f, h1 = 0.f, ssum = 0.f;
  #pragma unroll 8
  for (int t=0;t<SEG;t++){
    float dt = sdt[t][dl];
    float uu = su [t][dl];
    float4 q = *(const float4*)&sbc[t][4*j];
    float du = dt*uu;
    h0 = fmaf(exp2f(dt*a0), h0, du*q.x);
    h1 = fmaf(exp2f(dt*a1), h1, du*q.z);
    ssum += dt;
  }
  size_t cb = (((size_t)b*NSEG + g)*DIN + d)*DST;
  cseg[cb + 2*j    ] = h0;
  cseg[cb + 2*j + 1] = h1;
  if (j == 0) sdtb[((size_t)b*NSEG + g)*DIN + d] = ssum;
}

__global__ __launch_bounds__(256) void k_scanB(float* __restrict__ cseg,
    const float* __restrict__ sdtb, const float* __restrict__ alog){
  int gl = blockIdx.x*256 + threadIdx.x;
  int b   = gl >> 12;
  int rem = gl & 4095;
  int d = rem >> 4, s = rem & 15;
  const float LOG2E = 1.4426950408889634f;
  const float a = -expf(alog[d*DST + s]) * LOG2E;
  float h = 0.f;
  for (int g=0; g<NSEG; g++){
    size_t base = ((size_t)b*NSEG + g)*DIN;
    float sd = sdtb[base + d];
    size_t ci = (base + d)*DST + s;
    float c = cseg[ci];
    cseg[ci] = h;
    h = fmaf(exp2f(a*sd), h, c);
  }
}

__global__ __launch_bounds__(256) void k_scanC(const float* __restrict__ dta,
    float* xcio, const float* __restrict__ bc, const float* __restrict__ z,
    const float* __restrict__ alog, const float* __restrict__ Dpar,
    const float* __restrict__ cseg){
  __shared__ float sdt[SEG][33];
  __shared__ float su [SEG][33];
  __shared__ float sbc[SEG][36];
  __shared__ float szs[SEG][36];
  __shared__ float sys[SEG][33];
  const int tid = threadIdx.x;
  const int g = blockIdx.x, dg = blockIdx.y, b = blockIdx.z;
  const int j = tid & 7, dl = tid >> 3;
  const int d0 = dg << 5, d = d0 + dl;
  const float LOG2E = 1.4426950408889634f;
  const float a0 = -expf(alog[d*DST + 2*j    ]) * LOG2E;
  const float a1 = -expf(alog[d*DST + 2*j + 1]) * LOG2E;
  const int sr = tid >> 3, sc = (tid & 7) * 4;
  const float4 D4 = *(const float4*)(Dpar + d0 + sc);
  const size_t rowbase = (size_t)b*SL + (size_t)g*SEG;
  size_t cb = (((size_t)b*NSEG + g)*DIN + d)*DST;
  float h0 = cseg[cb + 2*j];
  float h1 = cseg[cb + 2*j + 1];
  #pragma unroll
  for (int p=0;p<2;p++){
    int r = p*32 + sr;
    size_t go = (rowbase + r)*DIN + d0 + sc;
    float4 dv = *(const float4*)(dta  + go);
    float4 uv = *(const float4*)(xcio + go);
    float4 zv = *(const float4*)(z    + go);
    sdt[r][sc]=dv.x; sdt[r][sc+1]=dv.y; sdt[r][sc+2]=dv.z; sdt[r][sc+3]=dv.w;
    su [r][sc]=uv.x; su [r][sc+1]=uv.y; su [r][sc+2]=uv.z; su [r][sc+3]=uv.w;
    *(float4*)&szs[r][sc] = zv;
  }
  #pragma unroll
  for (int p=0;p<2;p++){
    int idx = p*256 + tid;
    float4 bv = *(const float4*)(bc + rowbase*32 + (size_t)idx*4);
    *(float4*)&sbc[idx>>3][(idx&7)*4] = bv;
  }
  __syncthreads();
  #pragma unroll 8
  for (int t=0;t<SEG;t++){
    float dt = sdt[t][dl];
    float uu = su [t][dl];
    float4 q = *(const float4*)&sbc[t][4*j];
    float du = dt*uu;
    h0 = fmaf(exp2f(dt*a0), h0, du*q.x);
    h1 = fmaf(exp2f(dt*a1), h1, du*q.z);
    float p = fmaf(h0, q.y, h1*q.w);
    p += __shfl_xor(p, 1);
    p += __shfl_xor(p, 2);
    p += __shfl_xor(p, 4);
    if (j == 0) sys[t][dl] = p;
  }
  __syncthreads();
  #pragma unroll
  for (int p=0;p<2;p++){
    int r = p*32 + sr;
    float4 zv = *(const float4*)&szs[r][sc];
    float4 o;
    o.x = (sys[r][sc  ] + su[r][sc  ]*D4.x) * siluf(zv.x);
    o.y = (sys[r][sc+1] + su[r][sc+1]*D4.y) * siluf(zv.y);
    o.z = (sys[r][sc+2] + su[r][sc+2]*D4.z) * siluf(zv.z);
    o.w = (sys[r][sc+3] + su[r][sc+3]*D4.w) * siluf(zv.w);
    *(float4*)(xcio + (rowbase + r)*DIN + d0 + sc) = o;
  }
}

// ---------------- masked mean pool over a chunk ----------------
__global__ __launch_bounds__(256) void k_pool1(const float* __restrict__ x,
    const float* __restrict__ mask, float* __restrict__ part, float* __restrict__ pmask){
  int b = blockIdx.y, seg = blockIdx.x;
  int d = threadIdx.x & 127, half = threadIdx.x >> 7;
  int t0 = seg*128 + half*64;
  float acc = 0.f, macc = 0.f;
  for (int i=0;i<64;i++){
    int t = t0 + i;
    float mv = mask[(size_t)b*SL + t];
    acc = fmaf(x[((size_t)b*SL + t)*DMODEL + d], mv, acc);
    macc += mv;
  }
  __shared__ float sm[256];
  __shared__ float smm[2];
  sm[threadIdx.x] = acc;
  if (d == 0) smm[half] = macc;
  __syncthreads();
  if (half == 0){
    part[((size_t)b*16 + seg)*128 + d] = sm[d] + sm[128+d];
    if (d == 0) pmask[b*16 + seg] = smm[0] + smm[1];
  }
}

__global__ void k_pool2(const float* __restrict__ part, const float* __restrict__ pmask,
                        float* __restrict__ pooled){
  int b = blockIdx.x, d = threadIdx.x;
  float acc = 0.f, ms = 0.f;
  for (int s=0;s<16;s++){ acc += part[((size_t)b*16+s)*128 + d]; ms += pmask[b*16+s]; }
  pooled[(size_t)b*128 + d] = acc / fmaxf(ms, 1e-9f);
}

// ---------------- tiny MLP ----------------
__global__ void k_mlp_a(const float* __restrict__ in, const float* __restrict__ w,
                        const float* __restrict__ bias, float* __restrict__ out, int K){
  int b = blockIdx.y;
  int n = blockIdx.x*128 + threadIdx.x;
  const float4* pw = (const float4*)(w + (size_t)n*K);
  const float4* pi = (const float4*)(in + (size_t)b*K);
  float acc = 0.f;
  for (int k=0;k<K/4;k++){
    float4 a = pi[k], ww = pw[k];
    acc = fmaf(a.x,ww.x, fmaf(a.y,ww.y, fmaf(a.z,ww.z, fmaf(a.w,ww.w, acc))));
  }
  out[(size_t)b*512 + n] = fmaxf(acc + bias[n], 0.f);
}

__global__ void k_mlp3(const float* __restrict__ h, const float* __restrict__ w,
                       const float* __restrict__ bias, float* __restrict__ out){
  int b = blockIdx.x;
  int n = threadIdx.x >> 6, lane = threadIdx.x & 63;
  if (n >= 3) return;
  float acc = 0.f;
  for (int k=lane; k<512; k+=64) acc = fmaf(h[(size_t)b*512+k], w[(size_t)n*512+k], acc);
  #pragma unroll
  for (int m=1;m<64;m<<=1) acc += __shfl_xor(acc, m);
  if (lane == 0) out[(size_t)b*3 + n] = acc + bias[n];
}

// ---------------- launch ----------------
extern "C" void kernel_launch(void* const* d_in, const int* in_sizes, int n_in,
                              void* d_out, int out_size, void* d_ws, size_t ws_size,
                              hipStream_t stream){
  const int*   tokens = (const int*)  d_in[0];
  const float* mask   = (const float*)d_in[1];
  const float* emb    = (const float*)d_in[2];
  const float* bn_w   = (const float*)d_in[3];
  const float* bn_b   = (const float*)d_in[4];
  const float* conv_w = (const float*)d_in[5];
  const float* conv_b = (const float*)d_in[6];
  const float* in_w   = (const float*)d_in[7];
  const float* c1_w   = (const float*)d_in[8];
  const float* c1_b   = (const float*)d_in[9];
  const float* xp_w   = (const float*)d_in[10];
  const float* dtp_w  = (const float*)d_in[11];
  const float* dtp_b  = (const float*)d_in[12];
  const float* A_log  = (const float*)d_in[13];
  const float* D_par  = (const float*)d_in[14];
  const float* out_w  = (const float*)d_in[15];
  const float* nrm_w  = (const float*)d_in[16];
  const float* l1w = (const float*)d_in[17]; const float* l1b = (const float*)d_in[18];
  const float* l2w = (const float*)d_in[19]; const float* l2b = (const float*)d_in[20];
  const float* l3w = (const float*)d_in[21]; const float* l3b = (const float*)d_in[22];
  float* dout = (float*)d_out;

  // per-token floats: x 128 + rs 1 + xi 256 + z 256 + xc 256 + bc 32 + cseg 64 + sdt 4 = 997
  int CB = 64;
  while (CB > 1 && ((size_t)CB*SL*997 + FIX_END)*4 > ws_size) CB >>= 1;
  if (((size_t)CB*SL*997 + FIX_END)*4 > ws_size) return;
  const size_t CTOK = (size_t)CB*SL;

  float* ws  = (float*)d_ws;
  float* pl  = ws + FIX_PL;
  float* pm  = ws + FIX_PM;
  float* pd  = ws + FIX_PD;
  float* h1  = ws + FIX_H1;
  float* h2  = ws + FIX_H2;
  float* wpf = ws + FIX_WP;
  __bf16* w2b   = (__bf16*)(ws + FIX_W2B);
  __bf16* winb  = (__bf16*)(ws + FIX_WINB);
  __bf16* woutb = (__bf16*)(ws + FIX_WOUTB);
  float* xcb = ws + FIX_END;                 // CTOK*128
  float* rs  = xcb + CTOK*128;               // CTOK
  float* xi  = rs  + CTOK;                   // CTOK*256 (embed pad / x-branch / dta)
  float* z   = xi  + CTOK*256;               // CTOK*256
  float* xc  = z   + CTOK*256;               // CTOK*256
  float* bcb = xc  + CTOK*256;               // CTOK*32
  float* csg = bcb + CTOK*32;                // CTOK*64
  float* sdt = csg + CTOK*64;                // CTOK*4

  k_w2b<<<192, 256, 0, stream>>>(conv_w, w2b);
  k_cvt<<<1024, 256, 0, stream>>>(in_w,  winb,  4*512*128);
  k_cvt<<<512,  256, 0, stream>>>(out_w, woutb, 4*128*256);
  k_wprep<<<256, 256, 0, stream>>>(xp_w, wpf);

  const int nchunks = NB / CB;
  for (int c = 0; c < nchunks; c++){
    const int* tok_c = tokens + (size_t)c*CTOK;

    k_embed<<<CB*2050, 128, 0, stream>>>(tok_c, emb, bn_w, bn_b, xi);
    k_mgemm<0,384,128><<<dim3(1, CTOK/128), 256, 0, stream>>>(
        xi, w2b, conv_b, nullptr, nullptr, xcb, nullptr);

    for (int layer = 0; layer < NLAYER; layer++){
      const __bf16* lin  = winb  + (size_t)layer*512*128;
      const float* lcw  = c1_w  + (size_t)layer*DIN*4;
      const float* lcb  = c1_b  + (size_t)layer*DIN;
      const float* ldw  = dtp_w + (size_t)layer*DIN*8;
      const float* ldb  = dtp_b + (size_t)layer*DIN;
      const float* lal  = A_log + (size_t)layer*DIN*DST;
      const float* lD   = D_par + (size_t)layer*DIN;
      const __bf16* low  = woutb + (size_t)layer*128*256;
      const float* lnw  = nrm_w + (size_t)layer*128;

      k_rmsscale<<<CTOK/4, 256, 0, stream>>>(xcb, rs);
      k_mgemm<1,128,512><<<dim3(4, CTOK/128), 256, 0, stream>>>(
          xcb, lin, nullptr, rs, lnw, xi, z);
      k_dwconv<<<(int)CTOK, 256, 0, stream>>>(xi, lcw, lcb, xc);
      k_xdbl2<<<(int)(CTOK/64), 256, 0, stream>>>(
          xc, wpf + (size_t)layer*64*256, ldw, ldb, xi /*dta*/, bcb);
      k_scanA<<<dim3(NSEG, 8, CB), 256, 0, stream>>>(xi, xc, bcb, lal, csg, sdt);
      k_scanB<<<CB*16, 256, 0, stream>>>(csg, sdt, lal);
      k_scanC<<<dim3(NSEG, 8, CB), 256, 0, stream>>>(xi, xc, bcb, z, lal, lD, csg);
      k_mgemm<2,256,128><<<dim3(1, CTOK/128), 256, 0, stream>>>(
          xc, low, nullptr, nullptr, nullptr, xcb, nullptr);
    }

    k_pool1<<<dim3(16, CB), 256, 0, stream>>>(
        xcb, mask + (size_t)c*CTOK, pl + (size_t)c*CB*16*128, pm + (size_t)c*CB*16);
  }

  k_pool2<<<NB, 128, 0, stream>>>(pl, pm, pd);
  k_mlp_a<<<dim3(4, NB), 128, 0, stream>>>(pd, l1w, l1b, h1, 128);
  k_mlp_a<<<dim3(4, NB), 128, 0, stream>>>(h1, l2w, l2b, h2, 512);
  k_mlp3<<<NB, 256, 0, stream>>>(h2, l3w, l3b, dout);
}

// Round 8
// 4537.436 us; speedup vs baseline: 3.8950x; 1.0183x over previous
//
#include <hip/hip_runtime.h>
#include <math.h>

// ---------------- problem constants ----------------
#define NB     64
#define SL     2048
#define NTOK   (NB*SL)
#define EMB_D  128
#define DMODEL 128
#define DIN    256
#define DST    16
#define NLAYER 4
#define SEG    64
#define NSEG   (SL/SEG)        // 32

typedef __bf16 bf16x8 __attribute__((ext_vector_type(8)));
typedef __bf16 bf16x4 __attribute__((ext_vector_type(4)));
typedef float  f32x4  __attribute__((ext_vector_type(4)));

// fixed small region (floats)
#define FIX_PL   ((size_t)0)
#define FIX_PM   (FIX_PL + 131072)
#define FIX_PD   (FIX_PM + 1024)
#define FIX_H1   (FIX_PD + 8192)
#define FIX_H2   (FIX_H1 + 32768)
#define FIX_WP   (FIX_H2 + 32768)          // 4*64*256 x_proj combined (fp32)
#define FIX_W2B  (FIX_WP + 65536)          // 128*384 bf16 front conv w
#define FIX_WINB (FIX_W2B + 24576)         // 4*512*128 bf16 in_proj
#define FIX_WOUTB (FIX_WINB + 131072)      // 4*128*256 bf16 out_proj
#define FIX_END  (FIX_WOUTB + 65536)

__device__ __forceinline__ float siluf(float v){ return v / (1.f + expf(-v)); }
__device__ __forceinline__ float softplusf(float a){
  return (a > 0.f) ? (a + log1pf(expf(-a))) : log1pf(expf(a));
}

// ---------------- weight prep ----------------
__global__ void k_w2b(const float* __restrict__ cw, __bf16* __restrict__ w2){
  int g = blockIdx.x*256 + threadIdx.x;
  if (g >= 128*384) return;
  int d = g / 384, j = g % 384;
  int k = j >> 7, e = j & 127;
  w2[d*384 + k*128 + e] = (__bf16)cw[d*384 + e*3 + k];
}

__global__ void k_cvt(const float* __restrict__ src, __bf16* __restrict__ dst, int n){
  int i = blockIdx.x*256 + threadIdx.x;
  if (i < n) dst[i] = (__bf16)src[i];
}

// x_proj weight prep: Wp[l][64][256] fp32, bc-interleave baked in
__global__ void k_wprep(const float* __restrict__ xpw, float* __restrict__ wp){
  int g = blockIdx.x*256 + threadIdx.x;      // 65536
  int l = g >> 14, rem = g & 16383;
  int n = rem >> 8, k = rem & 255;
  float v = 0.f;
  if (n < 8){
    v = xpw[(size_t)l*40*256 + n*256 + k];
  } else if (n < 40){
    int i = n - 8;
    int row = 8 + ((i&1)<<4) + (i>>1);
    v = xpw[(size_t)l*40*256 + row*256 + k];
  }
  wp[g] = v;
}

// ---------------- embed + BN into padded chunk buffer ----------------
__global__ void k_embed(const int* __restrict__ tok, const float* __restrict__ emb,
                        const float* __restrict__ bnw, const float* __restrict__ bnb,
                        float* __restrict__ xp){
  int r = blockIdx.x;                 // CB*2050 rows
  int e = threadIdx.x;                // 128
  int b = r / 2050, tp = r % 2050;
  float v = 0.f;
  if (tp != 0 && tp != 2049){
    int t = tp - 1;
    int id = tok[(size_t)b*SL + t];
    float s = bnw[e] * rsqrtf(1.0f + 1e-5f);
    v = emb[(size_t)id*EMB_D + e] * s + bnb[e];
  }
  xp[(size_t)r*EMB_D + e] = v;
}

// ---------------- rmsnorm scale only ----------------
__global__ __launch_bounds__(256) void k_rmsscale(const float* __restrict__ x,
                                                  float* __restrict__ rs){
  int wv = threadIdx.x>>6, lane = threadIdx.x&63;
  size_t tok = (size_t)blockIdx.x*4 + wv;
  float2 v = *(const float2*)(x + tok*128 + lane*2);
  float ss = v.x*v.x + v.y*v.y;
  #pragma unroll
  for (int m=1;m<64;m<<=1) ss += __shfl_xor(ss, m);
  float r = rsqrtf(ss*(1.f/128.f) + 1e-5f);
  if (lane == 0) rs[tok] = r;
}

// ---------------- bf16 MFMA GEMM  out[M,N] = A[M,K] @ W[N,K]^T ----------------
// MODE 0: front conv (A = padded im2col rows), epi relu(+bias)
// MODE 1: in_proj, A staged as x*rs[m]*nw[k]; epi split n<256 -> out(xi) else outz(z bf16)
// MODE 2: out_proj, A = gated y fp32; epi: out += acc (residual)
template<int MODE, int K, int N>
__global__ __launch_bounds__(256) void k_mgemm(
    const float* __restrict__ A, const __bf16* __restrict__ Wb,
    const float* __restrict__ bias, const float* __restrict__ rsp,
    const float* __restrict__ nwp,
    float* __restrict__ out, __bf16* __restrict__ outz){
  __shared__ __bf16 As[128][40];
  __shared__ __bf16 Bs[128][40];
  const int tid  = threadIdx.x;
  const int wave = tid >> 6;
  const int lane = tid & 63;
  const int col  = lane & 15;
  const int quad = lane >> 4;
  const int wm = (wave & 1) * 64;
  const int wn = (wave >> 1) * 64;
  const int m0 = blockIdx.y * 128;
  const int n0 = blockIdx.x * 128;

  f32x4 acc[4][4];
  #pragma unroll
  for (int i=0;i<4;i++)
    #pragma unroll
    for (int j=0;j<4;j++) acc[i][j] = (f32x4){0.f,0.f,0.f,0.f};

  size_t abase;
  if constexpr(MODE==0){
    int bb = m0 >> 11, tloc = m0 & 2047;
    abase = ((size_t)bb*2050 + tloc) * 128;
  } else {
    abase = (size_t)m0 * K;
  }

  const int sm = tid >> 3;
  const int sk4 = (tid & 7) * 4;
  const int bn = tid >> 2;
  const int bk8 = (tid & 3) * 8;

  for (int k0 = 0; k0 < K; k0 += 32){
    #pragma unroll
    for (int p=0;p<4;p++){
      int m = p*32 + sm;
      float4 v;
      if constexpr(MODE==0){
        v = *(const float4*)(A + abase + (size_t)m*128 + k0 + sk4);
      } else if constexpr(MODE==1){
        float4 x4 = *(const float4*)(A + abase + (size_t)m*K + k0 + sk4);
        float4 w4 = *(const float4*)(nwp + k0 + sk4);
        float s = rsp[m0 + m];
        v.x = x4.x*s*w4.x; v.y = x4.y*s*w4.y; v.z = x4.z*s*w4.z; v.w = x4.w*s*w4.w;
      } else {
        v = *(const float4*)(A + abase + (size_t)m*K + k0 + sk4);
      }
      bf16x4 o;
      o[0] = (__bf16)v.x; o[1] = (__bf16)v.y; o[2] = (__bf16)v.z; o[3] = (__bf16)v.w;
      *(bf16x4*)&As[m][sk4] = o;
    }
    #pragma unroll
    for (int p=0;p<2;p++){
      int n = p*64 + bn;
      bf16x8 w = *(const bf16x8*)(Wb + (size_t)(n0+n)*K + k0 + bk8);
      *(bf16x8*)&Bs[n][bk8] = w;
    }
    __syncthreads();
    bf16x8 af[4], bfr[4];
    const int fq = quad*8;
    #pragma unroll
    for (int i=0;i<4;i++) af[i]  = *(const bf16x8*)&As[wm + i*16 + col][fq];
    #pragma unroll
    for (int j=0;j<4;j++) bfr[j] = *(const bf16x8*)&Bs[wn + j*16 + col][fq];
    #pragma unroll
    for (int i=0;i<4;i++)
      #pragma unroll
      for (int j=0;j<4;j++)
        acc[i][j] = __builtin_amdgcn_mfma_f32_16x16x32_bf16(af[i], bfr[j], acc[i][j], 0, 0, 0);
    __syncthreads();
  }

  #pragma unroll
  for (int i=0;i<4;i++){
    #pragma unroll
    for (int j=0;j<4;j++){
      int n_l = wn + j*16 + col;
      #pragma unroll
      for (int r=0;r<4;r++){
        int m = m0 + wm + i*16 + quad*4 + r;
        float c = acc[i][j][r];
        if constexpr(MODE==0){
          int n = n0 + n_l;
          out[(size_t)m*DMODEL + n] = fmaxf(c + bias[n], 0.f);
        } else if constexpr(MODE==1){
          int n = n0 + n_l;
          if (n < DIN) out [(size_t)m*DIN + n]        = c;
          else         outz[(size_t)m*DIN + n - DIN]  = (__bf16)c;
        } else {
          float* p = out + (size_t)m*DMODEL + n0 + n_l;
          *p = *p + c;
        }
      }
    }
  }
}

// ---------------- fused segment front: dwconv+silu -> x_proj GEMM -> vbc -> scanA summary
// One block = 64-token segment. Threads 256.
__global__ __launch_bounds__(256) void k_seg(const float* __restrict__ xi,
    float* __restrict__ xcg, const float* __restrict__ wp,
    const float* __restrict__ cw, const float* __restrict__ cb,
    const float* __restrict__ dtw, const float* __restrict__ dtb,
    const float* __restrict__ alog,
    float* __restrict__ vbc, float* __restrict__ cseg, float* __restrict__ sdtb){
  __shared__ float As[32][68];
  __shared__ float Bs[32][68];
  __shared__ float vls[64][68];
  const int tid = threadIdx.x;
  const size_t m0 = (size_t)blockIdx.x * 64;
  const int b = (int)(m0 >> 11);
  const int g = (int)((m0 >> 6) & (NSEG-1));
  const int seq0 = (int)(m0 & 2047);

  // ---- phase 0: depthwise conv(k=4) + silu, write xc ----
  {
    const int c4 = (tid & 63) * 4;
    const int tw = tid >> 6;
    float wc[4][4];
    #pragma unroll
    for (int j=0;j<4;j++)
      #pragma unroll
      for (int k=0;k<4;k++) wc[j][k] = cw[(c4+j)*4 + k];
    float4 cb4 = *(const float4*)(cb + c4);
    #pragma unroll
    for (int it=0; it<16; it++){
      int t = it*4 + tw;
      float4 acc = cb4;
      #pragma unroll
      for (int k=0;k<4;k++){
        if (seq0 + t - 3 + k >= 0){
          float4 xv = *(const float4*)(xi + (m0 + t - 3 + k)*DIN + c4);
          acc.x = fmaf(wc[0][k], xv.x, acc.x);
          acc.y = fmaf(wc[1][k], xv.y, acc.y);
          acc.z = fmaf(wc[2][k], xv.z, acc.z);
          acc.w = fmaf(wc[3][k], xv.w, acc.w);
        }
      }
      acc.x = siluf(acc.x); acc.y = siluf(acc.y);
      acc.z = siluf(acc.z); acc.w = siluf(acc.w);
      *(float4*)(xcg + (m0 + t)*DIN + c4) = acc;
    }
  }
  __syncthreads();   // drains vmcnt -> xc visible in L2 to whole block

  // ---- phase 1: GEMM vls[64][64] = xc[64x256] @ Wp[64x256]^T ----
  {
    const int row0 = (tid>>4)*4;
    const int col0 = (tid&15)*4;
    float acc[4][4];
    #pragma unroll
    for (int i=0;i<4;i++)
      #pragma unroll
      for (int j=0;j<4;j++) acc[i][j]=0.f;
    for (int k0 = 0; k0 < 256; k0 += 32){
      #pragma unroll
      for (int i=0;i<2;i++){
        int idx = tid + i*256;
        int m = idx>>3, kq = idx&7;
        int kk = kq*4;
        float4 va = *(const float4*)(xcg + (m0+m)*DIN + k0 + kk);
        As[kk  ][m]=va.x; As[kk+1][m]=va.y; As[kk+2][m]=va.z; As[kk+3][m]=va.w;
        float4 vb = *(const float4*)(wp + (size_t)m*256 + k0 + kk);
        Bs[kk  ][m]=vb.x; Bs[kk+1][m]=vb.y; Bs[kk+2][m]=vb.z; Bs[kk+3][m]=vb.w;
      }
      __syncthreads();
      #pragma unroll
      for (int k=0;k<32;k++){
        float4 a = *(const float4*)&As[k][row0];
        float4 bq = *(const float4*)&Bs[k][col0];
        float av[4]={a.x,a.y,a.z,a.w}, bv[4]={bq.x,bq.y,bq.z,bq.w};
        #pragma unroll
        for (int i=0;i<4;i++)
          #pragma unroll
          for (int j=0;j<4;j++) acc[i][j] = fmaf(av[i], bv[j], acc[i][j]);
      }
      __syncthreads();
    }
    #pragma unroll
    for (int i=0;i<4;i++)
      #pragma unroll
      for (int j=0;j<4;j++) vls[row0+i][col0+j] = acc[i][j];
  }
  __syncthreads();

  // ---- phase 2: write vbc[t][40] = vls[t][0..39] ----
  #pragma unroll
  for (int p=0;p<10;p++){
    int j = p*256 + tid;
    int t = j / 40, i = j - t*40;
    if (j < 2560) vbc[(m0+t)*40 + i] = vls[t][i];
  }

  // ---- phase 3: scanA summary, thread = channel, 16 states ----
  {
    const int d = tid;
    const float LOG2E = 1.4426950408889634f;
    float a[16];
    #pragma unroll
    for (int s=0;s<16;s++) a[s] = -expf(alog[d*DST + s]) * LOG2E;
    float w8[8];
    #pragma unroll
    for (int i=0;i<8;i++) w8[i] = dtw[d*8 + i];
    const float bd = dtb[d];
    float h[16];
    #pragma unroll
    for (int s=0;s<16;s++) h[s] = 0.f;
    float ssum = 0.f;
    for (int t=0;t<SEG;t++){
      float4 v0 = *(const float4*)&vls[t][0];
      float4 v1 = *(const float4*)&vls[t][4];
      float lin = bd;
      lin = fmaf(v0.x,w8[0], fmaf(v0.y,w8[1], fmaf(v0.z,w8[2], fmaf(v0.w,w8[3], lin))));
      lin = fmaf(v1.x,w8[4], fmaf(v1.y,w8[5], fmaf(v1.z,w8[6], fmaf(v1.w,w8[7], lin))));
      float dt = softplusf(lin);
      ssum += dt;
      float u = xcg[(m0+t)*DIN + d];
      float du = dt*u;
      #pragma unroll
      for (int sp=0;sp<8;sp++){
        float4 q = *(const float4*)&vls[t][8 + 4*sp];   // {B2sp,C2sp,B2sp+1,C2sp+1}
        h[2*sp  ] = fmaf(exp2f(dt*a[2*sp  ]), h[2*sp  ], du*q.x);
        h[2*sp+1] = fmaf(exp2f(dt*a[2*sp+1]), h[2*sp+1], du*q.z);
      }
    }
    size_t base = (((size_t)b*NSEG + g)*DIN + d)*DST;
    #pragma unroll
    for (int i=0;i<4;i++){
      float4 o; o.x=h[4*i]; o.y=h[4*i+1]; o.z=h[4*i+2]; o.w=h[4*i+3];
      *(float4*)(cseg + base + 4*i) = o;
    }
    sdtb[((size_t)b*NSEG + g)*DIN + d] = ssum;
  }
}

// ---------------- scanB: serial combine over segments (unchanged) ----------------
__global__ __launch_bounds__(256) void k_scanB(float* __restrict__ cseg,
    const float* __restrict__ sdtb, const float* __restrict__ alog){
  int gl = blockIdx.x*256 + threadIdx.x;
  int b   = gl >> 12;
  int rem = gl & 4095;
  int d = rem >> 4, s = rem & 15;
  const float LOG2E = 1.4426950408889634f;
  const float a = -expf(alog[d*DST + s]) * LOG2E;
  float h = 0.f;
  for (int g=0; g<NSEG; g++){
    size_t base = ((size_t)b*NSEG + g)*DIN;
    float sd = sdtb[base + d];
    size_t ci = (base + d)*DST + s;
    float c = cseg[ci];
    cseg[ci] = h;
    h = fmaf(exp2f(a*sd), h, c);
  }
}

// ---------------- scanC2: thread = channel, 16 states, fused gate, in-place xc ------
__global__ __launch_bounds__(256) void k_scanC2(float* __restrict__ xcg,
    const float* __restrict__ vbc, const __bf16* __restrict__ zb,
    const float* __restrict__ dtw, const float* __restrict__ dtb,
    const float* __restrict__ alog, const float* __restrict__ Dpar,
    const float* __restrict__ cseg){
  __shared__ float svbc[64][40];
  const int tid = threadIdx.x;
  const size_t m0 = (size_t)blockIdx.x * 64;
  const int b = (int)(m0 >> 11);
  const int g = (int)((m0 >> 6) & (NSEG-1));

  #pragma unroll
  for (int p=0;p<10;p++){
    int j = p*256 + tid;
    int t = j / 40, i = j - t*40;
    if (j < 2560) svbc[t][i] = vbc[(m0+t)*40 + i];
  }

  const int d = tid;
  const float LOG2E = 1.4426950408889634f;
  float a[16];
  #pragma unroll
  for (int s=0;s<16;s++) a[s] = -expf(alog[d*DST + s]) * LOG2E;
  float w8[8];
  #pragma unroll
  for (int i=0;i<8;i++) w8[i] = dtw[d*8 + i];
  const float bd = dtb[d];
  const float Dv = Dpar[d];
  float h[16];
  size_t base = (((size_t)b*NSEG + g)*DIN + d)*DST;
  #pragma unroll
  for (int i=0;i<4;i++){
    float4 hv = *(const float4*)(cseg + base + 4*i);
    h[4*i]=hv.x; h[4*i+1]=hv.y; h[4*i+2]=hv.z; h[4*i+3]=hv.w;
  }
  __syncthreads();

  for (int t=0;t<SEG;t++){
    float4 v0 = *(const float4*)&svbc[t][0];
    float4 v1 = *(const float4*)&svbc[t][4];
    float lin = bd;
    lin = fmaf(v0.x,w8[0], fmaf(v0.y,w8[1], fmaf(v0.z,w8[2], fmaf(v0.w,w8[3], lin))));
    lin = fmaf(v1.x,w8[4], fmaf(v1.y,w8[5], fmaf(v1.z,w8[6], fmaf(v1.w,w8[7], lin))));
    float dt = softplusf(lin);
    float u = xcg[(m0+t)*DIN + d];
    float du = dt*u;
    float y = 0.f;
    #pragma unroll
    for (int sp=0;sp<8;sp++){
      float4 q = *(const float4*)&svbc[t][8 + 4*sp];   // {B,C,B,C}
      h[2*sp  ] = fmaf(exp2f(dt*a[2*sp  ]), h[2*sp  ], du*q.x);
      h[2*sp+1] = fmaf(exp2f(dt*a[2*sp+1]), h[2*sp+1], du*q.z);
      y = fmaf(h[2*sp], q.y, fmaf(h[2*sp+1], q.w, y));
    }
    float zf = (float)zb[(m0+t)*DIN + d];
    xcg[(m0+t)*DIN + d] = (y + u*Dv) * siluf(zf);
  }
}

// ---------------- masked mean pool over a chunk ----------------
__global__ __launch_bounds__(256) void k_pool1(const float* __restrict__ x,
    const float* __restrict__ mask, float* __restrict__ part, float* __restrict__ pmask){
  int b = blockIdx.y, seg = blockIdx.x;
  int d = threadIdx.x & 127, half = threadIdx.x >> 7;
  int t0 = seg*128 + half*64;
  float acc = 0.f, macc = 0.f;
  for (int i=0;i<64;i++){
    int t = t0 + i;
    float mv = mask[(size_t)b*SL + t];
    acc = fmaf(x[((size_t)b*SL + t)*DMODEL + d], mv, acc);
    macc += mv;
  }
  __shared__ float sm[256];
  __shared__ float smm[2];
  sm[threadIdx.x] = acc;
  if (d == 0) smm[half] = macc;
  __syncthreads();
  if (half == 0){
    part[((size_t)b*16 + seg)*128 + d] = sm[d] + sm[128+d];
    if (d == 0) pmask[b*16 + seg] = smm[0] + smm[1];
  }
}

__global__ void k_pool2(const float* __restrict__ part, const float* __restrict__ pmask,
                        float* __restrict__ pooled){
  int b = blockIdx.x, d = threadIdx.x;
  float acc = 0.f, ms = 0.f;
  for (int s=0;s<16;s++){ acc += part[((size_t)b*16+s)*128 + d]; ms += pmask[b*16+s]; }
  pooled[(size_t)b*128 + d] = acc / fmaxf(ms, 1e-9f);
}

// ---------------- tiny MLP ----------------
__global__ void k_mlp_a(const float* __restrict__ in, const float* __restrict__ w,
                        const float* __restrict__ bias, float* __restrict__ out, int K){
  int b = blockIdx.y;
  int n = blockIdx.x*128 + threadIdx.x;
  const float4* pw = (const float4*)(w + (size_t)n*K);
  const float4* pi = (const float4*)(in + (size_t)b*K);
  float acc = 0.f;
  for (int k=0;k<K/4;k++){
    float4 a = pi[k], ww = pw[k];
    acc = fmaf(a.x,ww.x, fmaf(a.y,ww.y, fmaf(a.z,ww.z, fmaf(a.w,ww.w, acc))));
  }
  out[(size_t)b*512 + n] = fmaxf(acc + bias[n], 0.f);
}

__global__ void k_mlp3(const float* __restrict__ h, const float* __restrict__ w,
                       const float* __restrict__ bias, float* __restrict__ out){
  int b = blockIdx.x;
  int n = threadIdx.x >> 6, lane = threadIdx.x & 63;
  if (n >= 3) return;
  float acc = 0.f;
  for (int k=lane; k<512; k+=64) acc = fmaf(h[(size_t)b*512+k], w[(size_t)n*512+k], acc);
  #pragma unroll
  for (int m=1;m<64;m<<=1) acc += __shfl_xor(acc, m);
  if (lane == 0) out[(size_t)b*3 + n] = acc + bias[n];
}

// ---------------- launch ----------------
extern "C" void kernel_launch(void* const* d_in, const int* in_sizes, int n_in,
                              void* d_out, int out_size, void* d_ws, size_t ws_size,
                              hipStream_t stream){
  const int*   tokens = (const int*)  d_in[0];
  const float* mask   = (const float*)d_in[1];
  const float* emb    = (const float*)d_in[2];
  const float* bn_w   = (const float*)d_in[3];
  const float* bn_b   = (const float*)d_in[4];
  const float* conv_w = (const float*)d_in[5];
  const float* conv_b = (const float*)d_in[6];
  const float* in_w   = (const float*)d_in[7];
  const float* c1_w   = (const float*)d_in[8];
  const float* c1_b   = (const float*)d_in[9];
  const float* xp_w   = (const float*)d_in[10];
  const float* dtp_w  = (const float*)d_in[11];
  const float* dtp_b  = (const float*)d_in[12];
  const float* A_log  = (const float*)d_in[13];
  const float* D_par  = (const float*)d_in[14];
  const float* out_w  = (const float*)d_in[15];
  const float* nrm_w  = (const float*)d_in[16];
  const float* l1w = (const float*)d_in[17]; const float* l1b = (const float*)d_in[18];
  const float* l2w = (const float*)d_in[19]; const float* l2b = (const float*)d_in[20];
  const float* l3w = (const float*)d_in[21]; const float* l3b = (const float*)d_in[22];
  float* dout = (float*)d_out;

  // per-token floats: x 128 + rs 1 + xi 256 + xc 256 + vbc 40 + cseg 64 + sdt 4 + z(bf16) 128 = 877
  int CB = 64;
  while (CB > 1 && ((size_t)CB*SL*877 + FIX_END)*4 > ws_size) CB >>= 1;
  if (((size_t)CB*SL*877 + FIX_END)*4 > ws_size) return;
  const size_t CTOK = (size_t)CB*SL;

  float* ws  = (float*)d_ws;
  float* pl  = ws + FIX_PL;
  float* pm  = ws + FIX_PM;
  float* pd  = ws + FIX_PD;
  float* h1  = ws + FIX_H1;
  float* h2  = ws + FIX_H2;
  float* wpf = ws + FIX_WP;
  __bf16* w2b   = (__bf16*)(ws + FIX_W2B);
  __bf16* winb  = (__bf16*)(ws + FIX_WINB);
  __bf16* woutb = (__bf16*)(ws + FIX_WOUTB);
  float* xcb = ws + FIX_END;                 // CTOK*128 residual x
  float* rs  = xcb + CTOK*128;               // CTOK
  float* xi  = rs  + CTOK;                   // CTOK*256 (embed pad / x-branch)
  float* xc  = xi  + CTOK*256;               // CTOK*256 (conv out -> gated y in place)
  float* vbc = xc  + CTOK*256;               // CTOK*40 (v8 + interleaved B/C)
  float* csg = vbc + CTOK*40;                // CTOK*64
  float* sdt = csg + CTOK*64;                // CTOK*4
  __bf16* zb = (__bf16*)(sdt + CTOK*4);      // CTOK*256 bf16

  k_w2b<<<192, 256, 0, stream>>>(conv_w, w2b);
  k_cvt<<<1024, 256, 0, stream>>>(in_w,  winb,  4*512*128);
  k_cvt<<<512,  256, 0, stream>>>(out_w, woutb, 4*128*256);
  k_wprep<<<256, 256, 0, stream>>>(xp_w, wpf);

  const int nchunks = NB / CB;
  for (int c = 0; c < nchunks; c++){
    const int* tok_c = tokens + (size_t)c*CTOK;

    k_embed<<<CB*2050, 128, 0, stream>>>(tok_c, emb, bn_w, bn_b, xi);
    k_mgemm<0,384,128><<<dim3(1, CTOK/128), 256, 0, stream>>>(
        xi, w2b, conv_b, nullptr, nullptr, xcb, nullptr);

    for (int layer = 0; layer < NLAYER; layer++){
      const __bf16* lin = winb  + (size_t)layer*512*128;
      const float* lcw  = c1_w  + (size_t)layer*DIN*4;
      const float* lcb  = c1_b  + (size_t)layer*DIN;
      const float* ldw  = dtp_w + (size_t)layer*DIN*8;
      const float* ldb  = dtp_b + (size_t)layer*DIN;
      const float* lal  = A_log + (size_t)layer*DIN*DST;
      const float* lD   = D_par + (size_t)layer*DIN;
      const __bf16* low = woutb + (size_t)layer*128*256;
      const float* lnw  = nrm_w + (size_t)layer*128;

      k_rmsscale<<<CTOK/4, 256, 0, stream>>>(xcb, rs);
      k_mgemm<1,128,512><<<dim3(4, CTOK/128), 256, 0, stream>>>(
          xcb, lin, nullptr, rs, lnw, xi, zb);
      k_seg<<<(int)(CTOK/64), 256, 0, stream>>>(
          xi, xc, wpf + (size_t)layer*64*256, lcw, lcb, ldw, ldb, lal, vbc, csg, sdt);
      k_scanB<<<CB*16, 256, 0, stream>>>(csg, sdt, lal);
      k_scanC2<<<(int)(CTOK/64), 256, 0, stream>>>(
          xc, vbc, zb, ldw, ldb, lal, lD, csg);
      k_mgemm<2,256,128><<<dim3(1, CTOK/128), 256, 0, stream>>>(
          xc, low, nullptr, nullptr, nullptr, xcb, nullptr);
    }

    k_pool1<<<dim3(16, CB), 256, 0, stream>>>(
        xcb, mask + (size_t)c*CTOK, pl + (size_t)c*CB*16*128, pm + (size_t)c*CB*16);
  }

  k_pool2<<<NB, 128, 0, stream>>>(pl, pm, pd);
  k_mlp_a<<<dim3(4, NB), 128, 0, stream>>>(pd, l1w, l1b, h1, 128);
  k_mlp_a<<<dim3(4, NB), 128, 0, stream>>>(h1, l2w, l2b, h2, 512);
  k_mlp3<<<NB, 256, 0, stream>>>(h2, l3w, l3b, dout);
}

// Round 9
// 3683.073 us; speedup vs baseline: 4.7985x; 1.2320x over previous
//
#include <hip/hip_runtime.h>
#include <math.h>

// ---------------- problem constants ----------------
#define NB     64
#define SL     2048
#define NTOK   (NB*SL)
#define EMB_D  128
#define DMODEL 128
#define DIN    256
#define DST    16
#define NLAYER 4
#define SEG    64
#define NSEG   (SL/SEG)        // 32

typedef __bf16 bf16x8 __attribute__((ext_vector_type(8)));
typedef __bf16 bf16x4 __attribute__((ext_vector_type(4)));
typedef float  f32x4  __attribute__((ext_vector_type(4)));

// fixed small region (floats)
#define FIX_PL   ((size_t)0)
#define FIX_PM   (FIX_PL + 131072)
#define FIX_PD   (FIX_PM + 1024)
#define FIX_H1   (FIX_PD + 8192)
#define FIX_H2   (FIX_H1 + 32768)
#define FIX_WP   (FIX_H2 + 32768)          // 4*64*256 x_proj combined (bf16, region sized as fp32)
#define FIX_W2B  (FIX_WP + 65536)          // 128*384 bf16 front conv w
#define FIX_WINB (FIX_W2B + 24576)         // 4*512*128 bf16 in_proj
#define FIX_WOUTB (FIX_WINB + 131072)      // 4*128*256 bf16 out_proj
#define FIX_END  (FIX_WOUTB + 65536)

__device__ __forceinline__ float siluf(float v){ return v / (1.f + expf(-v)); }
__device__ __forceinline__ float softplusf(float a){
  return (a > 0.f) ? (a + log1pf(expf(-a))) : log1pf(expf(a));
}

// ---------------- weight prep ----------------
__global__ void k_w2b(const float* __restrict__ cw, __bf16* __restrict__ w2){
  int g = blockIdx.x*256 + threadIdx.x;
  if (g >= 128*384) return;
  int d = g / 384, j = g % 384;
  int k = j >> 7, e = j & 127;
  w2[d*384 + k*128 + e] = (__bf16)cw[d*384 + e*3 + k];
}

__global__ void k_cvt(const float* __restrict__ src, __bf16* __restrict__ dst, int n){
  int i = blockIdx.x*256 + threadIdx.x;
  if (i < n) dst[i] = (__bf16)src[i];
}

// x_proj weight prep -> bf16, bc-interleave baked in: Wp[l][64][256]
__global__ void k_wprep(const float* __restrict__ xpw, __bf16* __restrict__ wp){
  int g = blockIdx.x*256 + threadIdx.x;      // 65536
  int l = g >> 14, rem = g & 16383;
  int n = rem >> 8, k = rem & 255;
  float v = 0.f;
  if (n < 8){
    v = xpw[(size_t)l*40*256 + n*256 + k];
  } else if (n < 40){
    int i = n - 8;
    int row = 8 + ((i&1)<<4) + (i>>1);
    v = xpw[(size_t)l*40*256 + row*256 + k];
  }
  wp[g] = (__bf16)v;
}

// ---------------- embed + BN into padded chunk buffer ----------------
__global__ void k_embed(const int* __restrict__ tok, const float* __restrict__ emb,
                        const float* __restrict__ bnw, const float* __restrict__ bnb,
                        float* __restrict__ xp){
  int r = blockIdx.x;                 // CB*2050 rows
  int e = threadIdx.x;                // 128
  int b = r / 2050, tp = r % 2050;
  float v = 0.f;
  if (tp != 0 && tp != 2049){
    int t = tp - 1;
    int id = tok[(size_t)b*SL + t];
    float s = bnw[e] * rsqrtf(1.0f + 1e-5f);
    v = emb[(size_t)id*EMB_D + e] * s + bnb[e];
  }
  xp[(size_t)r*EMB_D + e] = v;
}

// ---------------- rmsnorm scale only ----------------
__global__ __launch_bounds__(256) void k_rmsscale(const float* __restrict__ x,
                                                  float* __restrict__ rs){
  int wv = threadIdx.x>>6, lane = threadIdx.x&63;
  size_t tok = (size_t)blockIdx.x*4 + wv;
  float2 v = *(const float2*)(x + tok*128 + lane*2);
  float ss = v.x*v.x + v.y*v.y;
  #pragma unroll
  for (int m=1;m<64;m<<=1) ss += __shfl_xor(ss, m);
  float r = rsqrtf(ss*(1.f/128.f) + 1e-5f);
  if (lane == 0) rs[tok] = r;
}

// ---------------- bf16 MFMA GEMM  out[M,N] = A[M,K] @ W[N,K]^T ----------------
template<int MODE, int K, int N>
__global__ __launch_bounds__(256) void k_mgemm(
    const float* __restrict__ A, const __bf16* __restrict__ Wb,
    const float* __restrict__ bias, const float* __restrict__ rsp,
    const float* __restrict__ nwp,
    float* __restrict__ out, __bf16* __restrict__ outz){
  __shared__ __bf16 As[128][40];
  __shared__ __bf16 Bs[128][40];
  const int tid  = threadIdx.x;
  const int wave = tid >> 6;
  const int lane = tid & 63;
  const int col  = lane & 15;
  const int quad = lane >> 4;
  const int wm = (wave & 1) * 64;
  const int wn = (wave >> 1) * 64;
  const int m0 = blockIdx.y * 128;
  const int n0 = blockIdx.x * 128;

  f32x4 acc[4][4];
  #pragma unroll
  for (int i=0;i<4;i++)
    #pragma unroll
    for (int j=0;j<4;j++) acc[i][j] = (f32x4){0.f,0.f,0.f,0.f};

  size_t abase;
  if constexpr(MODE==0){
    int bb = m0 >> 11, tloc = m0 & 2047;
    abase = ((size_t)bb*2050 + tloc) * 128;
  } else {
    abase = (size_t)m0 * K;
  }

  const int sm = tid >> 3;
  const int sk4 = (tid & 7) * 4;
  const int bn = tid >> 2;
  const int bk8 = (tid & 3) * 8;

  for (int k0 = 0; k0 < K; k0 += 32){
    #pragma unroll
    for (int p=0;p<4;p++){
      int m = p*32 + sm;
      float4 v;
      if constexpr(MODE==0){
        v = *(const float4*)(A + abase + (size_t)m*128 + k0 + sk4);
      } else if constexpr(MODE==1){
        float4 x4 = *(const float4*)(A + abase + (size_t)m*K + k0 + sk4);
        float4 w4 = *(const float4*)(nwp + k0 + sk4);
        float s = rsp[m0 + m];
        v.x = x4.x*s*w4.x; v.y = x4.y*s*w4.y; v.z = x4.z*s*w4.z; v.w = x4.w*s*w4.w;
      } else {
        v = *(const float4*)(A + abase + (size_t)m*K + k0 + sk4);
      }
      bf16x4 o;
      o[0] = (__bf16)v.x; o[1] = (__bf16)v.y; o[2] = (__bf16)v.z; o[3] = (__bf16)v.w;
      *(bf16x4*)&As[m][sk4] = o;
    }
    #pragma unroll
    for (int p=0;p<2;p++){
      int n = p*64 + bn;
      bf16x8 w = *(const bf16x8*)(Wb + (size_t)(n0+n)*K + k0 + bk8);
      *(bf16x8*)&Bs[n][bk8] = w;
    }
    __syncthreads();
    bf16x8 af[4], bfr[4];
    const int fq = quad*8;
    #pragma unroll
    for (int i=0;i<4;i++) af[i]  = *(const bf16x8*)&As[wm + i*16 + col][fq];
    #pragma unroll
    for (int j=0;j<4;j++) bfr[j] = *(const bf16x8*)&Bs[wn + j*16 + col][fq];
    #pragma unroll
    for (int i=0;i<4;i++)
      #pragma unroll
      for (int j=0;j<4;j++)
        acc[i][j] = __builtin_amdgcn_mfma_f32_16x16x32_bf16(af[i], bfr[j], acc[i][j], 0, 0, 0);
    __syncthreads();
  }

  #pragma unroll
  for (int i=0;i<4;i++){
    #pragma unroll
    for (int j=0;j<4;j++){
      int n_l = wn + j*16 + col;
      #pragma unroll
      for (int r=0;r<4;r++){
        int m = m0 + wm + i*16 + quad*4 + r;
        float c = acc[i][j][r];
        if constexpr(MODE==0){
          int n = n0 + n_l;
          out[(size_t)m*DMODEL + n] = fmaxf(c + bias[n], 0.f);
        } else if constexpr(MODE==1){
          int n = n0 + n_l;
          if (n < DIN) out [(size_t)m*DIN + n]        = c;
          else         outz[(size_t)m*DIN + n - DIN]  = (__bf16)c;
        } else {
          float* p = out + (size_t)m*DMODEL + n0 + n_l;
          *p = *p + c;
        }
      }
    }
  }
}

// ---------------- fused segment front: dwconv+silu -> MFMA x_proj -> vbc -> scanA summary
// One block = 64-token segment. 256 threads.
__global__ __launch_bounds__(256) void k_seg(const float* __restrict__ xi,
    float* __restrict__ xcg, const __bf16* __restrict__ wpb,
    const float* __restrict__ cw, const float* __restrict__ cb,
    const float* __restrict__ dtw, const float* __restrict__ dtb,
    const float* __restrict__ alog,
    float* __restrict__ vbc, float* __restrict__ cseg, float* __restrict__ sdtb){
  __shared__ __bf16 sxc[64][264];
  __shared__ float vls[64][68];
  const int tid = threadIdx.x;
  const size_t m0 = (size_t)blockIdx.x * 64;
  const int b = (int)(m0 >> 11);
  const int g = (int)((m0 >> 6) & (NSEG-1));
  const int seq0 = (int)(m0 & 2047);

  // ---- phase 0: depthwise conv(k=4) + silu -> xcg (fp32) + sxc (bf16 LDS) ----
  {
    const int c4 = (tid & 63) * 4;
    const int tw = tid >> 6;
    float wc[4][4];
    #pragma unroll
    for (int j=0;j<4;j++)
      #pragma unroll
      for (int k=0;k<4;k++) wc[j][k] = cw[(c4+j)*4 + k];
    float4 cb4 = *(const float4*)(cb + c4);
    #pragma unroll
    for (int it=0; it<16; it++){
      int t = it*4 + tw;
      float4 acc = cb4;
      #pragma unroll
      for (int k=0;k<4;k++){
        if (seq0 + t - 3 + k >= 0){
          float4 xv = *(const float4*)(xi + (m0 + t - 3 + k)*DIN + c4);
          acc.x = fmaf(wc[0][k], xv.x, acc.x);
          acc.y = fmaf(wc[1][k], xv.y, acc.y);
          acc.z = fmaf(wc[2][k], xv.z, acc.z);
          acc.w = fmaf(wc[3][k], xv.w, acc.w);
        }
      }
      acc.x = siluf(acc.x); acc.y = siluf(acc.y);
      acc.z = siluf(acc.z); acc.w = siluf(acc.w);
      *(float4*)(xcg + (m0 + t)*DIN + c4) = acc;
      bf16x4 o;
      o[0]=(__bf16)acc.x; o[1]=(__bf16)acc.y; o[2]=(__bf16)acc.z; o[3]=(__bf16)acc.w;
      *(bf16x4*)&sxc[t][c4] = o;
    }
  }
  __syncthreads();

  // ---- phase 1: MFMA vls[64][64] = sxc[64x256] @ wpb[64x256]^T ----
  {
    const int wave = tid >> 6, lane = tid & 63;
    const int col = lane & 15, quad = lane >> 4;
    const int wn = wave * 16;
    f32x4 acc[4];
    #pragma unroll
    for (int i=0;i<4;i++) acc[i] = (f32x4){0.f,0.f,0.f,0.f};
    #pragma unroll
    for (int kc=0;kc<8;kc++){
      bf16x8 bfr = *(const bf16x8*)(wpb + (size_t)(wn+col)*256 + kc*32 + quad*8);
      #pragma unroll
      for (int mi=0;mi<4;mi++){
        bf16x8 af = *(const bf16x8*)&sxc[mi*16 + col][kc*32 + quad*8];
        acc[mi] = __builtin_amdgcn_mfma_f32_16x16x32_bf16(af, bfr, acc[mi], 0, 0, 0);
      }
    }
    #pragma unroll
    for (int mi=0;mi<4;mi++)
      #pragma unroll
      for (int r=0;r<4;r++)
        vls[mi*16 + quad*4 + r][wn + col] = acc[mi][r];
  }
  __syncthreads();

  // ---- phase 2: write vbc[t][40] ----
  #pragma unroll
  for (int p=0;p<10;p++){
    int j = p*256 + tid;
    int t = j / 40, i = j - t*40;
    if (j < 2560) vbc[(m0+t)*40 + i] = vls[t][i];
  }

  // ---- phase 3: scanA summary, thread = channel ----
  {
    const int d = tid;
    const float LOG2E = 1.4426950408889634f;
    float a[16];
    #pragma unroll
    for (int s=0;s<16;s++) a[s] = -expf(alog[d*DST + s]) * LOG2E;
    const float a0 = a[0];
    bool fast = true;
    #pragma unroll
    for (int s=1;s<16;s++) fast = fast && (fabsf(a[s] - (float)(s+1)*a0) <= 1e-3f*fabsf(a[s]));
    float w8[8];
    #pragma unroll
    for (int i=0;i<8;i++) w8[i] = dtw[d*8 + i];
    const float bd = dtb[d];
    float h[16];
    #pragma unroll
    for (int s=0;s<16;s++) h[s] = 0.f;
    float ssum = 0.f;
    if (fast){
      for (int t=0;t<SEG;t++){
        float4 v0 = *(const float4*)&vls[t][0];
        float4 v1 = *(const float4*)&vls[t][4];
        float lin = bd;
        lin = fmaf(v0.x,w8[0], fmaf(v0.y,w8[1], fmaf(v0.z,w8[2], fmaf(v0.w,w8[3], lin))));
        lin = fmaf(v1.x,w8[4], fmaf(v1.y,w8[5], fmaf(v1.z,w8[6], fmaf(v1.w,w8[7], lin))));
        float dt = softplusf(lin);
        ssum += dt;
        float u = xcg[(m0+t)*DIN + d];
        float du = dt*u;
        float r = exp2f(dt*a0);
        float dA = 1.f;
        #pragma unroll
        for (int sp=0;sp<8;sp++){
          float4 q = *(const float4*)&vls[t][8 + 4*sp];
          dA *= r; h[2*sp  ] = fmaf(dA, h[2*sp  ], du*q.x);
          dA *= r; h[2*sp+1] = fmaf(dA, h[2*sp+1], du*q.z);
        }
      }
    } else {
      for (int t=0;t<SEG;t++){
        float4 v0 = *(const float4*)&vls[t][0];
        float4 v1 = *(const float4*)&vls[t][4];
        float lin = bd;
        lin = fmaf(v0.x,w8[0], fmaf(v0.y,w8[1], fmaf(v0.z,w8[2], fmaf(v0.w,w8[3], lin))));
        lin = fmaf(v1.x,w8[4], fmaf(v1.y,w8[5], fmaf(v1.z,w8[6], fmaf(v1.w,w8[7], lin))));
        float dt = softplusf(lin);
        ssum += dt;
        float u = xcg[(m0+t)*DIN + d];
        float du = dt*u;
        #pragma unroll
        for (int sp=0;sp<8;sp++){
          float4 q = *(const float4*)&vls[t][8 + 4*sp];
          h[2*sp  ] = fmaf(exp2f(dt*a[2*sp  ]), h[2*sp  ], du*q.x);
          h[2*sp+1] = fmaf(exp2f(dt*a[2*sp+1]), h[2*sp+1], du*q.z);
        }
      }
    }
    size_t base = (((size_t)b*NSEG + g)*DIN + d)*DST;
    #pragma unroll
    for (int i=0;i<4;i++){
      float4 o; o.x=h[4*i]; o.y=h[4*i+1]; o.z=h[4*i+2]; o.w=h[4*i+3];
      *(float4*)(cseg + base + 4*i) = o;
    }
    sdtb[((size_t)b*NSEG + g)*DIN + d] = ssum;
  }
}

// ---------------- scanB: serial combine over segments ----------------
__global__ __launch_bounds__(256) void k_scanB(float* __restrict__ cseg,
    const float* __restrict__ sdtb, const float* __restrict__ alog){
  int gl = blockIdx.x*256 + threadIdx.x;
  int b   = gl >> 12;
  int rem = gl & 4095;
  int d = rem >> 4, s = rem & 15;
  const float LOG2E = 1.4426950408889634f;
  const float a = -expf(alog[d*DST + s]) * LOG2E;
  float h = 0.f;
  for (int g=0; g<NSEG; g++){
    size_t base = ((size_t)b*NSEG + g)*DIN;
    float sd = sdtb[base + d];
    size_t ci = (base + d)*DST + s;
    float c = cseg[ci];
    cseg[ci] = h;
    h = fmaf(exp2f(a*sd), h, c);
  }
}

// ---------------- scanC2: thread = channel, fused gate, in-place xc ------
__global__ __launch_bounds__(256) void k_scanC2(float* __restrict__ xcg,
    const float* __restrict__ vbc, const __bf16* __restrict__ zb,
    const float* __restrict__ dtw, const float* __restrict__ dtb,
    const float* __restrict__ alog, const float* __restrict__ Dpar,
    const float* __restrict__ cseg){
  __shared__ float svbc[64][40];
  const int tid = threadIdx.x;
  const size_t m0 = (size_t)blockIdx.x * 64;
  const int b = (int)(m0 >> 11);
  const int g = (int)((m0 >> 6) & (NSEG-1));

  #pragma unroll
  for (int p=0;p<10;p++){
    int j = p*256 + tid;
    int t = j / 40, i = j - t*40;
    if (j < 2560) svbc[t][i] = vbc[(m0+t)*40 + i];
  }

  const int d = tid;
  const float LOG2E = 1.4426950408889634f;
  float a[16];
  #pragma unroll
  for (int s=0;s<16;s++) a[s] = -expf(alog[d*DST + s]) * LOG2E;
  const float a0 = a[0];
  bool fast = true;
  #pragma unroll
  for (int s=1;s<16;s++) fast = fast && (fabsf(a[s] - (float)(s+1)*a0) <= 1e-3f*fabsf(a[s]));
  float w8[8];
  #pragma unroll
  for (int i=0;i<8;i++) w8[i] = dtw[d*8 + i];
  const float bd = dtb[d];
  const float Dv = Dpar[d];
  float h[16];
  size_t base = (((size_t)b*NSEG + g)*DIN + d)*DST;
  #pragma unroll
  for (int i=0;i<4;i++){
    float4 hv = *(const float4*)(cseg + base + 4*i);
    h[4*i]=hv.x; h[4*i+1]=hv.y; h[4*i+2]=hv.z; h[4*i+3]=hv.w;
  }
  __syncthreads();

  if (fast){
    for (int t=0;t<SEG;t++){
      float4 v0 = *(const float4*)&svbc[t][0];
      float4 v1 = *(const float4*)&svbc[t][4];
      float lin = bd;
      lin = fmaf(v0.x,w8[0], fmaf(v0.y,w8[1], fmaf(v0.z,w8[2], fmaf(v0.w,w8[3], lin))));
      lin = fmaf(v1.x,w8[4], fmaf(v1.y,w8[5], fmaf(v1.z,w8[6], fmaf(v1.w,w8[7], lin))));
      float dt = softplusf(lin);
      float u = xcg[(m0+t)*DIN + d];
      float du = dt*u;
      float r = exp2f(dt*a0);
      float dA = 1.f, y = 0.f;
      #pragma unroll
      for (int sp=0;sp<8;sp++){
        float4 q = *(const float4*)&svbc[t][8 + 4*sp];
        dA *= r; h[2*sp  ] = fmaf(dA, h[2*sp  ], du*q.x);
        y = fmaf(h[2*sp], q.y, y);
        dA *= r; h[2*sp+1] = fmaf(dA, h[2*sp+1], du*q.z);
        y = fmaf(h[2*sp+1], q.w, y);
      }
      float zf = (float)zb[(m0+t)*DIN + d];
      xcg[(m0+t)*DIN + d] = (y + u*Dv) * siluf(zf);
    }
  } else {
    for (int t=0;t<SEG;t++){
      float4 v0 = *(const float4*)&svbc[t][0];
      float4 v1 = *(const float4*)&svbc[t][4];
      float lin = bd;
      lin = fmaf(v0.x,w8[0], fmaf(v0.y,w8[1], fmaf(v0.z,w8[2], fmaf(v0.w,w8[3], lin))));
      lin = fmaf(v1.x,w8[4], fmaf(v1.y,w8[5], fmaf(v1.z,w8[6], fmaf(v1.w,w8[7], lin))));
      float dt = softplusf(lin);
      float u = xcg[(m0+t)*DIN + d];
      float du = dt*u;
      float y = 0.f;
      #pragma unroll
      for (int sp=0;sp<8;sp++){
        float4 q = *(const float4*)&svbc[t][8 + 4*sp];
        h[2*sp  ] = fmaf(exp2f(dt*a[2*sp  ]), h[2*sp  ], du*q.x);
        y = fmaf(h[2*sp], q.y, y);
        h[2*sp+1] = fmaf(exp2f(dt*a[2*sp+1]), h[2*sp+1], du*q.z);
        y = fmaf(h[2*sp+1], q.w, y);
      }
      float zf = (float)zb[(m0+t)*DIN + d];
      xcg[(m0+t)*DIN + d] = (y + u*Dv) * siluf(zf);
    }
  }
}

// ---------------- masked mean pool over a chunk ----------------
__global__ __launch_bounds__(256) void k_pool1(const float* __restrict__ x,
    const float* __restrict__ mask, float* __restrict__ part, float* __restrict__ pmask){
  int b = blockIdx.y, seg = blockIdx.x;
  int d = threadIdx.x & 127, half = threadIdx.x >> 7;
  int t0 = seg*128 + half*64;
  float acc = 0.f, macc = 0.f;
  for (int i=0;i<64;i++){
    int t = t0 + i;
    float mv = mask[(size_t)b*SL + t];
    acc = fmaf(x[((size_t)b*SL + t)*DMODEL + d], mv, acc);
    macc += mv;
  }
  __shared__ float sm[256];
  __shared__ float smm[2];
  sm[threadIdx.x] = acc;
  if (d == 0) smm[half] = macc;
  __syncthreads();
  if (half == 0){
    part[((size_t)b*16 + seg)*128 + d] = sm[d] + sm[128+d];
    if (d == 0) pmask[b*16 + seg] = smm[0] + smm[1];
  }
}

__global__ void k_pool2(const float* __restrict__ part, const float* __restrict__ pmask,
                        float* __restrict__ pooled){
  int b = blockIdx.x, d = threadIdx.x;
  float acc = 0.f, ms = 0.f;
  for (int s=0;s<16;s++){ acc += part[((size_t)b*16+s)*128 + d]; ms += pmask[b*16+s]; }
  pooled[(size_t)b*128 + d] = acc / fmaxf(ms, 1e-9f);
}

// ---------------- tiny MLP ----------------
__global__ void k_mlp_a(const float* __restrict__ in, const float* __restrict__ w,
                        const float* __restrict__ bias, float* __restrict__ out, int K){
  int b = blockIdx.y;
  int n = blockIdx.x*128 + threadIdx.x;
  const float4* pw = (const float4*)(w + (size_t)n*K);
  const float4* pi = (const float4*)(in + (size_t)b*K);
  float acc = 0.f;
  for (int k=0;k<K/4;k++){
    float4 a = pi[k], ww = pw[k];
    acc = fmaf(a.x,ww.x, fmaf(a.y,ww.y, fmaf(a.z,ww.z, fmaf(a.w,ww.w, acc))));
  }
  out[(size_t)b*512 + n] = fmaxf(acc + bias[n], 0.f);
}

__global__ void k_mlp3(const float* __restrict__ h, const float* __restrict__ w,
                       const float* __restrict__ bias, float* __restrict__ out){
  int b = blockIdx.x;
  int n = threadIdx.x >> 6, lane = threadIdx.x & 63;
  if (n >= 3) return;
  float acc = 0.f;
  for (int k=lane; k<512; k+=64) acc = fmaf(h[(size_t)b*512+k], w[(size_t)n*512+k], acc);
  #pragma unroll
  for (int m=1;m<64;m<<=1) acc += __shfl_xor(acc, m);
  if (lane == 0) out[(size_t)b*3 + n] = acc + bias[n];
}

// ---------------- launch ----------------
extern "C" void kernel_launch(void* const* d_in, const int* in_sizes, int n_in,
                              void* d_out, int out_size, void* d_ws, size_t ws_size,
                              hipStream_t stream){
  const int*   tokens = (const int*)  d_in[0];
  const float* mask   = (const float*)d_in[1];
  const float* emb    = (const float*)d_in[2];
  const float* bn_w   = (const float*)d_in[3];
  const float* bn_b   = (const float*)d_in[4];
  const float* conv_w = (const float*)d_in[5];
  const float* conv_b = (const float*)d_in[6];
  const float* in_w   = (const float*)d_in[7];
  const float* c1_w   = (const float*)d_in[8];
  const float* c1_b   = (const float*)d_in[9];
  const float* xp_w   = (const float*)d_in[10];
  const float* dtp_w  = (const float*)d_in[11];
  const float* dtp_b  = (const float*)d_in[12];
  const float* A_log  = (const float*)d_in[13];
  const float* D_par  = (const float*)d_in[14];
  const float* out_w  = (const float*)d_in[15];
  const float* nrm_w  = (const float*)d_in[16];
  const float* l1w = (const float*)d_in[17]; const float* l1b = (const float*)d_in[18];
  const float* l2w = (const float*)d_in[19]; const float* l2b = (const float*)d_in[20];
  const float* l3w = (const float*)d_in[21]; const float* l3b = (const float*)d_in[22];
  float* dout = (float*)d_out;

  // per-token floats: x 128 + rs 1 + xi 256 + xc 256 + vbc 40 + cseg 64 + sdt 4 + z(bf16) 128 = 877
  int CB = 64;
  while (CB > 1 && ((size_t)CB*SL*877 + FIX_END)*4 > ws_size) CB >>= 1;
  if (((size_t)CB*SL*877 + FIX_END)*4 > ws_size) return;
  const size_t CTOK = (size_t)CB*SL;

  float* ws  = (float*)d_ws;
  float* pl  = ws + FIX_PL;
  float* pm  = ws + FIX_PM;
  float* pd  = ws + FIX_PD;
  float* h1  = ws + FIX_H1;
  float* h2  = ws + FIX_H2;
  __bf16* wpb   = (__bf16*)(ws + FIX_WP);
  __bf16* w2b   = (__bf16*)(ws + FIX_W2B);
  __bf16* winb  = (__bf16*)(ws + FIX_WINB);
  __bf16* woutb = (__bf16*)(ws + FIX_WOUTB);
  float* xcb = ws + FIX_END;                 // CTOK*128 residual x
  float* rs  = xcb + CTOK*128;               // CTOK
  float* xi  = rs  + CTOK;                   // CTOK*256 (embed pad / x-branch)
  float* xc  = xi  + CTOK*256;               // CTOK*256 (conv out -> gated y in place)
  float* vbc = xc  + CTOK*256;               // CTOK*40
  float* csg = vbc + CTOK*40;                // CTOK*64
  float* sdt = csg + CTOK*64;                // CTOK*4
  __bf16* zb = (__bf16*)(sdt + CTOK*4);      // CTOK*256 bf16

  k_w2b<<<192, 256, 0, stream>>>(conv_w, w2b);
  k_cvt<<<1024, 256, 0, stream>>>(in_w,  winb,  4*512*128);
  k_cvt<<<512,  256, 0, stream>>>(out_w, woutb, 4*128*256);
  k_wprep<<<256, 256, 0, stream>>>(xp_w, wpb);

  const int nchunks = NB / CB;
  for (int c = 0; c < nchunks; c++){
    const int* tok_c = tokens + (size_t)c*CTOK;

    k_embed<<<CB*2050, 128, 0, stream>>>(tok_c, emb, bn_w, bn_b, xi);
    k_mgemm<0,384,128><<<dim3(1, CTOK/128), 256, 0, stream>>>(
        xi, w2b, conv_b, nullptr, nullptr, xcb, nullptr);

    for (int layer = 0; layer < NLAYER; layer++){
      const __bf16* lin = winb  + (size_t)layer*512*128;
      const float* lcw  = c1_w  + (size_t)layer*DIN*4;
      const float* lcb  = c1_b  + (size_t)layer*DIN;
      const float* ldw  = dtp_w + (size_t)layer*DIN*8;
      const float* ldb  = dtp_b + (size_t)layer*DIN;
      const float* lal  = A_log + (size_t)layer*DIN*DST;
      const float* lD   = D_par + (size_t)layer*DIN;
      const __bf16* low = woutb + (size_t)layer*128*256;
      const float* lnw  = nrm_w + (size_t)layer*128;

      k_rmsscale<<<CTOK/4, 256, 0, stream>>>(xcb, rs);
      k_mgemm<1,128,512><<<dim3(4, CTOK/128), 256, 0, stream>>>(
          xcb, lin, nullptr, rs, lnw, xi, zb);
      k_seg<<<(int)(CTOK/64), 256, 0, stream>>>(
          xi, xc, wpb + (size_t)layer*64*256, lcw, lcb, ldw, ldb, lal, vbc, csg, sdt);
      k_scanB<<<CB*16, 256, 0, stream>>>(csg, sdt, lal);
      k_scanC2<<<(int)(CTOK/64), 256, 0, stream>>>(
          xc, vbc, zb, ldw, ldb, lal, lD, csg);
      k_mgemm<2,256,128><<<dim3(1, CTOK/128), 256, 0, stream>>>(
          xc, low, nullptr, nullptr, nullptr, xcb, nullptr);
    }

    k_pool1<<<dim3(16, CB), 256, 0, stream>>>(
        xcb, mask + (size_t)c*CTOK, pl + (size_t)c*CB*16*128, pm + (size_t)c*CB*16);
  }

  k_pool2<<<NB, 128, 0, stream>>>(pl, pm, pd);
  k_mlp_a<<<dim3(4, NB), 128, 0, stream>>>(pd, l1w, l1b, h1, 128);
  k_mlp_a<<<dim3(4, NB), 128, 0, stream>>>(h1, l2w, l2b, h2, 512);
  k_mlp3<<<NB, 256, 0, stream>>>(h2, l3w, l3b, dout);
}

// Round 10
// 3649.606 us; speedup vs baseline: 4.8425x; 1.0092x over previous
//
#include <hip/hip_runtime.h>
#include <math.h>

// ---------------- problem constants ----------------
#define NB     64
#define SL     2048
#define NTOK   (NB*SL)
#define EMB_D  128
#define DMODEL 128
#define DIN    256
#define DST    16
#define NLAYER 4
#define SEG    64
#define NSEG   (SL/SEG)        // 32

typedef __bf16 bf16x8 __attribute__((ext_vector_type(8)));
typedef __bf16 bf16x4 __attribute__((ext_vector_type(4)));
typedef float  f32x4  __attribute__((ext_vector_type(4)));

// fixed small region (floats)
#define FIX_PL   ((size_t)0)
#define FIX_PM   (FIX_PL + 131072)
#define FIX_PD   (FIX_PM + 1024)
#define FIX_H1   (FIX_PD + 8192)
#define FIX_H2   (FIX_H1 + 32768)
#define FIX_WP   (FIX_H2 + 32768)
#define FIX_W2B  (FIX_WP + 65536)
#define FIX_WINB (FIX_W2B + 24576)
#define FIX_WOUTB (FIX_WINB + 131072)
#define FIX_END  (FIX_WOUTB + 65536)

__device__ __forceinline__ float siluf(float v){ return v / (1.f + expf(-v)); }
__device__ __forceinline__ float softplusf(float a){
  return (a > 0.f) ? (a + log1pf(expf(-a))) : log1pf(expf(a));
}

// state-pair update macros (explicit scalars, no arrays -> guaranteed VGPR residency)
#define SPF(hA,hB,q)  { dA*=r; hA=fmaf(dA,hA,du*q.x); dA*=r; hB=fmaf(dA,hB,du*q.z); }
#define SPFY(hA,hB,q) { dA*=r; hA=fmaf(dA,hA,du*q.x); y=fmaf(hA,q.y,y); \
                        dA*=r; hB=fmaf(dA,hB,du*q.z); y=fmaf(hB,q.w,y); }
#define SPSA(hA,hB,q,s0,s1) { float eA=exp2f(dt*(-expf(alog[d*DST+s0])*LOG2E)); \
                              hA=fmaf(eA,hA,du*q.x); \
                              float eB=exp2f(dt*(-expf(alog[d*DST+s1])*LOG2E)); \
                              hB=fmaf(eB,hB,du*q.z); }
#define SPSY(hA,hB,q,s0,s1) { float eA=exp2f(dt*(-expf(alog[d*DST+s0])*LOG2E)); \
                              hA=fmaf(eA,hA,du*q.x); y=fmaf(hA,q.y,y); \
                              float eB=exp2f(dt*(-expf(alog[d*DST+s1])*LOG2E)); \
                              hB=fmaf(eB,hB,du*q.z); y=fmaf(hB,q.w,y); }

// ---------------- weight prep ----------------
__global__ void k_w2b(const float* __restrict__ cw, __bf16* __restrict__ w2){
  int g = blockIdx.x*256 + threadIdx.x;
  if (g >= 128*384) return;
  int d = g / 384, j = g % 384;
  int k = j >> 7, e = j & 127;
  w2[d*384 + k*128 + e] = (__bf16)cw[d*384 + e*3 + k];
}

__global__ void k_cvt(const float* __restrict__ src, __bf16* __restrict__ dst, int n){
  int i = blockIdx.x*256 + threadIdx.x;
  if (i < n) dst[i] = (__bf16)src[i];
}

__global__ void k_wprep(const float* __restrict__ xpw, __bf16* __restrict__ wp){
  int g = blockIdx.x*256 + threadIdx.x;      // 65536
  int l = g >> 14, rem = g & 16383;
  int n = rem >> 8, k = rem & 255;
  float v = 0.f;
  if (n < 8){
    v = xpw[(size_t)l*40*256 + n*256 + k];
  } else if (n < 40){
    int i = n - 8;
    int row = 8 + ((i&1)<<4) + (i>>1);
    v = xpw[(size_t)l*40*256 + row*256 + k];
  }
  wp[g] = (__bf16)v;
}

// ---------------- embed + BN into padded chunk buffer ----------------
__global__ void k_embed(const int* __restrict__ tok, const float* __restrict__ emb,
                        const float* __restrict__ bnw, const float* __restrict__ bnb,
                        float* __restrict__ xp){
  int r = blockIdx.x;                 // CB*2050 rows
  int e = threadIdx.x;                // 128
  int b = r / 2050, tp = r % 2050;
  float v = 0.f;
  if (tp != 0 && tp != 2049){
    int t = tp - 1;
    int id = tok[(size_t)b*SL + t];
    float s = bnw[e] * rsqrtf(1.0f + 1e-5f);
    v = emb[(size_t)id*EMB_D + e] * s + bnb[e];
  }
  xp[(size_t)r*EMB_D + e] = v;
}

// ---------------- rmsnorm scale only ----------------
__global__ __launch_bounds__(256) void k_rmsscale(const float* __restrict__ x,
                                                  float* __restrict__ rs){
  int wv = threadIdx.x>>6, lane = threadIdx.x&63;
  size_t tok = (size_t)blockIdx.x*4 + wv;
  float2 v = *(const float2*)(x + tok*128 + lane*2);
  float ss = v.x*v.x + v.y*v.y;
  #pragma unroll
  for (int m=1;m<64;m<<=1) ss += __shfl_xor(ss, m);
  float r = rsqrtf(ss*(1.f/128.f) + 1e-5f);
  if (lane == 0) rs[tok] = r;
}

// ---------------- bf16 MFMA GEMM  out[M,N] = A[M,K] @ W[N,K]^T ----------------
template<int MODE, int K, int N>
__global__ __launch_bounds__(256) void k_mgemm(
    const float* __restrict__ A, const __bf16* __restrict__ Wb,
    const float* __restrict__ bias, const float* __restrict__ rsp,
    const float* __restrict__ nwp,
    float* __restrict__ out, __bf16* __restrict__ outz){
  __shared__ __bf16 As[128][40];
  __shared__ __bf16 Bs[128][40];
  const int tid  = threadIdx.x;
  const int wave = tid >> 6;
  const int lane = tid & 63;
  const int col  = lane & 15;
  const int quad = lane >> 4;
  const int wm = (wave & 1) * 64;
  const int wn = (wave >> 1) * 64;
  const int m0 = blockIdx.y * 128;
  const int n0 = blockIdx.x * 128;

  f32x4 acc[4][4];
  #pragma unroll
  for (int i=0;i<4;i++)
    #pragma unroll
    for (int j=0;j<4;j++) acc[i][j] = (f32x4){0.f,0.f,0.f,0.f};

  size_t abase;
  if constexpr(MODE==0){
    int bb = m0 >> 11, tloc = m0 & 2047;
    abase = ((size_t)bb*2050 + tloc) * 128;
  } else {
    abase = (size_t)m0 * K;
  }

  const int sm = tid >> 3;
  const int sk4 = (tid & 7) * 4;
  const int bn = tid >> 2;
  const int bk8 = (tid & 3) * 8;

  for (int k0 = 0; k0 < K; k0 += 32){
    #pragma unroll
    for (int p=0;p<4;p++){
      int m = p*32 + sm;
      float4 v;
      if constexpr(MODE==0){
        v = *(const float4*)(A + abase + (size_t)m*128 + k0 + sk4);
      } else if constexpr(MODE==1){
        float4 x4 = *(const float4*)(A + abase + (size_t)m*K + k0 + sk4);
        float4 w4 = *(const float4*)(nwp + k0 + sk4);
        float s = rsp[m0 + m];
        v.x = x4.x*s*w4.x; v.y = x4.y*s*w4.y; v.z = x4.z*s*w4.z; v.w = x4.w*s*w4.w;
      } else {
        v = *(const float4*)(A + abase + (size_t)m*K + k0 + sk4);
      }
      bf16x4 o;
      o[0] = (__bf16)v.x; o[1] = (__bf16)v.y; o[2] = (__bf16)v.z; o[3] = (__bf16)v.w;
      *(bf16x4*)&As[m][sk4] = o;
    }
    #pragma unroll
    for (int p=0;p<2;p++){
      int n = p*64 + bn;
      bf16x8 w = *(const bf16x8*)(Wb + (size_t)(n0+n)*K + k0 + bk8);
      *(bf16x8*)&Bs[n][bk8] = w;
    }
    __syncthreads();
    bf16x8 af[4], bfr[4];
    const int fq = quad*8;
    #pragma unroll
    for (int i=0;i<4;i++) af[i]  = *(const bf16x8*)&As[wm + i*16 + col][fq];
    #pragma unroll
    for (int j=0;j<4;j++) bfr[j] = *(const bf16x8*)&Bs[wn + j*16 + col][fq];
    #pragma unroll
    for (int i=0;i<4;i++)
      #pragma unroll
      for (int j=0;j<4;j++)
        acc[i][j] = __builtin_amdgcn_mfma_f32_16x16x32_bf16(af[i], bfr[j], acc[i][j], 0, 0, 0);
    __syncthreads();
  }

  #pragma unroll
  for (int i=0;i<4;i++){
    #pragma unroll
    for (int j=0;j<4;j++){
      int n_l = wn + j*16 + col;
      #pragma unroll
      for (int r=0;r<4;r++){
        int m = m0 + wm + i*16 + quad*4 + r;
        float c = acc[i][j][r];
        if constexpr(MODE==0){
          int n = n0 + n_l;
          out[(size_t)m*DMODEL + n] = fmaxf(c + bias[n], 0.f);
        } else if constexpr(MODE==1){
          int n = n0 + n_l;
          if (n < DIN) out [(size_t)m*DIN + n]        = c;
          else         outz[(size_t)m*DIN + n - DIN]  = (__bf16)c;
        } else {
          float* p = out + (size_t)m*DMODEL + n0 + n_l;
          *p = *p + c;
        }
      }
    }
  }
}

// ---------------- fused segment front: dwconv+silu -> MFMA x_proj -> vbc -> scanA summary
__global__ __launch_bounds__(256) void k_seg(const float* __restrict__ xi,
    float* __restrict__ xcg, const __bf16* __restrict__ wpb,
    const float* __restrict__ cw, const float* __restrict__ cb,
    const float* __restrict__ dtw, const float* __restrict__ dtb,
    const float* __restrict__ alog,
    float* __restrict__ vbc, float* __restrict__ cseg, float* __restrict__ sdtb){
  __shared__ __bf16 sxc[64][264];
  __shared__ float vls[64][68];
  const int tid = threadIdx.x;
  const size_t m0 = (size_t)blockIdx.x * 64;
  const int b = (int)(m0 >> 11);
  const int g = (int)((m0 >> 6) & (NSEG-1));
  const int seq0 = (int)(m0 & 2047);

  // ---- phase 0: depthwise conv(k=4) + silu -> xcg (fp32) + sxc (bf16 LDS) ----
  {
    const int c4 = (tid & 63) * 4;
    const int tw = tid >> 6;
    float wc[4][4];
    #pragma unroll
    for (int j=0;j<4;j++)
      #pragma unroll
      for (int k=0;k<4;k++) wc[j][k] = cw[(c4+j)*4 + k];
    float4 cb4 = *(const float4*)(cb + c4);
    #pragma unroll
    for (int it=0; it<16; it++){
      int t = it*4 + tw;
      float4 acc = cb4;
      #pragma unroll
      for (int k=0;k<4;k++){
        if (seq0 + t - 3 + k >= 0){
          float4 xv = *(const float4*)(xi + (m0 + t - 3 + k)*DIN + c4);
          acc.x = fmaf(wc[0][k], xv.x, acc.x);
          acc.y = fmaf(wc[1][k], xv.y, acc.y);
          acc.z = fmaf(wc[2][k], xv.z, acc.z);
          acc.w = fmaf(wc[3][k], xv.w, acc.w);
        }
      }
      acc.x = siluf(acc.x); acc.y = siluf(acc.y);
      acc.z = siluf(acc.z); acc.w = siluf(acc.w);
      *(float4*)(xcg + (m0 + t)*DIN + c4) = acc;
      bf16x4 o;
      o[0]=(__bf16)acc.x; o[1]=(__bf16)acc.y; o[2]=(__bf16)acc.z; o[3]=(__bf16)acc.w;
      *(bf16x4*)&sxc[t][c4] = o;
    }
  }
  __syncthreads();

  // ---- phase 1: MFMA vls[64][64] = sxc[64x256] @ wpb[64x256]^T ----
  {
    const int wave = tid >> 6, lane = tid & 63;
    const int col = lane & 15, quad = lane >> 4;
    const int wn = wave * 16;
    f32x4 acc[4];
    #pragma unroll
    for (int i=0;i<4;i++) acc[i] = (f32x4){0.f,0.f,0.f,0.f};
    #pragma unroll
    for (int kc=0;kc<8;kc++){
      bf16x8 bfr = *(const bf16x8*)(wpb + (size_t)(wn+col)*256 + kc*32 + quad*8);
      #pragma unroll
      for (int mi=0;mi<4;mi++){
        bf16x8 af = *(const bf16x8*)&sxc[mi*16 + col][kc*32 + quad*8];
        acc[mi] = __builtin_amdgcn_mfma_f32_16x16x32_bf16(af, bfr, acc[mi], 0, 0, 0);
      }
    }
    #pragma unroll
    for (int mi=0;mi<4;mi++)
      #pragma unroll
      for (int r=0;r<4;r++)
        vls[mi*16 + quad*4 + r][wn + col] = acc[mi][r];
  }
  __syncthreads();

  // ---- phase 2: write vbc[t][40] ----
  #pragma unroll
  for (int p=0;p<10;p++){
    int j = p*256 + tid;
    int t = j / 40, i = j - t*40;
    if (j < 2560) vbc[(m0+t)*40 + i] = vls[t][i];
  }

  // ---- phase 3: scanA summary, thread = channel, explicit scalar state ----
  {
    const int d = tid;
    const float LOG2E = 1.4426950408889634f;
    const float a0 = -expf(alog[d*DST]) * LOG2E;
    bool fast = true;
    for (int s=1;s<16;s++){
      float as = -expf(alog[d*DST + s]) * LOG2E;
      fast = fast && (fabsf(as - (float)(s+1)*a0) <= 1e-3f*fabsf(as));
    }
    float4 w8a = *(const float4*)(dtw + d*8);
    float4 w8b = *(const float4*)(dtw + d*8 + 4);
    const float bd = dtb[d];
    float h0=0.f,h1=0.f,h2=0.f,h3=0.f,h4=0.f,h5=0.f,h6=0.f,h7=0.f;
    float h8=0.f,h9=0.f,h10=0.f,h11=0.f,h12=0.f,h13=0.f,h14=0.f,h15=0.f;
    float ssum = 0.f;
    if (fast){
      for (int t=0;t<SEG;t++){
        float4 v0 = *(const float4*)&vls[t][0];
        float4 v1 = *(const float4*)&vls[t][4];
        float lin = bd;
        lin = fmaf(v0.x,w8a.x, fmaf(v0.y,w8a.y, fmaf(v0.z,w8a.z, fmaf(v0.w,w8a.w, lin))));
        lin = fmaf(v1.x,w8b.x, fmaf(v1.y,w8b.y, fmaf(v1.z,w8b.z, fmaf(v1.w,w8b.w, lin))));
        float dt = softplusf(lin);
        ssum += dt;
        float u = xcg[(m0+t)*DIN + d];
        float du = dt*u;
        float r = exp2f(dt*a0);
        float dA = 1.f;
        float4 q0 = *(const float4*)&vls[t][8];
        float4 q1 = *(const float4*)&vls[t][12];
        float4 q2 = *(const float4*)&vls[t][16];
        float4 q3 = *(const float4*)&vls[t][20];
        float4 q4 = *(const float4*)&vls[t][24];
        float4 q5 = *(const float4*)&vls[t][28];
        float4 q6 = *(const float4*)&vls[t][32];
        float4 q7 = *(const float4*)&vls[t][36];
        SPF(h0,h1,q0)  SPF(h2,h3,q1)  SPF(h4,h5,q2)  SPF(h6,h7,q3)
        SPF(h8,h9,q4)  SPF(h10,h11,q5) SPF(h12,h13,q6) SPF(h14,h15,q7)
      }
    } else {
      for (int t=0;t<SEG;t++){
        float4 v0 = *(const float4*)&vls[t][0];
        float4 v1 = *(const float4*)&vls[t][4];
        float lin = bd;
        lin = fmaf(v0.x,w8a.x, fmaf(v0.y,w8a.y, fmaf(v0.z,w8a.z, fmaf(v0.w,w8a.w, lin))));
        lin = fmaf(v1.x,w8b.x, fmaf(v1.y,w8b.y, fmaf(v1.z,w8b.z, fmaf(v1.w,w8b.w, lin))));
        float dt = softplusf(lin);
        ssum += dt;
        float u = xcg[(m0+t)*DIN + d];
        float du = dt*u;
        float4 q0 = *(const float4*)&vls[t][8];
        float4 q1 = *(const float4*)&vls[t][12];
        float4 q2 = *(const float4*)&vls[t][16];
        float4 q3 = *(const float4*)&vls[t][20];
        float4 q4 = *(const float4*)&vls[t][24];
        float4 q5 = *(const float4*)&vls[t][28];
        float4 q6 = *(const float4*)&vls[t][32];
        float4 q7 = *(const float4*)&vls[t][36];
        SPSA(h0,h1,q0,0,1)   SPSA(h2,h3,q1,2,3)   SPSA(h4,h5,q2,4,5)   SPSA(h6,h7,q3,6,7)
        SPSA(h8,h9,q4,8,9)   SPSA(h10,h11,q5,10,11) SPSA(h12,h13,q6,12,13) SPSA(h14,h15,q7,14,15)
      }
    }
    size_t base = (((size_t)b*NSEG + g)*DIN + d)*DST;
    float4 o;
    o.x=h0; o.y=h1; o.z=h2; o.w=h3;     *(float4*)(cseg + base     ) = o;
    o.x=h4; o.y=h5; o.z=h6; o.w=h7;     *(float4*)(cseg + base +  4) = o;
    o.x=h8; o.y=h9; o.z=h10; o.w=h11;   *(float4*)(cseg + base +  8) = o;
    o.x=h12; o.y=h13; o.z=h14; o.w=h15; *(float4*)(cseg + base + 12) = o;
    sdtb[((size_t)b*NSEG + g)*DIN + d] = ssum;
  }
}

// ---------------- scanB: serial combine over segments ----------------
__global__ __launch_bounds__(256) void k_scanB(float* __restrict__ cseg,
    const float* __restrict__ sdtb, const float* __restrict__ alog){
  int gl = blockIdx.x*256 + threadIdx.x;
  int b   = gl >> 12;
  int rem = gl & 4095;
  int d = rem >> 4, s = rem & 15;
  const float LOG2E = 1.4426950408889634f;
  const float a = -expf(alog[d*DST + s]) * LOG2E;
  float h = 0.f;
  for (int g=0; g<NSEG; g++){
    size_t base = ((size_t)b*NSEG + g)*DIN;
    float sd = sdtb[base + d];
    size_t ci = (base + d)*DST + s;
    float c = cseg[ci];
    cseg[ci] = h;
    h = fmaf(exp2f(a*sd), h, c);
  }
}

// ---------------- scanC2: thread = channel, explicit scalar state, fused gate ------
__global__ __launch_bounds__(256) void k_scanC2(float* __restrict__ xcg,
    const float* __restrict__ vbc, const __bf16* __restrict__ zb,
    const float* __restrict__ dtw, const float* __restrict__ dtb,
    const float* __restrict__ alog, const float* __restrict__ Dpar,
    const float* __restrict__ cseg){
  __shared__ float svbc[64][40];
  const int tid = threadIdx.x;
  const size_t m0 = (size_t)blockIdx.x * 64;
  const int b = (int)(m0 >> 11);
  const int g = (int)((m0 >> 6) & (NSEG-1));

  #pragma unroll
  for (int p=0;p<10;p++){
    int j = p*256 + tid;
    int t = j / 40, i = j - t*40;
    if (j < 2560) svbc[t][i] = vbc[(m0+t)*40 + i];
  }

  const int d = tid;
  const float LOG2E = 1.4426950408889634f;
  const float a0 = -expf(alog[d*DST]) * LOG2E;
  bool fast = true;
  for (int s=1;s<16;s++){
    float as = -expf(alog[d*DST + s]) * LOG2E;
    fast = fast && (fabsf(as - (float)(s+1)*a0) <= 1e-3f*fabsf(as));
  }
  float4 w8a = *(const float4*)(dtw + d*8);
  float4 w8b = *(const float4*)(dtw + d*8 + 4);
  const float bd = dtb[d];
  const float Dv = Dpar[d];
  size_t base = (((size_t)b*NSEG + g)*DIN + d)*DST;
  float4 hv0 = *(const float4*)(cseg + base);
  float4 hv1 = *(const float4*)(cseg + base + 4);
  float4 hv2 = *(const float4*)(cseg + base + 8);
  float4 hv3 = *(const float4*)(cseg + base + 12);
  float h0=hv0.x,h1=hv0.y,h2=hv0.z,h3=hv0.w;
  float h4=hv1.x,h5=hv1.y,h6=hv1.z,h7=hv1.w;
  float h8=hv2.x,h9=hv2.y,h10=hv2.z,h11=hv2.w;
  float h12=hv3.x,h13=hv3.y,h14=hv3.z,h15=hv3.w;
  __syncthreads();

  if (fast){
    for (int t=0;t<SEG;t++){
      float4 v0 = *(const float4*)&svbc[t][0];
      float4 v1 = *(const float4*)&svbc[t][4];
      float lin = bd;
      lin = fmaf(v0.x,w8a.x, fmaf(v0.y,w8a.y, fmaf(v0.z,w8a.z, fmaf(v0.w,w8a.w, lin))));
      lin = fmaf(v1.x,w8b.x, fmaf(v1.y,w8b.y, fmaf(v1.z,w8b.z, fmaf(v1.w,w8b.w, lin))));
      float dt = softplusf(lin);
      float u = xcg[(m0+t)*DIN + d];
      float du = dt*u;
      float r = exp2f(dt*a0);
      float dA = 1.f, y = 0.f;
      float4 q0 = *(const float4*)&svbc[t][8];
      float4 q1 = *(const float4*)&svbc[t][12];
      float4 q2 = *(const float4*)&svbc[t][16];
      float4 q3 = *(const float4*)&svbc[t][20];
      float4 q4 = *(const float4*)&svbc[t][24];
      float4 q5 = *(const float4*)&svbc[t][28];
      float4 q6 = *(const float4*)&svbc[t][32];
      float4 q7 = *(const float4*)&svbc[t][36];
      SPFY(h0,h1,q0)  SPFY(h2,h3,q1)  SPFY(h4,h5,q2)  SPFY(h6,h7,q3)
      SPFY(h8,h9,q4)  SPFY(h10,h11,q5) SPFY(h12,h13,q6) SPFY(h14,h15,q7)
      float zf = (float)zb[(m0+t)*DIN + d];
      xcg[(m0+t)*DIN + d] = (y + u*Dv) * siluf(zf);
    }
  } else {
    for (int t=0;t<SEG;t++){
      float4 v0 = *(const float4*)&svbc[t][0];
      float4 v1 = *(const float4*)&svbc[t][4];
      float lin = bd;
      lin = fmaf(v0.x,w8a.x, fmaf(v0.y,w8a.y, fmaf(v0.z,w8a.z, fmaf(v0.w,w8a.w, lin))));
      lin = fmaf(v1.x,w8b.x, fmaf(v1.y,w8b.y, fmaf(v1.z,w8b.z, fmaf(v1.w,w8b.w, lin))));
      float dt = softplusf(lin);
      float u = xcg[(m0+t)*DIN + d];
      float du = dt*u;
      float y = 0.f;
      float4 q0 = *(const float4*)&svbc[t][8];
      float4 q1 = *(const float4*)&svbc[t][12];
      float4 q2 = *(const float4*)&svbc[t][16];
      float4 q3 = *(const float4*)&svbc[t][20];
      float4 q4 = *(const float4*)&svbc[t][24];
      float4 q5 = *(const float4*)&svbc[t][28];
      float4 q6 = *(const float4*)&svbc[t][32];
      float4 q7 = *(const float4*)&svbc[t][36];
      SPSY(h0,h1,q0,0,1)   SPSY(h2,h3,q1,2,3)   SPSY(h4,h5,q2,4,5)   SPSY(h6,h7,q3,6,7)
      SPSY(h8,h9,q4,8,9)   SPSY(h10,h11,q5,10,11) SPSY(h12,h13,q6,12,13) SPSY(h14,h15,q7,14,15)
      float zf = (float)zb[(m0+t)*DIN + d];
      xcg[(m0+t)*DIN + d] = (y + u*Dv) * siluf(zf);
    }
  }
}

// ---------------- masked mean pool over a chunk ----------------
__global__ __launch_bounds__(256) void k_pool1(const float* __restrict__ x,
    const float* __restrict__ mask, float* __restrict__ part, float* __restrict__ pmask){
  int b = blockIdx.y, seg = blockIdx.x;
  int d = threadIdx.x & 127, half = threadIdx.x >> 7;
  int t0 = seg*128 + half*64;
  float acc = 0.f, macc = 0.f;
  for (int i=0;i<64;i++){
    int t = t0 + i;
    float mv = mask[(size_t)b*SL + t];
    acc = fmaf(x[((size_t)b*SL + t)*DMODEL + d], mv, acc);
    macc += mv;
  }
  __shared__ float sm[256];
  __shared__ float smm[2];
  sm[threadIdx.x] = acc;
  if (d == 0) smm[half] = macc;
  __syncthreads();
  if (half == 0){
    part[((size_t)b*16 + seg)*128 + d] = sm[d] + sm[128+d];
    if (d == 0) pmask[b*16 + seg] = smm[0] + smm[1];
  }
}

__global__ void k_pool2(const float* __restrict__ part, const float* __restrict__ pmask,
                        float* __restrict__ pooled){
  int b = blockIdx.x, d = threadIdx.x;
  float acc = 0.f, ms = 0.f;
  for (int s=0;s<16;s++){ acc += part[((size_t)b*16+s)*128 + d]; ms += pmask[b*16+s]; }
  pooled[(size_t)b*128 + d] = acc / fmaxf(ms, 1e-9f);
}

// ---------------- tiny MLP ----------------
__global__ void k_mlp_a(const float* __restrict__ in, const float* __restrict__ w,
                        const float* __restrict__ bias, float* __restrict__ out, int K){
  int b = blockIdx.y;
  int n = blockIdx.x*128 + threadIdx.x;
  const float4* pw = (const float4*)(w + (size_t)n*K);
  const float4* pi = (const float4*)(in + (size_t)b*K);
  float acc = 0.f;
  for (int k=0;k<K/4;k++){
    float4 a = pi[k], ww = pw[k];
    acc = fmaf(a.x,ww.x, fmaf(a.y,ww.y, fmaf(a.z,ww.z, fmaf(a.w,ww.w, acc))));
  }
  out[(size_t)b*512 + n] = fmaxf(acc + bias[n], 0.f);
}

__global__ void k_mlp3(const float* __restrict__ h, const float* __restrict__ w,
                       const float* __restrict__ bias, float* __restrict__ out){
  int b = blockIdx.x;
  int n = threadIdx.x >> 6, lane = threadIdx.x & 63;
  if (n >= 3) return;
  float acc = 0.f;
  for (int k=lane; k<512; k+=64) acc = fmaf(h[(size_t)b*512+k], w[(size_t)n*512+k], acc);
  #pragma unroll
  for (int m=1;m<64;m<<=1) acc += __shfl_xor(acc, m);
  if (lane == 0) out[(size_t)b*3 + n] = acc + bias[n];
}

// ---------------- launch ----------------
extern "C" void kernel_launch(void* const* d_in, const int* in_sizes, int n_in,
                              void* d_out, int out_size, void* d_ws, size_t ws_size,
                              hipStream_t stream){
  const int*   tokens = (const int*)  d_in[0];
  const float* mask   = (const float*)d_in[1];
  const float* emb    = (const float*)d_in[2];
  const float* bn_w   = (const float*)d_in[3];
  const float* bn_b   = (const float*)d_in[4];
  const float* conv_w = (const float*)d_in[5];
  const float* conv_b = (const float*)d_in[6];
  const float* in_w   = (const float*)d_in[7];
  const float* c1_w   = (const float*)d_in[8];
  const float* c1_b   = (const float*)d_in[9];
  const float* xp_w   = (const float*)d_in[10];
  const float* dtp_w  = (const float*)d_in[11];
  const float* dtp_b  = (const float*)d_in[12];
  const float* A_log  = (const float*)d_in[13];
  const float* D_par  = (const float*)d_in[14];
  const float* out_w  = (const float*)d_in[15];
  const float* nrm_w  = (const float*)d_in[16];
  const float* l1w = (const float*)d_in[17]; const float* l1b = (const float*)d_in[18];
  const float* l2w = (const float*)d_in[19]; const float* l2b = (const float*)d_in[20];
  const float* l3w = (const float*)d_in[21]; const float* l3b = (const float*)d_in[22];
  float* dout = (float*)d_out;

  // per-token floats: x 128 + rs 1 + xi 256 + xc 256 + vbc 40 + cseg 64 + sdt 4 + z(bf16) 128 = 877
  int CB = 64;
  while (CB > 1 && ((size_t)CB*SL*877 + FIX_END)*4 > ws_size) CB >>= 1;
  if (((size_t)CB*SL*877 + FIX_END)*4 > ws_size) return;
  const size_t CTOK = (size_t)CB*SL;

  float* ws  = (float*)d_ws;
  float* pl  = ws + FIX_PL;
  float* pm  = ws + FIX_PM;
  float* pd  = ws + FIX_PD;
  float* h1  = ws + FIX_H1;
  float* h2  = ws + FIX_H2;
  __bf16* wpb   = (__bf16*)(ws + FIX_WP);
  __bf16* w2b   = (__bf16*)(ws + FIX_W2B);
  __bf16* winb  = (__bf16*)(ws + FIX_WINB);
  __bf16* woutb = (__bf16*)(ws + FIX_WOUTB);
  float* xcb = ws + FIX_END;                 // CTOK*128 residual x
  float* rs  = xcb + CTOK*128;               // CTOK
  float* xi  = rs  + CTOK;                   // CTOK*256 (embed pad / x-branch)
  float* xc  = xi  + CTOK*256;               // CTOK*256 (conv out -> gated y in place)
  float* vbc = xc  + CTOK*256;               // CTOK*40
  float* csg = vbc + CTOK*40;                // CTOK*64
  float* sdt = csg + CTOK*64;                // CTOK*4
  __bf16* zb = (__bf16*)(sdt + CTOK*4);      // CTOK*256 bf16

  k_w2b<<<192, 256, 0, stream>>>(conv_w, w2b);
  k_cvt<<<1024, 256, 0, stream>>>(in_w,  winb,  4*512*128);
  k_cvt<<<512,  256, 0, stream>>>(out_w, woutb, 4*128*256);
  k_wprep<<<256, 256, 0, stream>>>(xp_w, wpb);

  const int nchunks = NB / CB;
  for (int c = 0; c < nchunks; c++){
    const int* tok_c = tokens + (size_t)c*CTOK;

    k_embed<<<CB*2050, 128, 0, stream>>>(tok_c, emb, bn_w, bn_b, xi);
    k_mgemm<0,384,128><<<dim3(1, CTOK/128), 256, 0, stream>>>(
        xi, w2b, conv_b, nullptr, nullptr, xcb, nullptr);

    for (int layer = 0; layer < NLAYER; layer++){
      const __bf16* lin = winb  + (size_t)layer*512*128;
      const float* lcw  = c1_w  + (size_t)layer*DIN*4;
      const float* lcb  = c1_b  + (size_t)layer*DIN;
      const float* ldw  = dtp_w + (size_t)layer*DIN*8;
      const float* ldb  = dtp_b + (size_t)layer*DIN;
      const float* lal  = A_log + (size_t)layer*DIN*DST;
      const float* lD   = D_par + (size_t)layer*DIN;
      const __bf16* low = woutb + (size_t)layer*128*256;
      const float* lnw  = nrm_w + (size_t)layer*128;

      k_rmsscale<<<CTOK/4, 256, 0, stream>>>(xcb, rs);
      k_mgemm<1,128,512><<<dim3(4, CTOK/128), 256, 0, stream>>>(
          xcb, lin, nullptr, rs, lnw, xi, zb);
      k_seg<<<(int)(CTOK/64), 256, 0, stream>>>(
          xi, xc, wpb + (size_t)layer*64*256, lcw, lcb, ldw, ldb, lal, vbc, csg, sdt);
      k_scanB<<<CB*16, 256, 0, stream>>>(csg, sdt, lal);
      k_scanC2<<<(int)(CTOK/64), 256, 0, stream>>>(
          xc, vbc, zb, ldw, ldb, lal, lD, csg);
      k_mgemm<2,256,128><<<dim3(1, CTOK/128), 256, 0, stream>>>(
          xc, low, nullptr, nullptr, nullptr, xcb, nullptr);
    }

    k_pool1<<<dim3(16, CB), 256, 0, stream>>>(
        xcb, mask + (size_t)c*CTOK, pl + (size_t)c*CB*16*128, pm + (size_t)c*CB*16);
  }

  k_pool2<<<NB, 128, 0, stream>>>(pl, pm, pd);
  k_mlp_a<<<dim3(4, NB), 128, 0, stream>>>(pd, l1w, l1b, h1, 128);
  k_mlp_a<<<dim3(4, NB), 128, 0, stream>>>(h1, l2w, l2b, h2, 512);
  k_mlp3<<<NB, 256, 0, stream>>>(h2, l3w, l3b, dout);
}

// Round 11
// 2891.876 us; speedup vs baseline: 6.1114x; 1.2620x over previous
//
#include <hip/hip_runtime.h>
#include <math.h>

// ---------------- problem constants ----------------
#define NB     64
#define SL     2048
#define NTOK   (NB*SL)
#define EMB_D  128
#define DMODEL 128
#define DIN    256
#define DST    16
#define NLAYER 4
#define SEG    64
#define NSEG   (SL/SEG)        // 32

typedef __bf16 bf16x8 __attribute__((ext_vector_type(8)));
typedef __bf16 bf16x4 __attribute__((ext_vector_type(4)));
typedef float  f32x4  __attribute__((ext_vector_type(4)));

// fixed small region (floats)
#define FIX_PL   ((size_t)0)
#define FIX_PM   (FIX_PL + 131072)
#define FIX_PD   (FIX_PM + 1024)
#define FIX_H1   (FIX_PD + 8192)
#define FIX_H2   (FIX_H1 + 32768)
#define FIX_WP   (FIX_H2 + 32768)
#define FIX_W2B  (FIX_WP + 65536)
#define FIX_WINB (FIX_W2B + 24576)
#define FIX_WOUTB (FIX_WINB + 131072)
#define FIX_END  (FIX_WOUTB + 65536)

__device__ __forceinline__ float siluf(float v){ return v / (1.f + expf(-v)); }
__device__ __forceinline__ float softplusf(float a){
  return (a > 0.f) ? (a + log1pf(expf(-a))) : log1pf(expf(a));
}

// state-pair update macros (explicit scalars)
#define SPF(hA,hB,q)  { dA*=r; hA=fmaf(dA,hA,du*q.x); dA*=r; hB=fmaf(dA,hB,du*q.z); }
#define SPFY(hA,hB,q) { dA*=r; hA=fmaf(dA,hA,du*q.x); y=fmaf(hA,q.y,y); \
                        dA*=r; hB=fmaf(dA,hB,du*q.z); y=fmaf(hB,q.w,y); }
#define SPSA(hA,hB,q,s0,s1) { float eA=exp2f(dt*(-expf(alog[d*DST+s0])*LOG2E)); \
                              hA=fmaf(eA,hA,du*q.x); \
                              float eB=exp2f(dt*(-expf(alog[d*DST+s1])*LOG2E)); \
                              hB=fmaf(eB,hB,du*q.z); }
#define SPSY(hA,hB,q,s0,s1) { float eA=exp2f(dt*(-expf(alog[d*DST+s0])*LOG2E)); \
                              hA=fmaf(eA,hA,du*q.x); y=fmaf(hA,q.y,y); \
                              float eB=exp2f(dt*(-expf(alog[d*DST+s1])*LOG2E)); \
                              hB=fmaf(eB,hB,du*q.z); y=fmaf(hB,q.w,y); }

// ---------------- weight prep ----------------
__global__ void k_w2b(const float* __restrict__ cw, __bf16* __restrict__ w2){
  int g = blockIdx.x*256 + threadIdx.x;
  if (g >= 128*384) return;
  int d = g / 384, j = g % 384;
  int k = j >> 7, e = j & 127;
  w2[d*384 + k*128 + e] = (__bf16)cw[d*384 + e*3 + k];
}

__global__ void k_cvt(const float* __restrict__ src, __bf16* __restrict__ dst, int n){
  int i = blockIdx.x*256 + threadIdx.x;
  if (i < n) dst[i] = (__bf16)src[i];
}

__global__ void k_wprep(const float* __restrict__ xpw, __bf16* __restrict__ wp){
  int g = blockIdx.x*256 + threadIdx.x;      // 65536
  int l = g >> 14, rem = g & 16383;
  int n = rem >> 8, k = rem & 255;
  float v = 0.f;
  if (n < 8){
    v = xpw[(size_t)l*40*256 + n*256 + k];
  } else if (n < 40){
    int i = n - 8;
    int row = 8 + ((i&1)<<4) + (i>>1);
    v = xpw[(size_t)l*40*256 + row*256 + k];
  }
  wp[g] = (__bf16)v;
}

// ---------------- embed + BN into padded chunk buffer ----------------
__global__ void k_embed(const int* __restrict__ tok, const float* __restrict__ emb,
                        const float* __restrict__ bnw, const float* __restrict__ bnb,
                        float* __restrict__ xp){
  int r = blockIdx.x;                 // CB*2050 rows
  int e = threadIdx.x;                // 128
  int b = r / 2050, tp = r % 2050;
  float v = 0.f;
  if (tp != 0 && tp != 2049){
    int t = tp - 1;
    int id = tok[(size_t)b*SL + t];
    float s = bnw[e] * rsqrtf(1.0f + 1e-5f);
    v = emb[(size_t)id*EMB_D + e] * s + bnb[e];
  }
  xp[(size_t)r*EMB_D + e] = v;
}

// ---------------- rmsnorm scale only ----------------
__global__ __launch_bounds__(256) void k_rmsscale(const float* __restrict__ x,
                                                  float* __restrict__ rs){
  int wv = threadIdx.x>>6, lane = threadIdx.x&63;
  size_t tok = (size_t)blockIdx.x*4 + wv;
  float2 v = *(const float2*)(x + tok*128 + lane*2);
  float ss = v.x*v.x + v.y*v.y;
  #pragma unroll
  for (int m=1;m<64;m<<=1) ss += __shfl_xor(ss, m);
  float r = rsqrtf(ss*(1.f/128.f) + 1e-5f);
  if (lane == 0) rs[tok] = r;
}

// ---------------- bf16 MFMA GEMM  out[M,N] = A[M,K] @ W[N,K]^T ----------------
// MODE 1 epilogue now stores gz = silu(z) bf16.
template<int MODE, int K, int N>
__global__ __launch_bounds__(256) void k_mgemm(
    const float* __restrict__ A, const __bf16* __restrict__ Wb,
    const float* __restrict__ bias, const float* __restrict__ rsp,
    const float* __restrict__ nwp,
    float* __restrict__ out, __bf16* __restrict__ outz){
  __shared__ __bf16 As[128][40];
  __shared__ __bf16 Bs[128][40];
  const int tid  = threadIdx.x;
  const int wave = tid >> 6;
  const int lane = tid & 63;
  const int col  = lane & 15;
  const int quad = lane >> 4;
  const int wm = (wave & 1) * 64;
  const int wn = (wave >> 1) * 64;
  const int m0 = blockIdx.y * 128;
  const int n0 = blockIdx.x * 128;

  f32x4 acc[4][4];
  #pragma unroll
  for (int i=0;i<4;i++)
    #pragma unroll
    for (int j=0;j<4;j++) acc[i][j] = (f32x4){0.f,0.f,0.f,0.f};

  size_t abase;
  if constexpr(MODE==0){
    int bb = m0 >> 11, tloc = m0 & 2047;
    abase = ((size_t)bb*2050 + tloc) * 128;
  } else {
    abase = (size_t)m0 * K;
  }

  const int sm = tid >> 3;
  const int sk4 = (tid & 7) * 4;
  const int bn = tid >> 2;
  const int bk8 = (tid & 3) * 8;

  for (int k0 = 0; k0 < K; k0 += 32){
    #pragma unroll
    for (int p=0;p<4;p++){
      int m = p*32 + sm;
      float4 v;
      if constexpr(MODE==0){
        v = *(const float4*)(A + abase + (size_t)m*128 + k0 + sk4);
      } else if constexpr(MODE==1){
        float4 x4 = *(const float4*)(A + abase + (size_t)m*K + k0 + sk4);
        float4 w4 = *(const float4*)(nwp + k0 + sk4);
        float s = rsp[m0 + m];
        v.x = x4.x*s*w4.x; v.y = x4.y*s*w4.y; v.z = x4.z*s*w4.z; v.w = x4.w*s*w4.w;
      } else {
        v = *(const float4*)(A + abase + (size_t)m*K + k0 + sk4);
      }
      bf16x4 o;
      o[0] = (__bf16)v.x; o[1] = (__bf16)v.y; o[2] = (__bf16)v.z; o[3] = (__bf16)v.w;
      *(bf16x4*)&As[m][sk4] = o;
    }
    #pragma unroll
    for (int p=0;p<2;p++){
      int n = p*64 + bn;
      bf16x8 w = *(const bf16x8*)(Wb + (size_t)(n0+n)*K + k0 + bk8);
      *(bf16x8*)&Bs[n][bk8] = w;
    }
    __syncthreads();
    bf16x8 af[4], bfr[4];
    const int fq = quad*8;
    #pragma unroll
    for (int i=0;i<4;i++) af[i]  = *(const bf16x8*)&As[wm + i*16 + col][fq];
    #pragma unroll
    for (int j=0;j<4;j++) bfr[j] = *(const bf16x8*)&Bs[wn + j*16 + col][fq];
    #pragma unroll
    for (int i=0;i<4;i++)
      #pragma unroll
      for (int j=0;j<4;j++)
        acc[i][j] = __builtin_amdgcn_mfma_f32_16x16x32_bf16(af[i], bfr[j], acc[i][j], 0, 0, 0);
    __syncthreads();
  }

  #pragma unroll
  for (int i=0;i<4;i++){
    #pragma unroll
    for (int j=0;j<4;j++){
      int n_l = wn + j*16 + col;
      #pragma unroll
      for (int r=0;r<4;r++){
        int m = m0 + wm + i*16 + quad*4 + r;
        float c = acc[i][j][r];
        if constexpr(MODE==0){
          int n = n0 + n_l;
          out[(size_t)m*DMODEL + n] = fmaxf(c + bias[n], 0.f);
        } else if constexpr(MODE==1){
          int n = n0 + n_l;
          if (n < DIN) out [(size_t)m*DIN + n]        = c;
          else         outz[(size_t)m*DIN + n - DIN]  = (__bf16)siluf(c);
        } else {
          float* p = out + (size_t)m*DMODEL + n0 + n_l;
          *p = *p + c;
        }
      }
    }
  }
}

// ---------------- fused segment front: dwconv+silu -> MFMA x_proj -> vbc/dt -> scanA summary
__global__ __launch_bounds__(256) void k_seg(const float* __restrict__ xi,
    float* __restrict__ xcg, const __bf16* __restrict__ wpb,
    const float* __restrict__ cw, const float* __restrict__ cb,
    const float* __restrict__ dtw, const float* __restrict__ dtb,
    const float* __restrict__ alog,
    float* __restrict__ vbc, __bf16* __restrict__ dtg,
    float* __restrict__ cseg, float* __restrict__ sdtb){
  __shared__ __bf16 sxc[64][264];
  __shared__ float vls[64][68];
  const int tid = threadIdx.x;
  const size_t m0 = (size_t)blockIdx.x * 64;
  const int b = (int)(m0 >> 11);
  const int g = (int)((m0 >> 6) & (NSEG-1));
  const int seq0 = (int)(m0 & 2047);

  // ---- phase 0: depthwise conv(k=4) + silu -> xcg (fp32) + sxc (bf16 LDS) ----
  {
    const int c4 = (tid & 63) * 4;
    const int tw = tid >> 6;
    float wc[4][4];
    #pragma unroll
    for (int j=0;j<4;j++)
      #pragma unroll
      for (int k=0;k<4;k++) wc[j][k] = cw[(c4+j)*4 + k];
    float4 cb4 = *(const float4*)(cb + c4);
    #pragma unroll
    for (int it=0; it<16; it++){
      int t = it*4 + tw;
      float4 acc = cb4;
      #pragma unroll
      for (int k=0;k<4;k++){
        if (seq0 + t - 3 + k >= 0){
          float4 xv = *(const float4*)(xi + (m0 + t - 3 + k)*DIN + c4);
          acc.x = fmaf(wc[0][k], xv.x, acc.x);
          acc.y = fmaf(wc[1][k], xv.y, acc.y);
          acc.z = fmaf(wc[2][k], xv.z, acc.z);
          acc.w = fmaf(wc[3][k], xv.w, acc.w);
        }
      }
      acc.x = siluf(acc.x); acc.y = siluf(acc.y);
      acc.z = siluf(acc.z); acc.w = siluf(acc.w);
      *(float4*)(xcg + (m0 + t)*DIN + c4) = acc;
      bf16x4 o;
      o[0]=(__bf16)acc.x; o[1]=(__bf16)acc.y; o[2]=(__bf16)acc.z; o[3]=(__bf16)acc.w;
      *(bf16x4*)&sxc[t][c4] = o;
    }
  }
  __syncthreads();

  // ---- phase 1: MFMA vls[64][64] = sxc[64x256] @ wpb[64x256]^T ----
  {
    const int wave = tid >> 6, lane = tid & 63;
    const int col = lane & 15, quad = lane >> 4;
    const int wn = wave * 16;
    f32x4 acc[4];
    #pragma unroll
    for (int i=0;i<4;i++) acc[i] = (f32x4){0.f,0.f,0.f,0.f};
    #pragma unroll
    for (int kc=0;kc<8;kc++){
      bf16x8 bfr = *(const bf16x8*)(wpb + (size_t)(wn+col)*256 + kc*32 + quad*8);
      #pragma unroll
      for (int mi=0;mi<4;mi++){
        bf16x8 af = *(const bf16x8*)&sxc[mi*16 + col][kc*32 + quad*8];
        acc[mi] = __builtin_amdgcn_mfma_f32_16x16x32_bf16(af, bfr, acc[mi], 0, 0, 0);
      }
    }
    #pragma unroll
    for (int mi=0;mi<4;mi++)
      #pragma unroll
      for (int r=0;r<4;r++)
        vls[mi*16 + quad*4 + r][wn + col] = acc[mi][r];
  }
  __syncthreads();

  // ---- phase 2: write vbc[t][32] = BC only ----
  #pragma unroll
  for (int p=0;p<8;p++){
    int j = p*256 + tid;           // 2048
    int t = j >> 5, i = j & 31;
    vbc[(m0+t)*32 + i] = vls[t][8+i];
  }

  // ---- phase 3: scanA summary, thread = channel, explicit scalar state; store dt bf16 ----
  {
    const int d = tid;
    const float LOG2E = 1.4426950408889634f;
    const float a0 = -expf(alog[d*DST]) * LOG2E;
    bool fast = true;
    for (int s=1;s<16;s++){
      float as = -expf(alog[d*DST + s]) * LOG2E;
      fast = fast && (fabsf(as - (float)(s+1)*a0) <= 1e-3f*fabsf(as));
    }
    float4 w8a = *(const float4*)(dtw + d*8);
    float4 w8b = *(const float4*)(dtw + d*8 + 4);
    const float bd = dtb[d];
    float h0=0.f,h1=0.f,h2=0.f,h3=0.f,h4=0.f,h5=0.f,h6=0.f,h7=0.f;
    float h8=0.f,h9=0.f,h10=0.f,h11=0.f,h12=0.f,h13=0.f,h14=0.f,h15=0.f;
    float ssum = 0.f;
    if (fast){
      for (int t=0;t<SEG;t++){
        float4 v0 = *(const float4*)&vls[t][0];
        float4 v1 = *(const float4*)&vls[t][4];
        float lin = bd;
        lin = fmaf(v0.x,w8a.x, fmaf(v0.y,w8a.y, fmaf(v0.z,w8a.z, fmaf(v0.w,w8a.w, lin))));
        lin = fmaf(v1.x,w8b.x, fmaf(v1.y,w8b.y, fmaf(v1.z,w8b.z, fmaf(v1.w,w8b.w, lin))));
        float dt = softplusf(lin);
        ssum += dt;
        dtg[(m0+t)*DIN + d] = (__bf16)dt;
        float u = xcg[(m0+t)*DIN + d];
        float du = dt*u;
        float r = exp2f(dt*a0);
        float dA = 1.f;
        float4 q0 = *(const float4*)&vls[t][8];
        float4 q1 = *(const float4*)&vls[t][12];
        float4 q2 = *(const float4*)&vls[t][16];
        float4 q3 = *(const float4*)&vls[t][20];
        float4 q4 = *(const float4*)&vls[t][24];
        float4 q5 = *(const float4*)&vls[t][28];
        float4 q6 = *(const float4*)&vls[t][32];
        float4 q7 = *(const float4*)&vls[t][36];
        SPF(h0,h1,q0)  SPF(h2,h3,q1)  SPF(h4,h5,q2)  SPF(h6,h7,q3)
        SPF(h8,h9,q4)  SPF(h10,h11,q5) SPF(h12,h13,q6) SPF(h14,h15,q7)
      }
    } else {
      for (int t=0;t<SEG;t++){
        float4 v0 = *(const float4*)&vls[t][0];
        float4 v1 = *(const float4*)&vls[t][4];
        float lin = bd;
        lin = fmaf(v0.x,w8a.x, fmaf(v0.y,w8a.y, fmaf(v0.z,w8a.z, fmaf(v0.w,w8a.w, lin))));
        lin = fmaf(v1.x,w8b.x, fmaf(v1.y,w8b.y, fmaf(v1.z,w8b.z, fmaf(v1.w,w8b.w, lin))));
        float dt = softplusf(lin);
        ssum += dt;
        dtg[(m0+t)*DIN + d] = (__bf16)dt;
        float u = xcg[(m0+t)*DIN + d];
        float du = dt*u;
        float4 q0 = *(const float4*)&vls[t][8];
        float4 q1 = *(const float4*)&vls[t][12];
        float4 q2 = *(const float4*)&vls[t][16];
        float4 q3 = *(const float4*)&vls[t][20];
        float4 q4 = *(const float4*)&vls[t][24];
        float4 q5 = *(const float4*)&vls[t][28];
        float4 q6 = *(const float4*)&vls[t][32];
        float4 q7 = *(const float4*)&vls[t][36];
        SPSA(h0,h1,q0,0,1)   SPSA(h2,h3,q1,2,3)   SPSA(h4,h5,q2,4,5)   SPSA(h6,h7,q3,6,7)
        SPSA(h8,h9,q4,8,9)   SPSA(h10,h11,q5,10,11) SPSA(h12,h13,q6,12,13) SPSA(h14,h15,q7,14,15)
      }
    }
    size_t base = (((size_t)b*NSEG + g)*DIN + d)*DST;
    float4 o;
    o.x=h0; o.y=h1; o.z=h2; o.w=h3;     *(float4*)(cseg + base     ) = o;
    o.x=h4; o.y=h5; o.z=h6; o.w=h7;     *(float4*)(cseg + base +  4) = o;
    o.x=h8; o.y=h9; o.z=h10; o.w=h11;   *(float4*)(cseg + base +  8) = o;
    o.x=h12; o.y=h13; o.z=h14; o.w=h15; *(float4*)(cseg + base + 12) = o;
    sdtb[((size_t)b*NSEG + g)*DIN + d] = ssum;
  }
}

// ---------------- scanB: serial combine over segments ----------------
__global__ __launch_bounds__(256) void k_scanB(float* __restrict__ cseg,
    const float* __restrict__ sdtb, const float* __restrict__ alog){
  int gl = blockIdx.x*256 + threadIdx.x;
  int b   = gl >> 12;
  int rem = gl & 4095;
  int d = rem >> 4, s = rem & 15;
  const float LOG2E = 1.4426950408889634f;
  const float a = -expf(alog[d*DST + s]) * LOG2E;
  float h = 0.f;
  for (int g=0; g<NSEG; g++){
    size_t base = ((size_t)b*NSEG + g)*DIN;
    float sd = sdtb[base + d];
    size_t ci = (base + d)*DST + s;
    float c = cseg[ci];
    cseg[ci] = h;
    h = fmaf(exp2f(a*sd), h, c);
  }
}

// ---------------- scanC2: thread = channel, precomputed dt/gz, fused gate ------
__global__ __launch_bounds__(256) void k_scanC2(float* __restrict__ xcg,
    const float* __restrict__ vbc, const __bf16* __restrict__ gzb,
    const __bf16* __restrict__ dtg,
    const float* __restrict__ alog, const float* __restrict__ Dpar,
    const float* __restrict__ cseg){
  __shared__ float svbc[64][32];
  const int tid = threadIdx.x;
  const size_t m0 = (size_t)blockIdx.x * 64;
  const int b = (int)(m0 >> 11);
  const int g = (int)((m0 >> 6) & (NSEG-1));

  #pragma unroll
  for (int p=0;p<8;p++){
    int j = p*256 + tid;           // 2048
    int t = j >> 5, i = j & 31;
    svbc[t][i] = vbc[(m0+t)*32 + i];
  }

  const int d = tid;
  const float LOG2E = 1.4426950408889634f;
  const float a0 = -expf(alog[d*DST]) * LOG2E;
  bool fast = true;
  for (int s=1;s<16;s++){
    float as = -expf(alog[d*DST + s]) * LOG2E;
    fast = fast && (fabsf(as - (float)(s+1)*a0) <= 1e-3f*fabsf(as));
  }
  const float Dv = Dpar[d];
  size_t base = (((size_t)b*NSEG + g)*DIN + d)*DST;
  float4 hv0 = *(const float4*)(cseg + base);
  float4 hv1 = *(const float4*)(cseg + base + 4);
  float4 hv2 = *(const float4*)(cseg + base + 8);
  float4 hv3 = *(const float4*)(cseg + base + 12);
  float h0=hv0.x,h1=hv0.y,h2=hv0.z,h3=hv0.w;
  float h4=hv1.x,h5=hv1.y,h6=hv1.z,h7=hv1.w;
  float h8=hv2.x,h9=hv2.y,h10=hv2.z,h11=hv2.w;
  float h12=hv3.x,h13=hv3.y,h14=hv3.z,h15=hv3.w;
  __syncthreads();

  if (fast){
    for (int t=0;t<SEG;t++){
      float dt = (float)dtg[(m0+t)*DIN + d];
      float u  = xcg[(m0+t)*DIN + d];
      float du = dt*u;
      float r = exp2f(dt*a0);
      float dA = 1.f, y = 0.f;
      float4 q0 = *(const float4*)&svbc[t][0];
      float4 q1 = *(const float4*)&svbc[t][4];
      float4 q2 = *(const float4*)&svbc[t][8];
      float4 q3 = *(const float4*)&svbc[t][12];
      float4 q4 = *(const float4*)&svbc[t][16];
      float4 q5 = *(const float4*)&svbc[t][20];
      float4 q6 = *(const float4*)&svbc[t][24];
      float4 q7 = *(const float4*)&svbc[t][28];
      SPFY(h0,h1,q0)  SPFY(h2,h3,q1)  SPFY(h4,h5,q2)  SPFY(h6,h7,q3)
      SPFY(h8,h9,q4)  SPFY(h10,h11,q5) SPFY(h12,h13,q6) SPFY(h14,h15,q7)
      float gz = (float)gzb[(m0+t)*DIN + d];
      xcg[(m0+t)*DIN + d] = (y + u*Dv) * gz;
    }
  } else {
    for (int t=0;t<SEG;t++){
      float dt = (float)dtg[(m0+t)*DIN + d];
      float u  = xcg[(m0+t)*DIN + d];
      float du = dt*u;
      float y = 0.f;
      float4 q0 = *(const float4*)&svbc[t][0];
      float4 q1 = *(const float4*)&svbc[t][4];
      float4 q2 = *(const float4*)&svbc[t][8];
      float4 q3 = *(const float4*)&svbc[t][12];
      float4 q4 = *(const float4*)&svbc[t][16];
      float4 q5 = *(const float4*)&svbc[t][20];
      float4 q6 = *(const float4*)&svbc[t][24];
      float4 q7 = *(const float4*)&svbc[t][28];
      SPSY(h0,h1,q0,0,1)   SPSY(h2,h3,q1,2,3)   SPSY(h4,h5,q2,4,5)   SPSY(h6,h7,q3,6,7)
      SPSY(h8,h9,q4,8,9)   SPSY(h10,h11,q5,10,11) SPSY(h12,h13,q6,12,13) SPSY(h14,h15,q7,14,15)
      float gz = (float)gzb[(m0+t)*DIN + d];
      xcg[(m0+t)*DIN + d] = (y + u*Dv) * gz;
    }
  }
}

// ---------------- masked mean pool over a chunk ----------------
__global__ __launch_bounds__(256) void k_pool1(const float* __restrict__ x,
    const float* __restrict__ mask, float* __restrict__ part, float* __restrict__ pmask){
  int b = blockIdx.y, seg = blockIdx.x;
  int d = threadIdx.x & 127, half = threadIdx.x >> 7;
  int t0 = seg*128 + half*64;
  float acc = 0.f, macc = 0.f;
  for (int i=0;i<64;i++){
    int t = t0 + i;
    float mv = mask[(size_t)b*SL + t];
    acc = fmaf(x[((size_t)b*SL + t)*DMODEL + d], mv, acc);
    macc += mv;
  }
  __shared__ float sm[256];
  __shared__ float smm[2];
  sm[threadIdx.x] = acc;
  if (d == 0) smm[half] = macc;
  __syncthreads();
  if (half == 0){
    part[((size_t)b*16 + seg)*128 + d] = sm[d] + sm[128+d];
    if (d == 0) pmask[b*16 + seg] = smm[0] + smm[1];
  }
}

__global__ void k_pool2(const float* __restrict__ part, const float* __restrict__ pmask,
                        float* __restrict__ pooled){
  int b = blockIdx.x, d = threadIdx.x;
  float acc = 0.f, ms = 0.f;
  for (int s=0;s<16;s++){ acc += part[((size_t)b*16+s)*128 + d]; ms += pmask[b*16+s]; }
  pooled[(size_t)b*128 + d] = acc / fmaxf(ms, 1e-9f);
}

// ---------------- tiny MLP ----------------
__global__ void k_mlp_a(const float* __restrict__ in, const float* __restrict__ w,
                        const float* __restrict__ bias, float* __restrict__ out, int K){
  int b = blockIdx.y;
  int n = blockIdx.x*128 + threadIdx.x;
  const float4* pw = (const float4*)(w + (size_t)n*K);
  const float4* pi = (const float4*)(in + (size_t)b*K);
  float acc = 0.f;
  for (int k=0;k<K/4;k++){
    float4 a = pi[k], ww = pw[k];
    acc = fmaf(a.x,ww.x, fmaf(a.y,ww.y, fmaf(a.z,ww.z, fmaf(a.w,ww.w, acc))));
  }
  out[(size_t)b*512 + n] = fmaxf(acc + bias[n], 0.f);
}

__global__ void k_mlp3(const float* __restrict__ h, const float* __restrict__ w,
                       const float* __restrict__ bias, float* __restrict__ out){
  int b = blockIdx.x;
  int n = threadIdx.x >> 6, lane = threadIdx.x & 63;
  if (n >= 3) return;
  float acc = 0.f;
  for (int k=lane; k<512; k+=64) acc = fmaf(h[(size_t)b*512+k], w[(size_t)n*512+k], acc);
  #pragma unroll
  for (int m=1;m<64;m<<=1) acc += __shfl_xor(acc, m);
  if (lane == 0) out[(size_t)b*3 + n] = acc + bias[n];
}

// ---------------- launch ----------------
extern "C" void kernel_launch(void* const* d_in, const int* in_sizes, int n_in,
                              void* d_out, int out_size, void* d_ws, size_t ws_size,
                              hipStream_t stream){
  const int*   tokens = (const int*)  d_in[0];
  const float* mask   = (const float*)d_in[1];
  const float* emb    = (const float*)d_in[2];
  const float* bn_w   = (const float*)d_in[3];
  const float* bn_b   = (const float*)d_in[4];
  const float* conv_w = (const float*)d_in[5];
  const float* conv_b = (const float*)d_in[6];
  const float* in_w   = (const float*)d_in[7];
  const float* c1_w   = (const float*)d_in[8];
  const float* c1_b   = (const float*)d_in[9];
  const float* xp_w   = (const float*)d_in[10];
  const float* dtp_w  = (const float*)d_in[11];
  const float* dtp_b  = (const float*)d_in[12];
  const float* A_log  = (const float*)d_in[13];
  const float* D_par  = (const float*)d_in[14];
  const float* out_w  = (const float*)d_in[15];
  const float* nrm_w  = (const float*)d_in[16];
  const float* l1w = (const float*)d_in[17]; const float* l1b = (const float*)d_in[18];
  const float* l2w = (const float*)d_in[19]; const float* l2b = (const float*)d_in[20];
  const float* l3w = (const float*)d_in[21]; const float* l3b = (const float*)d_in[22];
  float* dout = (float*)d_out;

  // per-token floats: x 128 + rs 1 + xi 256 + xc 256 + vbc 32 + cseg 64 + sdt 4
  //                   + gz(bf16) 128 + dt(bf16) 128 = 997
  int CB = 64;
  while (CB > 1 && ((size_t)CB*SL*997 + FIX_END)*4 > ws_size) CB >>= 1;
  if (((size_t)CB*SL*997 + FIX_END)*4 > ws_size) return;
  const size_t CTOK = (size_t)CB*SL;

  float* ws  = (float*)d_ws;
  float* pl  = ws + FIX_PL;
  float* pm  = ws + FIX_PM;
  float* pd  = ws + FIX_PD;
  float* h1  = ws + FIX_H1;
  float* h2  = ws + FIX_H2;
  __bf16* wpb   = (__bf16*)(ws + FIX_WP);
  __bf16* w2b   = (__bf16*)(ws + FIX_W2B);
  __bf16* winb  = (__bf16*)(ws + FIX_WINB);
  __bf16* woutb = (__bf16*)(ws + FIX_WOUTB);
  float* xcb = ws + FIX_END;                 // CTOK*128 residual x
  float* rs  = xcb + CTOK*128;               // CTOK
  float* xi  = rs  + CTOK;                   // CTOK*256 (embed pad / x-branch)
  float* xc  = xi  + CTOK*256;               // CTOK*256 (conv out -> gated y in place)
  float* vbc = xc  + CTOK*256;               // CTOK*32 (interleaved BC)
  float* csg = vbc + CTOK*32;                // CTOK*64
  float* sdt = csg + CTOK*64;                // CTOK*4
  __bf16* zb  = (__bf16*)(sdt + CTOK*4);     // CTOK*256 bf16 (gz = silu(z))
  __bf16* dtg = zb + CTOK*256;               // CTOK*256 bf16 (dt)

  k_w2b<<<192, 256, 0, stream>>>(conv_w, w2b);
  k_cvt<<<1024, 256, 0, stream>>>(in_w,  winb,  4*512*128);
  k_cvt<<<512,  256, 0, stream>>>(out_w, woutb, 4*128*256);
  k_wprep<<<256, 256, 0, stream>>>(xp_w, wpb);

  const int nchunks = NB / CB;
  for (int c = 0; c < nchunks; c++){
    const int* tok_c = tokens + (size_t)c*CTOK;

    k_embed<<<CB*2050, 128, 0, stream>>>(tok_c, emb, bn_w, bn_b, xi);
    k_mgemm<0,384,128><<<dim3(1, CTOK/128), 256, 0, stream>>>(
        xi, w2b, conv_b, nullptr, nullptr, xcb, nullptr);

    for (int layer = 0; layer < NLAYER; layer++){
      const __bf16* lin = winb  + (size_t)layer*512*128;
      const float* lcw  = c1_w  + (size_t)layer*DIN*4;
      const float* lcb  = c1_b  + (size_t)layer*DIN;
      const float* ldw  = dtp_w + (size_t)layer*DIN*8;
      const float* ldb  = dtp_b + (size_t)layer*DIN;
      const float* lal  = A_log + (size_t)layer*DIN*DST;
      const float* lD   = D_par + (size_t)layer*DIN;
      const __bf16* low = woutb + (size_t)layer*128*256;
      const float* lnw  = nrm_w + (size_t)layer*128;

      k_rmsscale<<<CTOK/4, 256, 0, stream>>>(xcb, rs);
      k_mgemm<1,128,512><<<dim3(4, CTOK/128), 256, 0, stream>>>(
          xcb, lin, nullptr, rs, lnw, xi, zb);
      k_seg<<<(int)(CTOK/64), 256, 0, stream>>>(
          xi, xc, wpb + (size_t)layer*64*256, lcw, lcb, ldw, ldb, lal, vbc, dtg, csg, sdt);
      k_scanB<<<CB*16, 256, 0, stream>>>(csg, sdt, lal);
      k_scanC2<<<(int)(CTOK/64), 256, 0, stream>>>(
          xc, vbc, zb, dtg, lal, lD, csg);
      k_mgemm<2,256,128><<<dim3(1, CTOK/128), 256, 0, stream>>>(
          xc, low, nullptr, nullptr, nullptr, xcb, nullptr);
    }

    k_pool1<<<dim3(16, CB), 256, 0, stream>>>(
        xcb, mask + (size_t)c*CTOK, pl + (size_t)c*CB*16*128, pm + (size_t)c*CB*16);
  }

  k_pool2<<<NB, 128, 0, stream>>>(pl, pm, pd);
  k_mlp_a<<<dim3(4, NB), 128, 0, stream>>>(pd, l1w, l1b, h1, 128);
  k_mlp_a<<<dim3(4, NB), 128, 0, stream>>>(h1, l2w, l2b, h2, 512);
  k_mlp3<<<NB, 256, 0, stream>>>(h2, l3w, l3b, dout);
}

// Round 12
// 2043.959 us; speedup vs baseline: 8.6466x; 1.4148x over previous
//
#include <hip/hip_runtime.h>
#include <math.h>

// ---------------- problem constants ----------------
#define NB     64
#define SL     2048
#define NTOK   (NB*SL)
#define EMB_D  128
#define DMODEL 128
#define DIN    256
#define DST    16
#define NLAYER 4
#define SEG    64
#define NSEG   (SL/SEG)        // 32
#define L2E    1.4426950408889634f
#define LN2    0.6931471805599453f

typedef __bf16 bf16x8 __attribute__((ext_vector_type(8)));
typedef __bf16 bf16x4 __attribute__((ext_vector_type(4)));
typedef float  f32x4  __attribute__((ext_vector_type(4)));

// fixed small region (floats)
#define FIX_PL   ((size_t)0)
#define FIX_PM   (FIX_PL + 131072)
#define FIX_PD   (FIX_PM + 1024)
#define FIX_H1   (FIX_PD + 8192)
#define FIX_H2   (FIX_H1 + 32768)
#define FIX_WP   (FIX_H2 + 32768)
#define FIX_W2B  (FIX_WP + 65536)
#define FIX_WINB (FIX_W2B + 24576)
#define FIX_WOUTB (FIX_WINB + 131072)
#define FIX_END  (FIX_WOUTB + 65536)

// raw-instruction transcendentals (v_exp_f32 / v_log_f32 / v_rcp_f32)
__device__ __forceinline__ float fexp2(float x){ return __builtin_amdgcn_exp2f(x); }
__device__ __forceinline__ float flog2(float x){ return __builtin_amdgcn_logf(x); }
__device__ __forceinline__ float frcp (float x){ return __builtin_amdgcn_rcpf(x); }
__device__ __forceinline__ float fast_exp(float x){ return fexp2(x*L2E); }
__device__ __forceinline__ float siluf(float v){ return v * frcp(1.f + fast_exp(-v)); }
__device__ __forceinline__ float softplusf(float a){
  return fmaxf(a,0.f) + flog2(1.f + fexp2(-fabsf(a)*L2E)) * LN2;
}

// state-pair update macros (explicit scalars)
#define SPF(hA,hB,q)  { dA*=r; hA=fmaf(dA,hA,du*q.x); dA*=r; hB=fmaf(dA,hB,du*q.z); }
#define SPFY(hA,hB,q) { dA*=r; hA=fmaf(dA,hA,du*q.x); y=fmaf(hA,q.y,y); \
                        dA*=r; hB=fmaf(dA,hB,du*q.z); y=fmaf(hB,q.w,y); }
#define SPSA(hA,hB,q,s0,s1) { float eA=fexp2(dt*(-fast_exp(alog[d*DST+s0])*L2E)); \
                              hA=fmaf(eA,hA,du*q.x); \
                              float eB=fexp2(dt*(-fast_exp(alog[d*DST+s1])*L2E)); \
                              hB=fmaf(eB,hB,du*q.z); }
#define SPSY(hA,hB,q,s0,s1) { float eA=fexp2(dt*(-fast_exp(alog[d*DST+s0])*L2E)); \
                              hA=fmaf(eA,hA,du*q.x); y=fmaf(hA,q.y,y); \
                              float eB=fexp2(dt*(-fast_exp(alog[d*DST+s1])*L2E)); \
                              hB=fmaf(eB,hB,du*q.z); y=fmaf(hB,q.w,y); }

// ---------------- weight prep ----------------
__global__ void k_w2b(const float* __restrict__ cw, __bf16* __restrict__ w2){
  int g = blockIdx.x*256 + threadIdx.x;
  if (g >= 128*384) return;
  int d = g / 384, j = g % 384;
  int k = j >> 7, e = j & 127;
  w2[d*384 + k*128 + e] = (__bf16)cw[d*384 + e*3 + k];
}

__global__ void k_cvt(const float* __restrict__ src, __bf16* __restrict__ dst, int n){
  int i = blockIdx.x*256 + threadIdx.x;
  if (i < n) dst[i] = (__bf16)src[i];
}

__global__ void k_wprep(const float* __restrict__ xpw, __bf16* __restrict__ wp){
  int g = blockIdx.x*256 + threadIdx.x;      // 65536
  int l = g >> 14, rem = g & 16383;
  int n = rem >> 8, k = rem & 255;
  float v = 0.f;
  if (n < 8){
    v = xpw[(size_t)l*40*256 + n*256 + k];
  } else if (n < 40){
    int i = n - 8;
    int row = 8 + ((i&1)<<4) + (i>>1);
    v = xpw[(size_t)l*40*256 + row*256 + k];
  }
  wp[g] = (__bf16)v;
}

// ---------------- embed + BN into padded chunk buffer ----------------
__global__ void k_embed(const int* __restrict__ tok, const float* __restrict__ emb,
                        const float* __restrict__ bnw, const float* __restrict__ bnb,
                        float* __restrict__ xp){
  int r = blockIdx.x;                 // CB*2050 rows
  int e = threadIdx.x;                // 128
  int b = r / 2050, tp = r % 2050;
  float v = 0.f;
  if (tp != 0 && tp != 2049){
    int t = tp - 1;
    int id = tok[(size_t)b*SL + t];
    float s = bnw[e] * rsqrtf(1.0f + 1e-5f);
    v = emb[(size_t)id*EMB_D + e] * s + bnb[e];
  }
  xp[(size_t)r*EMB_D + e] = v;
}

// ---------------- rmsnorm scale only ----------------
__global__ __launch_bounds__(256) void k_rmsscale(const float* __restrict__ x,
                                                  float* __restrict__ rs){
  int wv = threadIdx.x>>6, lane = threadIdx.x&63;
  size_t tok = (size_t)blockIdx.x*4 + wv;
  float2 v = *(const float2*)(x + tok*128 + lane*2);
  float ss = v.x*v.x + v.y*v.y;
  #pragma unroll
  for (int m=1;m<64;m<<=1) ss += __shfl_xor(ss, m);
  float r = rsqrtf(ss*(1.f/128.f) + 1e-5f);
  if (lane == 0) rs[tok] = r;
}

// ---------------- bf16 MFMA GEMM  out[M,N] = A[M,K] @ W[N,K]^T ----------------
template<int MODE, int K, int N>
__global__ __launch_bounds__(256) void k_mgemm(
    const float* __restrict__ A, const __bf16* __restrict__ Wb,
    const float* __restrict__ bias, const float* __restrict__ rsp,
    const float* __restrict__ nwp,
    float* __restrict__ out, __bf16* __restrict__ outz){
  __shared__ __bf16 As[128][40];
  __shared__ __bf16 Bs[128][40];
  const int tid  = threadIdx.x;
  const int wave = tid >> 6;
  const int lane = tid & 63;
  const int col  = lane & 15;
  const int quad = lane >> 4;
  const int wm = (wave & 1) * 64;
  const int wn = (wave >> 1) * 64;
  const int m0 = blockIdx.y * 128;
  const int n0 = blockIdx.x * 128;

  f32x4 acc[4][4];
  #pragma unroll
  for (int i=0;i<4;i++)
    #pragma unroll
    for (int j=0;j<4;j++) acc[i][j] = (f32x4){0.f,0.f,0.f,0.f};

  size_t abase;
  if constexpr(MODE==0){
    int bb = m0 >> 11, tloc = m0 & 2047;
    abase = ((size_t)bb*2050 + tloc) * 128;
  } else {
    abase = (size_t)m0 * K;
  }

  const int sm = tid >> 3;
  const int sk4 = (tid & 7) * 4;
  const int bn = tid >> 2;
  const int bk8 = (tid & 3) * 8;

  for (int k0 = 0; k0 < K; k0 += 32){
    #pragma unroll
    for (int p=0;p<4;p++){
      int m = p*32 + sm;
      float4 v;
      if constexpr(MODE==0){
        v = *(const float4*)(A + abase + (size_t)m*128 + k0 + sk4);
      } else if constexpr(MODE==1){
        float4 x4 = *(const float4*)(A + abase + (size_t)m*K + k0 + sk4);
        float4 w4 = *(const float4*)(nwp + k0 + sk4);
        float s = rsp[m0 + m];
        v.x = x4.x*s*w4.x; v.y = x4.y*s*w4.y; v.z = x4.z*s*w4.z; v.w = x4.w*s*w4.w;
      } else {
        v = *(const float4*)(A + abase + (size_t)m*K + k0 + sk4);
      }
      bf16x4 o;
      o[0] = (__bf16)v.x; o[1] = (__bf16)v.y; o[2] = (__bf16)v.z; o[3] = (__bf16)v.w;
      *(bf16x4*)&As[m][sk4] = o;
    }
    #pragma unroll
    for (int p=0;p<2;p++){
      int n = p*64 + bn;
      bf16x8 w = *(const bf16x8*)(Wb + (size_t)(n0+n)*K + k0 + bk8);
      *(bf16x8*)&Bs[n][bk8] = w;
    }
    __syncthreads();
    bf16x8 af[4], bfr[4];
    const int fq = quad*8;
    #pragma unroll
    for (int i=0;i<4;i++) af[i]  = *(const bf16x8*)&As[wm + i*16 + col][fq];
    #pragma unroll
    for (int j=0;j<4;j++) bfr[j] = *(const bf16x8*)&Bs[wn + j*16 + col][fq];
    #pragma unroll
    for (int i=0;i<4;i++)
      #pragma unroll
      for (int j=0;j<4;j++)
        acc[i][j] = __builtin_amdgcn_mfma_f32_16x16x32_bf16(af[i], bfr[j], acc[i][j], 0, 0, 0);
    __syncthreads();
  }

  #pragma unroll
  for (int i=0;i<4;i++){
    #pragma unroll
    for (int j=0;j<4;j++){
      int n_l = wn + j*16 + col;
      #pragma unroll
      for (int r=0;r<4;r++){
        int m = m0 + wm + i*16 + quad*4 + r;
        float c = acc[i][j][r];
        if constexpr(MODE==0){
          int n = n0 + n_l;
          out[(size_t)m*DMODEL + n] = fmaxf(c + bias[n], 0.f);
        } else if constexpr(MODE==1){
          int n = n0 + n_l;
          if (n < DIN) out [(size_t)m*DIN + n]        = c;
          else         outz[(size_t)m*DIN + n - DIN]  = (__bf16)siluf(c);
        } else {
          float* p = out + (size_t)m*DMODEL + n0 + n_l;
          *p = *p + c;
        }
      }
    }
  }
}

// ---------------- fused segment front: dwconv+silu -> MFMA x_proj -> vbc/dt -> scanA summary
__global__ __launch_bounds__(256) void k_seg(const float* __restrict__ xi,
    float* __restrict__ xcg, const __bf16* __restrict__ wpb,
    const float* __restrict__ cw, const float* __restrict__ cb,
    const float* __restrict__ dtw, const float* __restrict__ dtb,
    const float* __restrict__ alog,
    float* __restrict__ vbc, __bf16* __restrict__ dtg,
    float* __restrict__ cseg, float* __restrict__ sdtb){
  __shared__ __bf16 sxc[64][264];
  __shared__ float vls[64][68];
  const int tid = threadIdx.x;
  const size_t m0 = (size_t)blockIdx.x * 64;
  const int b = (int)(m0 >> 11);
  const int g = (int)((m0 >> 6) & (NSEG-1));
  const int seq0 = (int)(m0 & 2047);

  // ---- phase 0: depthwise conv(k=4) + silu -> xcg (fp32) + sxc (bf16 LDS) ----
  {
    const int c4 = (tid & 63) * 4;
    const int tw = tid >> 6;
    float wc[4][4];
    #pragma unroll
    for (int j=0;j<4;j++)
      #pragma unroll
      for (int k=0;k<4;k++) wc[j][k] = cw[(c4+j)*4 + k];
    float4 cb4 = *(const float4*)(cb + c4);
    #pragma unroll
    for (int it=0; it<16; it++){
      int t = it*4 + tw;
      float4 acc = cb4;
      #pragma unroll
      for (int k=0;k<4;k++){
        if (seq0 + t - 3 + k >= 0){
          float4 xv = *(const float4*)(xi + (m0 + t - 3 + k)*DIN + c4);
          acc.x = fmaf(wc[0][k], xv.x, acc.x);
          acc.y = fmaf(wc[1][k], xv.y, acc.y);
          acc.z = fmaf(wc[2][k], xv.z, acc.z);
          acc.w = fmaf(wc[3][k], xv.w, acc.w);
        }
      }
      acc.x = siluf(acc.x); acc.y = siluf(acc.y);
      acc.z = siluf(acc.z); acc.w = siluf(acc.w);
      *(float4*)(xcg + (m0 + t)*DIN + c4) = acc;
      bf16x4 o;
      o[0]=(__bf16)acc.x; o[1]=(__bf16)acc.y; o[2]=(__bf16)acc.z; o[3]=(__bf16)acc.w;
      *(bf16x4*)&sxc[t][c4] = o;
    }
  }
  __syncthreads();

  // ---- phase 1: MFMA vls[64][64] = sxc[64x256] @ wpb[64x256]^T ----
  {
    const int wave = tid >> 6, lane = tid & 63;
    const int col = lane & 15, quad = lane >> 4;
    const int wn = wave * 16;
    f32x4 acc[4];
    #pragma unroll
    for (int i=0;i<4;i++) acc[i] = (f32x4){0.f,0.f,0.f,0.f};
    #pragma unroll
    for (int kc=0;kc<8;kc++){
      bf16x8 bfr = *(const bf16x8*)(wpb + (size_t)(wn+col)*256 + kc*32 + quad*8);
      #pragma unroll
      for (int mi=0;mi<4;mi++){
        bf16x8 af = *(const bf16x8*)&sxc[mi*16 + col][kc*32 + quad*8];
        acc[mi] = __builtin_amdgcn_mfma_f32_16x16x32_bf16(af, bfr, acc[mi], 0, 0, 0);
      }
    }
    #pragma unroll
    for (int mi=0;mi<4;mi++)
      #pragma unroll
      for (int r=0;r<4;r++)
        vls[mi*16 + quad*4 + r][wn + col] = acc[mi][r];
  }
  __syncthreads();

  // ---- phase 2: write vbc[t][32] = BC only ----
  #pragma unroll
  for (int p=0;p<8;p++){
    int j = p*256 + tid;           // 2048
    int t = j >> 5, i = j & 31;
    vbc[(m0+t)*32 + i] = vls[t][8+i];
  }

  // ---- phase 3: scanA summary, thread = channel, explicit scalar state; store dt bf16 ----
  {
    const int d = tid;
    const float a0 = -fast_exp(alog[d*DST]) * L2E;
    bool fast = true;
    for (int s=1;s<16;s++){
      float as = -fast_exp(alog[d*DST + s]) * L2E;
      fast = fast && (fabsf(as - (float)(s+1)*a0) <= 1e-3f*fabsf(as));
    }
    float4 w8a = *(const float4*)(dtw + d*8);
    float4 w8b = *(const float4*)(dtw + d*8 + 4);
    const float bd = dtb[d];
    float h0=0.f,h1=0.f,h2=0.f,h3=0.f,h4=0.f,h5=0.f,h6=0.f,h7=0.f;
    float h8=0.f,h9=0.f,h10=0.f,h11=0.f,h12=0.f,h13=0.f,h14=0.f,h15=0.f;
    float ssum = 0.f;
    if (fast){
      for (int t=0;t<SEG;t++){
        float4 v0 = *(const float4*)&vls[t][0];
        float4 v1 = *(const float4*)&vls[t][4];
        float lin = bd;
        lin = fmaf(v0.x,w8a.x, fmaf(v0.y,w8a.y, fmaf(v0.z,w8a.z, fmaf(v0.w,w8a.w, lin))));
        lin = fmaf(v1.x,w8b.x, fmaf(v1.y,w8b.y, fmaf(v1.z,w8b.z, fmaf(v1.w,w8b.w, lin))));
        float dt = softplusf(lin);
        ssum += dt;
        dtg[(m0+t)*DIN + d] = (__bf16)dt;
        float u = xcg[(m0+t)*DIN + d];
        float du = dt*u;
        float r = fexp2(dt*a0);
        float dA = 1.f;
        float4 q0 = *(const float4*)&vls[t][8];
        float4 q1 = *(const float4*)&vls[t][12];
        float4 q2 = *(const float4*)&vls[t][16];
        float4 q3 = *(const float4*)&vls[t][20];
        float4 q4 = *(const float4*)&vls[t][24];
        float4 q5 = *(const float4*)&vls[t][28];
        float4 q6 = *(const float4*)&vls[t][32];
        float4 q7 = *(const float4*)&vls[t][36];
        SPF(h0,h1,q0)  SPF(h2,h3,q1)  SPF(h4,h5,q2)  SPF(h6,h7,q3)
        SPF(h8,h9,q4)  SPF(h10,h11,q5) SPF(h12,h13,q6) SPF(h14,h15,q7)
      }
    } else {
      for (int t=0;t<SEG;t++){
        float4 v0 = *(const float4*)&vls[t][0];
        float4 v1 = *(const float4*)&vls[t][4];
        float lin = bd;
        lin = fmaf(v0.x,w8a.x, fmaf(v0.y,w8a.y, fmaf(v0.z,w8a.z, fmaf(v0.w,w8a.w, lin))));
        lin = fmaf(v1.x,w8b.x, fmaf(v1.y,w8b.y, fmaf(v1.z,w8b.z, fmaf(v1.w,w8b.w, lin))));
        float dt = softplusf(lin);
        ssum += dt;
        dtg[(m0+t)*DIN + d] = (__bf16)dt;
        float u = xcg[(m0+t)*DIN + d];
        float du = dt*u;
        float4 q0 = *(const float4*)&vls[t][8];
        float4 q1 = *(const float4*)&vls[t][12];
        float4 q2 = *(const float4*)&vls[t][16];
        float4 q3 = *(const float4*)&vls[t][20];
        float4 q4 = *(const float4*)&vls[t][24];
        float4 q5 = *(const float4*)&vls[t][28];
        float4 q6 = *(const float4*)&vls[t][32];
        float4 q7 = *(const float4*)&vls[t][36];
        SPSA(h0,h1,q0,0,1)   SPSA(h2,h3,q1,2,3)   SPSA(h4,h5,q2,4,5)   SPSA(h6,h7,q3,6,7)
        SPSA(h8,h9,q4,8,9)   SPSA(h10,h11,q5,10,11) SPSA(h12,h13,q6,12,13) SPSA(h14,h15,q7,14,15)
      }
    }
    size_t base = (((size_t)b*NSEG + g)*DIN + d)*DST;
    float4 o;
    o.x=h0; o.y=h1; o.z=h2; o.w=h3;     *(float4*)(cseg + base     ) = o;
    o.x=h4; o.y=h5; o.z=h6; o.w=h7;     *(float4*)(cseg + base +  4) = o;
    o.x=h8; o.y=h9; o.z=h10; o.w=h11;   *(float4*)(cseg + base +  8) = o;
    o.x=h12; o.y=h13; o.z=h14; o.w=h15; *(float4*)(cseg + base + 12) = o;
    sdtb[((size_t)b*NSEG + g)*DIN + d] = ssum;
  }
}

// ---------------- scanB: serial combine over segments ----------------
__global__ __launch_bounds__(256) void k_scanB(float* __restrict__ cseg,
    const float* __restrict__ sdtb, const float* __restrict__ alog){
  int gl = blockIdx.x*256 + threadIdx.x;
  int b   = gl >> 12;
  int rem = gl & 4095;
  int d = rem >> 4, s = rem & 15;
  const float a = -fast_exp(alog[d*DST + s]) * L2E;
  float h = 0.f;
  for (int g=0; g<NSEG; g++){
    size_t base = ((size_t)b*NSEG + g)*DIN;
    float sd = sdtb[base + d];
    size_t ci = (base + d)*DST + s;
    float c = cseg[ci];
    cseg[ci] = h;
    h = fmaf(fexp2(a*sd), h, c);
  }
}

// ---------------- scanC2: thread = channel, precomputed dt/gz, fused gate ------
__global__ __launch_bounds__(256) void k_scanC2(float* __restrict__ xcg,
    const float* __restrict__ vbc, const __bf16* __restrict__ gzb,
    const __bf16* __restrict__ dtg,
    const float* __restrict__ alog, const float* __restrict__ Dpar,
    const float* __restrict__ cseg){
  __shared__ float svbc[64][32];
  const int tid = threadIdx.x;
  const size_t m0 = (size_t)blockIdx.x * 64;
  const int b = (int)(m0 >> 11);
  const int g = (int)((m0 >> 6) & (NSEG-1));

  #pragma unroll
  for (int p=0;p<8;p++){
    int j = p*256 + tid;           // 2048
    int t = j >> 5, i = j & 31;
    svbc[t][i] = vbc[(m0+t)*32 + i];
  }

  const int d = tid;
  const float a0 = -fast_exp(alog[d*DST]) * L2E;
  bool fast = true;
  for (int s=1;s<16;s++){
    float as = -fast_exp(alog[d*DST + s]) * L2E;
    fast = fast && (fabsf(as - (float)(s+1)*a0) <= 1e-3f*fabsf(as));
  }
  const float Dv = Dpar[d];
  size_t base = (((size_t)b*NSEG + g)*DIN + d)*DST;
  float4 hv0 = *(const float4*)(cseg + base);
  float4 hv1 = *(const float4*)(cseg + base + 4);
  float4 hv2 = *(const float4*)(cseg + base + 8);
  float4 hv3 = *(const float4*)(cseg + base + 12);
  float h0=hv0.x,h1=hv0.y,h2=hv0.z,h3=hv0.w;
  float h4=hv1.x,h5=hv1.y,h6=hv1.z,h7=hv1.w;
  float h8=hv2.x,h9=hv2.y,h10=hv2.z,h11=hv2.w;
  float h12=hv3.x,h13=hv3.y,h14=hv3.z,h15=hv3.w;
  __syncthreads();

  if (fast){
    for (int t=0;t<SEG;t++){
      float dt = (float)dtg[(m0+t)*DIN + d];
      float u  = xcg[(m0+t)*DIN + d];
      float du = dt*u;
      float r = fexp2(dt*a0);
      float dA = 1.f, y = 0.f;
      float4 q0 = *(const float4*)&svbc[t][0];
      float4 q1 = *(const float4*)&svbc[t][4];
      float4 q2 = *(const float4*)&svbc[t][8];
      float4 q3 = *(const float4*)&svbc[t][12];
      float4 q4 = *(const float4*)&svbc[t][16];
      float4 q5 = *(const float4*)&svbc[t][20];
      float4 q6 = *(const float4*)&svbc[t][24];
      float4 q7 = *(const float4*)&svbc[t][28];
      SPFY(h0,h1,q0)  SPFY(h2,h3,q1)  SPFY(h4,h5,q2)  SPFY(h6,h7,q3)
      SPFY(h8,h9,q4)  SPFY(h10,h11,q5) SPFY(h12,h13,q6) SPFY(h14,h15,q7)
      float gz = (float)gzb[(m0+t)*DIN + d];
      xcg[(m0+t)*DIN + d] = (y + u*Dv) * gz;
    }
  } else {
    for (int t=0;t<SEG;t++){
      float dt = (float)dtg[(m0+t)*DIN + d];
      float u  = xcg[(m0+t)*DIN + d];
      float du = dt*u;
      float y = 0.f;
      float4 q0 = *(const float4*)&svbc[t][0];
      float4 q1 = *(const float4*)&svbc[t][4];
      float4 q2 = *(const float4*)&svbc[t][8];
      float4 q3 = *(const float4*)&svbc[t][12];
      float4 q4 = *(const float4*)&svbc[t][16];
      float4 q5 = *(const float4*)&svbc[t][20];
      float4 q6 = *(const float4*)&svbc[t][24];
      float4 q7 = *(const float4*)&svbc[t][28];
      SPSY(h0,h1,q0,0,1)   SPSY(h2,h3,q1,2,3)   SPSY(h4,h5,q2,4,5)   SPSY(h6,h7,q3,6,7)
      SPSY(h8,h9,q4,8,9)   SPSY(h10,h11,q5,10,11) SPSY(h12,h13,q6,12,13) SPSY(h14,h15,q7,14,15)
      float gz = (float)gzb[(m0+t)*DIN + d];
      xcg[(m0+t)*DIN + d] = (y + u*Dv) * gz;
    }
  }
}

// ---------------- masked mean pool over a chunk ----------------
__global__ __launch_bounds__(256) void k_pool1(const float* __restrict__ x,
    const float* __restrict__ mask, float* __restrict__ part, float* __restrict__ pmask){
  int b = blockIdx.y, seg = blockIdx.x;
  int d = threadIdx.x & 127, half = threadIdx.x >> 7;
  int t0 = seg*128 + half*64;
  float acc = 0.f, macc = 0.f;
  for (int i=0;i<64;i++){
    int t = t0 + i;
    float mv = mask[(size_t)b*SL + t];
    acc = fmaf(x[((size_t)b*SL + t)*DMODEL + d], mv, acc);
    macc += mv;
  }
  __shared__ float sm[256];
  __shared__ float smm[2];
  sm[threadIdx.x] = acc;
  if (d == 0) smm[half] = macc;
  __syncthreads();
  if (half == 0){
    part[((size_t)b*16 + seg)*128 + d] = sm[d] + sm[128+d];
    if (d == 0) pmask[b*16 + seg] = smm[0] + smm[1];
  }
}

__global__ void k_pool2(const float* __restrict__ part, const float* __restrict__ pmask,
                        float* __restrict__ pooled){
  int b = blockIdx.x, d = threadIdx.x;
  float acc = 0.f, ms = 0.f;
  for (int s=0;s<16;s++){ acc += part[((size_t)b*16+s)*128 + d]; ms += pmask[b*16+s]; }
  pooled[(size_t)b*128 + d] = acc / fmaxf(ms, 1e-9f);
}

// ---------------- tiny MLP ----------------
__global__ void k_mlp_a(const float* __restrict__ in, const float* __restrict__ w,
                        const float* __restrict__ bias, float* __restrict__ out, int K){
  int b = blockIdx.y;
  int n = blockIdx.x*128 + threadIdx.x;
  const float4* pw = (const float4*)(w + (size_t)n*K);
  const float4* pi = (const float4*)(in + (size_t)b*K);
  float acc = 0.f;
  for (int k=0;k<K/4;k++){
    float4 a = pi[k], ww = pw[k];
    acc = fmaf(a.x,ww.x, fmaf(a.y,ww.y, fmaf(a.z,ww.z, fmaf(a.w,ww.w, acc))));
  }
  out[(size_t)b*512 + n] = fmaxf(acc + bias[n], 0.f);
}

__global__ void k_mlp3(const float* __restrict__ h, const float* __restrict__ w,
                       const float* __restrict__ bias, float* __restrict__ out){
  int b = blockIdx.x;
  int n = threadIdx.x >> 6, lane = threadIdx.x & 63;
  if (n >= 3) return;
  float acc = 0.f;
  for (int k=lane; k<512; k+=64) acc = fmaf(h[(size_t)b*512+k], w[(size_t)n*512+k], acc);
  #pragma unroll
  for (int m=1;m<64;m<<=1) acc += __shfl_xor(acc, m);
  if (lane == 0) out[(size_t)b*3 + n] = acc + bias[n];
}

// ---------------- launch ----------------
extern "C" void kernel_launch(void* const* d_in, const int* in_sizes, int n_in,
                              void* d_out, int out_size, void* d_ws, size_t ws_size,
                              hipStream_t stream){
  const int*   tokens = (const int*)  d_in[0];
  const float* mask   = (const float*)d_in[1];
  const float* emb    = (const float*)d_in[2];
  const float* bn_w   = (const float*)d_in[3];
  const float* bn_b   = (const float*)d_in[4];
  const float* conv_w = (const float*)d_in[5];
  const float* conv_b = (const float*)d_in[6];
  const float* in_w   = (const float*)d_in[7];
  const float* c1_w   = (const float*)d_in[8];
  const float* c1_b   = (const float*)d_in[9];
  const float* xp_w   = (const float*)d_in[10];
  const float* dtp_w  = (const float*)d_in[11];
  const float* dtp_b  = (const float*)d_in[12];
  const float* A_log  = (const float*)d_in[13];
  const float* D_par  = (const float*)d_in[14];
  const float* out_w  = (const float*)d_in[15];
  const float* nrm_w  = (const float*)d_in[16];
  const float* l1w = (const float*)d_in[17]; const float* l1b = (const float*)d_in[18];
  const float* l2w = (const float*)d_in[19]; const float* l2b = (const float*)d_in[20];
  const float* l3w = (const float*)d_in[21]; const float* l3b = (const float*)d_in[22];
  float* dout = (float*)d_out;

  // per-token floats: x 128 + rs 1 + xi 256 + xc 256 + vbc 32 + cseg 64 + sdt 4
  //                   + gz(bf16) 128 + dt(bf16) 128 = 997
  int CB = 64;
  while (CB > 1 && ((size_t)CB*SL*997 + FIX_END)*4 > ws_size) CB >>= 1;
  if (((size_t)CB*SL*997 + FIX_END)*4 > ws_size) return;
  const size_t CTOK = (size_t)CB*SL;

  float* ws  = (float*)d_ws;
  float* pl  = ws + FIX_PL;
  float* pm  = ws + FIX_PM;
  float* pd  = ws + FIX_PD;
  float* h1  = ws + FIX_H1;
  float* h2  = ws + FIX_H2;
  __bf16* wpb   = (__bf16*)(ws + FIX_WP);
  __bf16* w2b   = (__bf16*)(ws + FIX_W2B);
  __bf16* winb  = (__bf16*)(ws + FIX_WINB);
  __bf16* woutb = (__bf16*)(ws + FIX_WOUTB);
  float* xcb = ws + FIX_END;                 // CTOK*128 residual x
  float* rs  = xcb + CTOK*128;               // CTOK
  float* xi  = rs  + CTOK;                   // CTOK*256 (embed pad / x-branch)
  float* xc  = xi  + CTOK*256;               // CTOK*256 (conv out -> gated y in place)
  float* vbc = xc  + CTOK*256;               // CTOK*32 (interleaved BC)
  float* csg = vbc + CTOK*32;                // CTOK*64
  float* sdt = csg + CTOK*64;                // CTOK*4
  __bf16* zb  = (__bf16*)(sdt + CTOK*4);     // CTOK*256 bf16 (gz = silu(z))
  __bf16* dtg = zb + CTOK*256;               // CTOK*256 bf16 (dt)

  k_w2b<<<192, 256, 0, stream>>>(conv_w, w2b);
  k_cvt<<<1024, 256, 0, stream>>>(in_w,  winb,  4*512*128);
  k_cvt<<<512,  256, 0, stream>>>(out_w, woutb, 4*128*256);
  k_wprep<<<256, 256, 0, stream>>>(xp_w, wpb);

  const int nchunks = NB / CB;
  for (int c = 0; c < nchunks; c++){
    const int* tok_c = tokens + (size_t)c*CTOK;

    k_embed<<<CB*2050, 128, 0, stream>>>(tok_c, emb, bn_w, bn_b, xi);
    k_mgemm<0,384,128><<<dim3(1, CTOK/128), 256, 0, stream>>>(
        xi, w2b, conv_b, nullptr, nullptr, xcb, nullptr);

    for (int layer = 0; layer < NLAYER; layer++){
      const __bf16* lin = winb  + (size_t)layer*512*128;
      const float* lcw  = c1_w  + (size_t)layer*DIN*4;
      const float* lcb  = c1_b  + (size_t)layer*DIN;
      const float* ldw  = dtp_w + (size_t)layer*DIN*8;
      const float* ldb  = dtp_b + (size_t)layer*DIN;
      const float* lal  = A_log + (size_t)layer*DIN*DST;
      const float* lD   = D_par + (size_t)layer*DIN;
      const __bf16* low = woutb + (size_t)layer*128*256;
      const float* lnw  = nrm_w + (size_t)layer*128;

      k_rmsscale<<<CTOK/4, 256, 0, stream>>>(xcb, rs);
      k_mgemm<1,128,512><<<dim3(4, CTOK/128), 256, 0, stream>>>(
          xcb, lin, nullptr, rs, lnw, xi, zb);
      k_seg<<<(int)(CTOK/64), 256, 0, stream>>>(
          xi, xc, wpb + (size_t)layer*64*256, lcw, lcb, ldw, ldb, lal, vbc, dtg, csg, sdt);
      k_scanB<<<CB*16, 256, 0, stream>>>(csg, sdt, lal);
      k_scanC2<<<(int)(CTOK/64), 256, 0, stream>>>(
          xc, vbc, zb, dtg, lal, lD, csg);
      k_mgemm<2,256,128><<<dim3(1, CTOK/128), 256, 0, stream>>>(
          xc, low, nullptr, nullptr, nullptr, xcb, nullptr);
    }

    k_pool1<<<dim3(16, CB), 256, 0, stream>>>(
        xcb, mask + (size_t)c*CTOK, pl + (size_t)c*CB*16*128, pm + (size_t)c*CB*16);
  }

  k_pool2<<<NB, 128, 0, stream>>>(pl, pm, pd);
  k_mlp_a<<<dim3(4, NB), 128, 0, stream>>>(pd, l1w, l1b, h1, 128);
  k_mlp_a<<<dim3(4, NB), 128, 0, stream>>>(h1, l2w, l2b, h2, 512);
  k_mlp3<<<NB, 256, 0, stream>>>(h2, l3w, l3b, dout);
}

// Round 13
// 1776.743 us; speedup vs baseline: 9.9471x; 1.1504x over previous
//
#include <hip/hip_runtime.h>
#include <math.h>

// ---------------- problem constants ----------------
#define NB     64
#define SL     2048
#define NTOK   (NB*SL)
#define EMB_D  128
#define DMODEL 128
#define DIN    256
#define DST    16
#define NLAYER 4
#define SEG    64
#define NSEG   (SL/SEG)        // 32
#define L2E    1.4426950408889634f
#define LN2    0.6931471805599453f

typedef __bf16 bf16x8 __attribute__((ext_vector_type(8)));
typedef __bf16 bf16x4 __attribute__((ext_vector_type(4)));
typedef float  f32x4  __attribute__((ext_vector_type(4)));

// fixed small region (floats)
#define FIX_PL   ((size_t)0)
#define FIX_PM   (FIX_PL + 131072)
#define FIX_PD   (FIX_PM + 1024)
#define FIX_H1   (FIX_PD + 8192)
#define FIX_H2   (FIX_H1 + 32768)
#define FIX_WP   (FIX_H2 + 32768)
#define FIX_W2B  (FIX_WP + 65536)
#define FIX_WINB (FIX_W2B + 24576)
#define FIX_WOUTB (FIX_WINB + 131072)
#define FIX_END  (FIX_WOUTB + 65536)

// raw-instruction transcendentals
__device__ __forceinline__ float fexp2(float x){ return __builtin_amdgcn_exp2f(x); }
__device__ __forceinline__ float flog2(float x){ return __builtin_amdgcn_logf(x); }
__device__ __forceinline__ float frcp (float x){ return __builtin_amdgcn_rcpf(x); }
__device__ __forceinline__ float fast_exp(float x){ return fexp2(x*L2E); }
__device__ __forceinline__ float siluf(float v){ return v * frcp(1.f + fast_exp(-v)); }
__device__ __forceinline__ float softplusf(float a){
  return fmaxf(a,0.f) + flog2(1.f + fexp2(-fabsf(a)*L2E)) * LN2;
}

// state-pair update macros (explicit scalars)
#define SPF(hA,hB,q)  { dA*=r; hA=fmaf(dA,hA,du*q.x); dA*=r; hB=fmaf(dA,hB,du*q.z); }
#define SPFY(hA,hB,q) { dA*=r; hA=fmaf(dA,hA,du*q.x); y=fmaf(hA,q.y,y); \
                        dA*=r; hB=fmaf(dA,hB,du*q.z); y=fmaf(hB,q.w,y); }
#define SPSA(hA,hB,q,s0,s1) { float eA=fexp2(dt*(-fast_exp(alog[d*DST+s0])*L2E)); \
                              hA=fmaf(eA,hA,du*q.x); \
                              float eB=fexp2(dt*(-fast_exp(alog[d*DST+s1])*L2E)); \
                              hB=fmaf(eB,hB,du*q.z); }
#define SPSY(hA,hB,q,s0,s1) { float eA=fexp2(dt*(-fast_exp(alog[d*DST+s0])*L2E)); \
                              hA=fmaf(eA,hA,du*q.x); y=fmaf(hA,q.y,y); \
                              float eB=fexp2(dt*(-fast_exp(alog[d*DST+s1])*L2E)); \
                              hB=fmaf(eB,hB,du*q.z); y=fmaf(hB,q.w,y); }

// ---------------- weight prep ----------------
__global__ void k_w2b(const float* __restrict__ cw, __bf16* __restrict__ w2){
  int g = blockIdx.x*256 + threadIdx.x;
  if (g >= 128*384) return;
  int d = g / 384, j = g % 384;
  int k = j >> 7, e = j & 127;
  w2[d*384 + k*128 + e] = (__bf16)cw[d*384 + e*3 + k];
}

__global__ void k_cvt(const float* __restrict__ src, __bf16* __restrict__ dst, int n){
  int i = blockIdx.x*256 + threadIdx.x;
  if (i < n) dst[i] = (__bf16)src[i];
}

__global__ void k_wprep(const float* __restrict__ xpw, __bf16* __restrict__ wp){
  int g = blockIdx.x*256 + threadIdx.x;      // 65536
  int l = g >> 14, rem = g & 16383;
  int n = rem >> 8, k = rem & 255;
  float v = 0.f;
  if (n < 8){
    v = xpw[(size_t)l*40*256 + n*256 + k];
  } else if (n < 40){
    int i = n - 8;
    int row = 8 + ((i&1)<<4) + (i>>1);
    v = xpw[(size_t)l*40*256 + row*256 + k];
  }
  wp[g] = (__bf16)v;
}

// ---------------- embed + BN into padded chunk buffer (fp32 scratch) ----------------
__global__ void k_embed(const int* __restrict__ tok, const float* __restrict__ emb,
                        const float* __restrict__ bnw, const float* __restrict__ bnb,
                        float* __restrict__ xp){
  int r = blockIdx.x;                 // CB*2050 rows
  int e = threadIdx.x;                // 128
  int b = r / 2050, tp = r % 2050;
  float v = 0.f;
  if (tp != 0 && tp != 2049){
    int t = tp - 1;
    int id = tok[(size_t)b*SL + t];
    float s = bnw[e] * rsqrtf(1.0f + 1e-5f);
    v = emb[(size_t)id*EMB_D + e] * s + bnb[e];
  }
  xp[(size_t)r*EMB_D + e] = v;
}

// ---------------- rmsnorm scale only ----------------
__global__ __launch_bounds__(256) void k_rmsscale(const float* __restrict__ x,
                                                  float* __restrict__ rs){
  int wv = threadIdx.x>>6, lane = threadIdx.x&63;
  size_t tok = (size_t)blockIdx.x*4 + wv;
  float2 v = *(const float2*)(x + tok*128 + lane*2);
  float ss = v.x*v.x + v.y*v.y;
  #pragma unroll
  for (int m=1;m<64;m<<=1) ss += __shfl_xor(ss, m);
  float r = rsqrtf(ss*(1.f/128.f) + 1e-5f);
  if (lane == 0) rs[tok] = r;
}

// ---------------- bf16 MFMA GEMM  out[M,N] = A[M,K] @ W[N,K]^T ----------------
// MODE 0: A fp32 (padded im2col rows), epi relu(+bias) -> out fp32
// MODE 1: A fp32 (x), staged *rs*nw; epi n<256 -> outb (xi bf16), else outz (gz bf16)
// MODE 2: A bf16 (gated y); epi: out fp32 += acc (residual)
template<int MODE, int K, int N>
__global__ __launch_bounds__(256) void k_mgemm(
    const void* __restrict__ Av, const __bf16* __restrict__ Wb,
    const float* __restrict__ bias, const float* __restrict__ rsp,
    const float* __restrict__ nwp,
    float* __restrict__ out, __bf16* __restrict__ outb, __bf16* __restrict__ outz){
  __shared__ __bf16 As[128][40];
  __shared__ __bf16 Bs[128][40];
  const int tid  = threadIdx.x;
  const int wave = tid >> 6;
  const int lane = tid & 63;
  const int col  = lane & 15;
  const int quad = lane >> 4;
  const int wm = (wave & 1) * 64;
  const int wn = (wave >> 1) * 64;
  const int m0 = blockIdx.y * 128;
  const int n0 = blockIdx.x * 128;

  f32x4 acc[4][4];
  #pragma unroll
  for (int i=0;i<4;i++)
    #pragma unroll
    for (int j=0;j<4;j++) acc[i][j] = (f32x4){0.f,0.f,0.f,0.f};

  size_t abase;
  if constexpr(MODE==0){
    int bb = m0 >> 11, tloc = m0 & 2047;
    abase = ((size_t)bb*2050 + tloc) * 128;
  } else {
    abase = (size_t)m0 * K;
  }

  const int sm = tid >> 3;
  const int sk4 = (tid & 7) * 4;
  const int bn = tid >> 2;
  const int bk8 = (tid & 3) * 8;

  for (int k0 = 0; k0 < K; k0 += 32){
    #pragma unroll
    for (int p=0;p<4;p++){
      int m = p*32 + sm;
      if constexpr(MODE==2){
        const __bf16* A = (const __bf16*)Av;
        bf16x4 v = *(const bf16x4*)(A + abase + (size_t)m*K + k0 + sk4);
        *(bf16x4*)&As[m][sk4] = v;
      } else {
        const float* A = (const float*)Av;
        float4 v;
        if constexpr(MODE==0){
          v = *(const float4*)(A + abase + (size_t)m*128 + k0 + sk4);
        } else {
          float4 x4 = *(const float4*)(A + abase + (size_t)m*K + k0 + sk4);
          float4 w4 = *(const float4*)(nwp + k0 + sk4);
          float s = rsp[m0 + m];
          v.x = x4.x*s*w4.x; v.y = x4.y*s*w4.y; v.z = x4.z*s*w4.z; v.w = x4.w*s*w4.w;
        }
        bf16x4 o;
        o[0] = (__bf16)v.x; o[1] = (__bf16)v.y; o[2] = (__bf16)v.z; o[3] = (__bf16)v.w;
        *(bf16x4*)&As[m][sk4] = o;
      }
    }
    #pragma unroll
    for (int p=0;p<2;p++){
      int n = p*64 + bn;
      bf16x8 w = *(const bf16x8*)(Wb + (size_t)(n0+n)*K + k0 + bk8);
      *(bf16x8*)&Bs[n][bk8] = w;
    }
    __syncthreads();
    bf16x8 af[4], bfr[4];
    const int fq = quad*8;
    #pragma unroll
    for (int i=0;i<4;i++) af[i]  = *(const bf16x8*)&As[wm + i*16 + col][fq];
    #pragma unroll
    for (int j=0;j<4;j++) bfr[j] = *(const bf16x8*)&Bs[wn + j*16 + col][fq];
    #pragma unroll
    for (int i=0;i<4;i++)
      #pragma unroll
      for (int j=0;j<4;j++)
        acc[i][j] = __builtin_amdgcn_mfma_f32_16x16x32_bf16(af[i], bfr[j], acc[i][j], 0, 0, 0);
    __syncthreads();
  }

  #pragma unroll
  for (int i=0;i<4;i++){
    #pragma unroll
    for (int j=0;j<4;j++){
      int n_l = wn + j*16 + col;
      #pragma unroll
      for (int r=0;r<4;r++){
        int m = m0 + wm + i*16 + quad*4 + r;
        float c = acc[i][j][r];
        if constexpr(MODE==0){
          int n = n0 + n_l;
          out[(size_t)m*DMODEL + n] = fmaxf(c + bias[n], 0.f);
        } else if constexpr(MODE==1){
          int n = n0 + n_l;
          if (n < DIN) outb[(size_t)m*DIN + n]        = (__bf16)c;
          else         outz[(size_t)m*DIN + n - DIN]  = (__bf16)siluf(c);
        } else {
          float* p = out + (size_t)m*DMODEL + n0 + n_l;
          *p = *p + c;
        }
      }
    }
  }
}

// ---------------- fused segment front: dwconv+silu -> MFMA x_proj -> vbc/dt -> scanA summary
__global__ __launch_bounds__(256) void k_seg(const __bf16* __restrict__ xi,
    __bf16* __restrict__ xcg, const __bf16* __restrict__ wpb,
    const float* __restrict__ cw, const float* __restrict__ cb,
    const float* __restrict__ dtw, const float* __restrict__ dtb,
    const float* __restrict__ alog,
    float* __restrict__ vbc, __bf16* __restrict__ dtg,
    float* __restrict__ cseg, float* __restrict__ sdtb){
  __shared__ __bf16 sxc[64][264];
  __shared__ float vls[64][68];
  const int tid = threadIdx.x;
  const size_t m0 = (size_t)blockIdx.x * 64;
  const int b = (int)(m0 >> 11);
  const int g = (int)((m0 >> 6) & (NSEG-1));
  const int seq0 = (int)(m0 & 2047);

  // ---- phase 0: depthwise conv(k=4, bf16 in) + silu -> xcg (bf16) + sxc (bf16 LDS) ----
  {
    const int c4 = (tid & 63) * 4;
    const int tw = tid >> 6;
    float wc[4][4];
    #pragma unroll
    for (int j=0;j<4;j++)
      #pragma unroll
      for (int k=0;k<4;k++) wc[j][k] = cw[(c4+j)*4 + k];
    float4 cb4 = *(const float4*)(cb + c4);
    #pragma unroll
    for (int it=0; it<16; it++){
      int t = it*4 + tw;
      float4 acc = cb4;
      #pragma unroll
      for (int k=0;k<4;k++){
        if (seq0 + t - 3 + k >= 0){
          bf16x4 xv = *(const bf16x4*)(xi + (m0 + t - 3 + k)*DIN + c4);
          acc.x = fmaf(wc[0][k], (float)xv[0], acc.x);
          acc.y = fmaf(wc[1][k], (float)xv[1], acc.y);
          acc.z = fmaf(wc[2][k], (float)xv[2], acc.z);
          acc.w = fmaf(wc[3][k], (float)xv[3], acc.w);
        }
      }
      bf16x4 o;
      o[0]=(__bf16)siluf(acc.x); o[1]=(__bf16)siluf(acc.y);
      o[2]=(__bf16)siluf(acc.z); o[3]=(__bf16)siluf(acc.w);
      *(bf16x4*)(xcg + (m0 + t)*DIN + c4) = o;
      *(bf16x4*)&sxc[t][c4] = o;
    }
  }
  __syncthreads();

  // ---- phase 1: MFMA vls[64][64] = sxc[64x256] @ wpb[64x256]^T ----
  {
    const int wave = tid >> 6, lane = tid & 63;
    const int col = lane & 15, quad = lane >> 4;
    const int wn = wave * 16;
    f32x4 acc[4];
    #pragma unroll
    for (int i=0;i<4;i++) acc[i] = (f32x4){0.f,0.f,0.f,0.f};
    #pragma unroll
    for (int kc=0;kc<8;kc++){
      bf16x8 bfr = *(const bf16x8*)(wpb + (size_t)(wn+col)*256 + kc*32 + quad*8);
      #pragma unroll
      for (int mi=0;mi<4;mi++){
        bf16x8 af = *(const bf16x8*)&sxc[mi*16 + col][kc*32 + quad*8];
        acc[mi] = __builtin_amdgcn_mfma_f32_16x16x32_bf16(af, bfr, acc[mi], 0, 0, 0);
      }
    }
    #pragma unroll
    for (int mi=0;mi<4;mi++)
      #pragma unroll
      for (int r=0;r<4;r++)
        vls[mi*16 + quad*4 + r][wn + col] = acc[mi][r];
  }
  __syncthreads();

  // ---- phase 2: write vbc[t][32] = BC only ----
  #pragma unroll
  for (int p=0;p<8;p++){
    int j = p*256 + tid;           // 2048
    int t = j >> 5, i = j & 31;
    vbc[(m0+t)*32 + i] = vls[t][8+i];
  }

  // ---- phase 3: scanA summary, thread = channel; u from LDS; store dt bf16 ----
  {
    const int d = tid;
    const float a0 = -fast_exp(alog[d*DST]) * L2E;
    bool fast = true;
    for (int s=1;s<16;s++){
      float as = -fast_exp(alog[d*DST + s]) * L2E;
      fast = fast && (fabsf(as - (float)(s+1)*a0) <= 1e-3f*fabsf(as));
    }
    float4 w8a = *(const float4*)(dtw + d*8);
    float4 w8b = *(const float4*)(dtw + d*8 + 4);
    const float bd = dtb[d];
    float h0=0.f,h1=0.f,h2=0.f,h3=0.f,h4=0.f,h5=0.f,h6=0.f,h7=0.f;
    float h8=0.f,h9=0.f,h10=0.f,h11=0.f,h12=0.f,h13=0.f,h14=0.f,h15=0.f;
    float ssum = 0.f;
    if (fast){
      for (int t=0;t<SEG;t++){
        float4 v0 = *(const float4*)&vls[t][0];
        float4 v1 = *(const float4*)&vls[t][4];
        float lin = bd;
        lin = fmaf(v0.x,w8a.x, fmaf(v0.y,w8a.y, fmaf(v0.z,w8a.z, fmaf(v0.w,w8a.w, lin))));
        lin = fmaf(v1.x,w8b.x, fmaf(v1.y,w8b.y, fmaf(v1.z,w8b.z, fmaf(v1.w,w8b.w, lin))));
        float dt = softplusf(lin);
        ssum += dt;
        dtg[(m0+t)*DIN + d] = (__bf16)dt;
        float u = (float)sxc[t][d];
        float du = dt*u;
        float r = fexp2(dt*a0);
        float dA = 1.f;
        float4 q0 = *(const float4*)&vls[t][8];
        float4 q1 = *(const float4*)&vls[t][12];
        float4 q2 = *(const float4*)&vls[t][16];
        float4 q3 = *(const float4*)&vls[t][20];
        float4 q4 = *(const float4*)&vls[t][24];
        float4 q5 = *(const float4*)&vls[t][28];
        float4 q6 = *(const float4*)&vls[t][32];
        float4 q7 = *(const float4*)&vls[t][36];
        SPF(h0,h1,q0)  SPF(h2,h3,q1)  SPF(h4,h5,q2)  SPF(h6,h7,q3)
        SPF(h8,h9,q4)  SPF(h10,h11,q5) SPF(h12,h13,q6) SPF(h14,h15,q7)
      }
    } else {
      for (int t=0;t<SEG;t++){
        float4 v0 = *(const float4*)&vls[t][0];
        float4 v1 = *(const float4*)&vls[t][4];
        float lin = bd;
        lin = fmaf(v0.x,w8a.x, fmaf(v0.y,w8a.y, fmaf(v0.z,w8a.z, fmaf(v0.w,w8a.w, lin))));
        lin = fmaf(v1.x,w8b.x, fmaf(v1.y,w8b.y, fmaf(v1.z,w8b.z, fmaf(v1.w,w8b.w, lin))));
        float dt = softplusf(lin);
        ssum += dt;
        dtg[(m0+t)*DIN + d] = (__bf16)dt;
        float u = (float)sxc[t][d];
        float du = dt*u;
        float4 q0 = *(const float4*)&vls[t][8];
        float4 q1 = *(const float4*)&vls[t][12];
        float4 q2 = *(const float4*)&vls[t][16];
        float4 q3 = *(const float4*)&vls[t][20];
        float4 q4 = *(const float4*)&vls[t][24];
        float4 q5 = *(const float4*)&vls[t][28];
        float4 q6 = *(const float4*)&vls[t][32];
        float4 q7 = *(const float4*)&vls[t][36];
        SPSA(h0,h1,q0,0,1)   SPSA(h2,h3,q1,2,3)   SPSA(h4,h5,q2,4,5)   SPSA(h6,h7,q3,6,7)
        SPSA(h8,h9,q4,8,9)   SPSA(h10,h11,q5,10,11) SPSA(h12,h13,q6,12,13) SPSA(h14,h15,q7,14,15)
      }
    }
    size_t base = (((size_t)b*NSEG + g)*DIN + d)*DST;
    float4 o;
    o.x=h0; o.y=h1; o.z=h2; o.w=h3;     *(float4*)(cseg + base     ) = o;
    o.x=h4; o.y=h5; o.z=h6; o.w=h7;     *(float4*)(cseg + base +  4) = o;
    o.x=h8; o.y=h9; o.z=h10; o.w=h11;   *(float4*)(cseg + base +  8) = o;
    o.x=h12; o.y=h13; o.z=h14; o.w=h15; *(float4*)(cseg + base + 12) = o;
    sdtb[((size_t)b*NSEG + g)*DIN + d] = ssum;
  }
}

// ---------------- scanB: serial combine over segments ----------------
__global__ __launch_bounds__(256) void k_scanB(float* __restrict__ cseg,
    const float* __restrict__ sdtb, const float* __restrict__ alog){
  int gl = blockIdx.x*256 + threadIdx.x;
  int b   = gl >> 12;
  int rem = gl & 4095;
  int d = rem >> 4, s = rem & 15;
  const float a = -fast_exp(alog[d*DST + s]) * L2E;
  float h = 0.f;
  for (int g=0; g<NSEG; g++){
    size_t base = ((size_t)b*NSEG + g)*DIN;
    float sd = sdtb[base + d];
    size_t ci = (base + d)*DST + s;
    float c = cseg[ci];
    cseg[ci] = h;
    h = fmaf(fexp2(a*sd), h, c);
  }
}

// ---------------- scanC2: thread = channel, bf16 u/dt/gz, fused gate, in-place bf16 ------
__global__ __launch_bounds__(256) void k_scanC2(__bf16* __restrict__ xcg,
    const float* __restrict__ vbc, const __bf16* __restrict__ gzb,
    const __bf16* __restrict__ dtg,
    const float* __restrict__ alog, const float* __restrict__ Dpar,
    const float* __restrict__ cseg){
  __shared__ float svbc[64][32];
  const int tid = threadIdx.x;
  const size_t m0 = (size_t)blockIdx.x * 64;
  const int b = (int)(m0 >> 11);
  const int g = (int)((m0 >> 6) & (NSEG-1));

  #pragma unroll
  for (int p=0;p<8;p++){
    int j = p*256 + tid;           // 2048
    int t = j >> 5, i = j & 31;
    svbc[t][i] = vbc[(m0+t)*32 + i];
  }

  const int d = tid;
  const float a0 = -fast_exp(alog[d*DST]) * L2E;
  bool fast = true;
  for (int s=1;s<16;s++){
    float as = -fast_exp(alog[d*DST + s]) * L2E;
    fast = fast && (fabsf(as - (float)(s+1)*a0) <= 1e-3f*fabsf(as));
  }
  const float Dv = Dpar[d];
  size_t base = (((size_t)b*NSEG + g)*DIN + d)*DST;
  float4 hv0 = *(const float4*)(cseg + base);
  float4 hv1 = *(const float4*)(cseg + base + 4);
  float4 hv2 = *(const float4*)(cseg + base + 8);
  float4 hv3 = *(const float4*)(cseg + base + 12);
  float h0=hv0.x,h1=hv0.y,h2=hv0.z,h3=hv0.w;
  float h4=hv1.x,h5=hv1.y,h6=hv1.z,h7=hv1.w;
  float h8=hv2.x,h9=hv2.y,h10=hv2.z,h11=hv2.w;
  float h12=hv3.x,h13=hv3.y,h14=hv3.z,h15=hv3.w;
  __syncthreads();

  if (fast){
    for (int t=0;t<SEG;t++){
      float dt = (float)dtg[(m0+t)*DIN + d];
      float u  = (float)xcg[(m0+t)*DIN + d];
      float du = dt*u;
      float r = fexp2(dt*a0);
      float dA = 1.f, y = 0.f;
      float4 q0 = *(const float4*)&svbc[t][0];
      float4 q1 = *(const float4*)&svbc[t][4];
      float4 q2 = *(const float4*)&svbc[t][8];
      float4 q3 = *(const float4*)&svbc[t][12];
      float4 q4 = *(const float4*)&svbc[t][16];
      float4 q5 = *(const float4*)&svbc[t][20];
      float4 q6 = *(const float4*)&svbc[t][24];
      float4 q7 = *(const float4*)&svbc[t][28];
      SPFY(h0,h1,q0)  SPFY(h2,h3,q1)  SPFY(h4,h5,q2)  SPFY(h6,h7,q3)
      SPFY(h8,h9,q4)  SPFY(h10,h11,q5) SPFY(h12,h13,q6) SPFY(h14,h15,q7)
      float gz = (float)gzb[(m0+t)*DIN + d];
      xcg[(m0+t)*DIN + d] = (__bf16)((y + u*Dv) * gz);
    }
  } else {
    for (int t=0;t<SEG;t++){
      float dt = (float)dtg[(m0+t)*DIN + d];
      float u  = (float)xcg[(m0+t)*DIN + d];
      float du = dt*u;
      float y = 0.f;
      float4 q0 = *(const float4*)&svbc[t][0];
      float4 q1 = *(const float4*)&svbc[t][4];
      float4 q2 = *(const float4*)&svbc[t][8];
      float4 q3 = *(const float4*)&svbc[t][12];
      float4 q4 = *(const float4*)&svbc[t][16];
      float4 q5 = *(const float4*)&svbc[t][20];
      float4 q6 = *(const float4*)&svbc[t][24];
      float4 q7 = *(const float4*)&svbc[t][28];
      SPSY(h0,h1,q0,0,1)   SPSY(h2,h3,q1,2,3)   SPSY(h4,h5,q2,4,5)   SPSY(h6,h7,q3,6,7)
      SPSY(h8,h9,q4,8,9)   SPSY(h10,h11,q5,10,11) SPSY(h12,h13,q6,12,13) SPSY(h14,h15,q7,14,15)
      float gz = (float)gzb[(m0+t)*DIN + d];
      xcg[(m0+t)*DIN + d] = (__bf16)((y + u*Dv) * gz);
    }
  }
}

// ---------------- masked mean pool over a chunk ----------------
__global__ __launch_bounds__(256) void k_pool1(const float* __restrict__ x,
    const float* __restrict__ mask, float* __restrict__ part, float* __restrict__ pmask){
  int b = blockIdx.y, seg = blockIdx.x;
  int d = threadIdx.x & 127, half = threadIdx.x >> 7;
  int t0 = seg*128 + half*64;
  float acc = 0.f, macc = 0.f;
  for (int i=0;i<64;i++){
    int t = t0 + i;
    float mv = mask[(size_t)b*SL + t];
    acc = fmaf(x[((size_t)b*SL + t)*DMODEL + d], mv, acc);
    macc += mv;
  }
  __shared__ float sm[256];
  __shared__ float smm[2];
  sm[threadIdx.x] = acc;
  if (d == 0) smm[half] = macc;
  __syncthreads();
  if (half == 0){
    part[((size_t)b*16 + seg)*128 + d] = sm[d] + sm[128+d];
    if (d == 0) pmask[b*16 + seg] = smm[0] + smm[1];
  }
}

__global__ void k_pool2(const float* __restrict__ part, const float* __restrict__ pmask,
                        float* __restrict__ pooled){
  int b = blockIdx.x, d = threadIdx.x;
  float acc = 0.f, ms = 0.f;
  for (int s=0;s<16;s++){ acc += part[((size_t)b*16+s)*128 + d]; ms += pmask[b*16+s]; }
  pooled[(size_t)b*128 + d] = acc / fmaxf(ms, 1e-9f);
}

// ---------------- tiny MLP ----------------
__global__ void k_mlp_a(const float* __restrict__ in, const float* __restrict__ w,
                        const float* __restrict__ bias, float* __restrict__ out, int K){
  int b = blockIdx.y;
  int n = blockIdx.x*128 + threadIdx.x;
  const float4* pw = (const float4*)(w + (size_t)n*K);
  const float4* pi = (const float4*)(in + (size_t)b*K);
  float acc = 0.f;
  for (int k=0;k<K/4;k++){
    float4 a = pi[k], ww = pw[k];
    acc = fmaf(a.x,ww.x, fmaf(a.y,ww.y, fmaf(a.z,ww.z, fmaf(a.w,ww.w, acc))));
  }
  out[(size_t)b*512 + n] = fmaxf(acc + bias[n], 0.f);
}

__global__ void k_mlp3(const float* __restrict__ h, const float* __restrict__ w,
                       const float* __restrict__ bias, float* __restrict__ out){
  int b = blockIdx.x;
  int n = threadIdx.x >> 6, lane = threadIdx.x & 63;
  if (n >= 3) return;
  float acc = 0.f;
  for (int k=lane; k<512; k+=64) acc = fmaf(h[(size_t)b*512+k], w[(size_t)n*512+k], acc);
  #pragma unroll
  for (int m=1;m<64;m<<=1) acc += __shfl_xor(acc, m);
  if (lane == 0) out[(size_t)b*3 + n] = acc + bias[n];
}

// ---------------- launch ----------------
extern "C" void kernel_launch(void* const* d_in, const int* in_sizes, int n_in,
                              void* d_out, int out_size, void* d_ws, size_t ws_size,
                              hipStream_t stream){
  const int*   tokens = (const int*)  d_in[0];
  const float* mask   = (const float*)d_in[1];
  const float* emb    = (const float*)d_in[2];
  const float* bn_w   = (const float*)d_in[3];
  const float* bn_b   = (const float*)d_in[4];
  const float* conv_w = (const float*)d_in[5];
  const float* conv_b = (const float*)d_in[6];
  const float* in_w   = (const float*)d_in[7];
  const float* c1_w   = (const float*)d_in[8];
  const float* c1_b   = (const float*)d_in[9];
  const float* xp_w   = (const float*)d_in[10];
  const float* dtp_w  = (const float*)d_in[11];
  const float* dtp_b  = (const float*)d_in[12];
  const float* A_log  = (const float*)d_in[13];
  const float* D_par  = (const float*)d_in[14];
  const float* out_w  = (const float*)d_in[15];
  const float* nrm_w  = (const float*)d_in[16];
  const float* l1w = (const float*)d_in[17]; const float* l1b = (const float*)d_in[18];
  const float* l2w = (const float*)d_in[19]; const float* l2b = (const float*)d_in[20];
  const float* l3w = (const float*)d_in[21]; const float* l3b = (const float*)d_in[22];
  float* dout = (float*)d_out;

  // per-token floats: x 128 + rs 1 + xi(bf16) 128 + xc(bf16) 128 + vbc 32 + cseg 64
  //                   + sdt 4 + gz(bf16) 128 + dt(bf16) 128 = 741
  // embed pad (fp32, CB*2050*128) aliases xi+xc (CB*2048*256 floats) -> fits.
  int CB = 64;
  while (CB > 1 && ((size_t)CB*SL*741 + FIX_END)*4 > ws_size) CB >>= 1;
  if (((size_t)CB*SL*741 + FIX_END)*4 > ws_size) return;
  const size_t CTOK = (size_t)CB*SL;

  float* ws  = (float*)d_ws;
  float* pl  = ws + FIX_PL;
  float* pm  = ws + FIX_PM;
  float* pd  = ws + FIX_PD;
  float* h1  = ws + FIX_H1;
  float* h2  = ws + FIX_H2;
  __bf16* wpb   = (__bf16*)(ws + FIX_WP);
  __bf16* w2b   = (__bf16*)(ws + FIX_W2B);
  __bf16* winb  = (__bf16*)(ws + FIX_WINB);
  __bf16* woutb = (__bf16*)(ws + FIX_WOUTB);
  float* xcb = ws + FIX_END;                 // CTOK*128 fp32 residual x
  float* rs  = xcb + CTOK*128;               // CTOK
  __bf16* xib = (__bf16*)(rs + CTOK);        // CTOK*256 bf16 (x-branch)
  __bf16* xcc = xib + CTOK*256;              // CTOK*256 bf16 (conv out -> gated y)
  float* pad = (float*)xib;                  // fp32 embed-pad scratch (aliases xib+xcc)
  float* vbc = (float*)(xcc + CTOK*256);     // CTOK*32 fp32 (interleaved BC)
  float* csg = vbc + CTOK*32;                // CTOK*64
  float* sdt = csg + CTOK*64;                // CTOK*4
  __bf16* zb  = (__bf16*)(sdt + CTOK*4);     // CTOK*256 bf16 (gz)
  __bf16* dtg = zb + CTOK*256;               // CTOK*256 bf16 (dt)

  k_w2b<<<192, 256, 0, stream>>>(conv_w, w2b);
  k_cvt<<<1024, 256, 0, stream>>>(in_w,  winb,  4*512*128);
  k_cvt<<<512,  256, 0, stream>>>(out_w, woutb, 4*128*256);
  k_wprep<<<256, 256, 0, stream>>>(xp_w, wpb);

  const int nchunks = NB / CB;
  for (int c = 0; c < nchunks; c++){
    const int* tok_c = tokens + (size_t)c*CTOK;

    k_embed<<<CB*2050, 128, 0, stream>>>(tok_c, emb, bn_w, bn_b, pad);
    k_mgemm<0,384,128><<<dim3(1, CTOK/128), 256, 0, stream>>>(
        pad, w2b, conv_b, nullptr, nullptr, xcb, nullptr, nullptr);

    for (int layer = 0; layer < NLAYER; layer++){
      const __bf16* lin = winb  + (size_t)layer*512*128;
      const float* lcw  = c1_w  + (size_t)layer*DIN*4;
      const float* lcb  = c1_b  + (size_t)layer*DIN;
      const float* ldw  = dtp_w + (size_t)layer*DIN*8;
      const float* ldb  = dtp_b + (size_t)layer*DIN;
      const float* lal  = A_log + (size_t)layer*DIN*DST;
      const float* lD   = D_par + (size_t)layer*DIN;
      const __bf16* low = woutb + (size_t)layer*128*256;
      const float* lnw  = nrm_w + (size_t)layer*128;

      k_rmsscale<<<CTOK/4, 256, 0, stream>>>(xcb, rs);
      k_mgemm<1,128,512><<<dim3(4, CTOK/128), 256, 0, stream>>>(
          xcb, lin, nullptr, rs, lnw, nullptr, xib, zb);
      k_seg<<<(int)(CTOK/64), 256, 0, stream>>>(
          xib, xcc, wpb + (size_t)layer*64*256, lcw, lcb, ldw, ldb, lal, vbc, dtg, csg, sdt);
      k_scanB<<<CB*16, 256, 0, stream>>>(csg, sdt, lal);
      k_scanC2<<<(int)(CTOK/64), 256, 0, stream>>>(
          xcc, vbc, zb, dtg, lal, lD, csg);
      k_mgemm<2,256,128><<<dim3(1, CTOK/128), 256, 0, stream>>>(
          xcc, low, nullptr, nullptr, nullptr, xcb, nullptr, nullptr);
    }

    k_pool1<<<dim3(16, CB), 256, 0, stream>>>(
        xcb, mask + (size_t)c*CTOK, pl + (size_t)c*CB*16*128, pm + (size_t)c*CB*16);
  }

  k_pool2<<<NB, 128, 0, stream>>>(pl, pm, pd);
  k_mlp_a<<<dim3(4, NB), 128, 0, stream>>>(pd, l1w, l1b, h1, 128);
  k_mlp_a<<<dim3(4, NB), 128, 0, stream>>>(h1, l2w, l2b, h2, 512);
  k_mlp3<<<NB, 256, 0, stream>>>(h2, l3w, l3b, dout);
}

// Round 14
// 1631.563 us; speedup vs baseline: 10.8322x; 1.0890x over previous
//
#include <hip/hip_runtime.h>
#include <math.h>

// ---------------- problem constants ----------------
#define NB     64
#define SL     2048
#define NTOK   (NB*SL)
#define EMB_D  128
#define DMODEL 128
#define DIN    256
#define DST    16
#define NLAYER 4
#define SEG    64
#define NSEG   (SL/SEG)        // 32
#define L2E    1.4426950408889634f
#define LN2    0.6931471805599453f

typedef __bf16 bf16x8 __attribute__((ext_vector_type(8)));
typedef __bf16 bf16x4 __attribute__((ext_vector_type(4)));
typedef float  f32x4  __attribute__((ext_vector_type(4)));

// fixed small region (floats)
#define FIX_PL   ((size_t)0)
#define FIX_PM   (FIX_PL + 131072)
#define FIX_PD   (FIX_PM + 1024)
#define FIX_H1   (FIX_PD + 8192)
#define FIX_H2   (FIX_H1 + 32768)
#define FIX_WP   (FIX_H2 + 32768)
#define FIX_W2B  (FIX_WP + 65536)
#define FIX_WINB (FIX_W2B + 24576)
#define FIX_WOUTB (FIX_WINB + 131072)
#define FIX_END  (FIX_WOUTB + 65536)

// raw-instruction transcendentals
__device__ __forceinline__ float fexp2(float x){ return __builtin_amdgcn_exp2f(x); }
__device__ __forceinline__ float flog2(float x){ return __builtin_amdgcn_logf(x); }
__device__ __forceinline__ float frcp (float x){ return __builtin_amdgcn_rcpf(x); }
__device__ __forceinline__ float fast_exp(float x){ return fexp2(x*L2E); }
__device__ __forceinline__ float siluf(float v){ return v * frcp(1.f + fast_exp(-v)); }
__device__ __forceinline__ float softplusf(float a){
  return fmaxf(a,0.f) + flog2(1.f + fexp2(-fabsf(a)*L2E)) * LN2;
}

// state-pair update macros (explicit scalars)
#define SPF(hA,hB,q)  { dA*=r; hA=fmaf(dA,hA,du*q.x); dA*=r; hB=fmaf(dA,hB,du*q.z); }
#define SPFY(hA,hB,q) { dA*=r; hA=fmaf(dA,hA,du*q.x); y=fmaf(hA,q.y,y); \
                        dA*=r; hB=fmaf(dA,hB,du*q.z); y=fmaf(hB,q.w,y); }
#define SPSA(hA,hB,q,s0,s1) { float eA=fexp2(dt*(-fast_exp(alog[d*DST+s0])*L2E)); \
                              hA=fmaf(eA,hA,du*q.x); \
                              float eB=fexp2(dt*(-fast_exp(alog[d*DST+s1])*L2E)); \
                              hB=fmaf(eB,hB,du*q.z); }
#define SPSY(hA,hB,q,s0,s1) { float eA=fexp2(dt*(-fast_exp(alog[d*DST+s0])*L2E)); \
                              hA=fmaf(eA,hA,du*q.x); y=fmaf(hA,q.y,y); \
                              float eB=fexp2(dt*(-fast_exp(alog[d*DST+s1])*L2E)); \
                              hB=fmaf(eB,hB,du*q.z); y=fmaf(hB,q.w,y); }

// ---------------- weight prep ----------------
__global__ void k_w2b(const float* __restrict__ cw, __bf16* __restrict__ w2){
  int g = blockIdx.x*256 + threadIdx.x;
  if (g >= 128*384) return;
  int d = g / 384, j = g % 384;
  int k = j >> 7, e = j & 127;
  w2[d*384 + k*128 + e] = (__bf16)cw[d*384 + e*3 + k];
}

__global__ void k_cvt(const float* __restrict__ src, __bf16* __restrict__ dst, int n){
  int i = blockIdx.x*256 + threadIdx.x;
  if (i < n) dst[i] = (__bf16)src[i];
}

__global__ void k_wprep(const float* __restrict__ xpw, __bf16* __restrict__ wp){
  int g = blockIdx.x*256 + threadIdx.x;      // 65536
  int l = g >> 14, rem = g & 16383;
  int n = rem >> 8, k = rem & 255;
  float v = 0.f;
  if (n < 8){
    v = xpw[(size_t)l*40*256 + n*256 + k];
  } else if (n < 40){
    int i = n - 8;
    int row = 8 + ((i&1)<<4) + (i>>1);
    v = xpw[(size_t)l*40*256 + row*256 + k];
  }
  wp[g] = (__bf16)v;
}

// ---------------- embed + BN into padded chunk buffer (fp32 scratch) ----------------
__global__ void k_embed(const int* __restrict__ tok, const float* __restrict__ emb,
                        const float* __restrict__ bnw, const float* __restrict__ bnb,
                        float* __restrict__ xp){
  int r = blockIdx.x;                 // CB*2050 rows
  int e = threadIdx.x;                // 128
  int b = r / 2050, tp = r % 2050;
  float v = 0.f;
  if (tp != 0 && tp != 2049){
    int t = tp - 1;
    int id = tok[(size_t)b*SL + t];
    float s = bnw[e] * rsqrtf(1.0f + 1e-5f);
    v = emb[(size_t)id*EMB_D + e] * s + bnb[e];
  }
  xp[(size_t)r*EMB_D + e] = v;
}

// ---------------- rmsnorm scale only (layer 0 / after front conv) ----------------
__global__ __launch_bounds__(256) void k_rmsscale(const float* __restrict__ x,
                                                  float* __restrict__ rs){
  int wv = threadIdx.x>>6, lane = threadIdx.x&63;
  size_t tok = (size_t)blockIdx.x*4 + wv;
  float2 v = *(const float2*)(x + tok*128 + lane*2);
  float ss = v.x*v.x + v.y*v.y;
  #pragma unroll
  for (int m=1;m<64;m<<=1) ss += __shfl_xor(ss, m);
  float r = rsqrtf(ss*(1.f/128.f) + 1e-5f);
  if (lane == 0) rs[tok] = r;
}

// ---------------- bf16 MFMA GEMM ----------------
// MODE 0: A fp32 (padded im2col rows), epi relu(+bias) -> out fp32
// MODE 1: A fp32 (x), staged *rs*nw; epi n<256 -> outb (xi bf16), else outz (gz bf16)
template<int MODE, int K, int N>
__global__ __launch_bounds__(256) void k_mgemm(
    const void* __restrict__ Av, const __bf16* __restrict__ Wb,
    const float* __restrict__ bias, const float* __restrict__ rsp,
    const float* __restrict__ nwp,
    float* __restrict__ out, __bf16* __restrict__ outb, __bf16* __restrict__ outz){
  __shared__ __bf16 As[128][40];
  __shared__ __bf16 Bs[128][40];
  const int tid  = threadIdx.x;
  const int wave = tid >> 6;
  const int lane = tid & 63;
  const int col  = lane & 15;
  const int quad = lane >> 4;
  const int wm = (wave & 1) * 64;
  const int wn = (wave >> 1) * 64;
  const int m0 = blockIdx.y * 128;
  const int n0 = blockIdx.x * 128;

  f32x4 acc[4][4];
  #pragma unroll
  for (int i=0;i<4;i++)
    #pragma unroll
    for (int j=0;j<4;j++) acc[i][j] = (f32x4){0.f,0.f,0.f,0.f};

  size_t abase;
  if constexpr(MODE==0){
    int bb = m0 >> 11, tloc = m0 & 2047;
    abase = ((size_t)bb*2050 + tloc) * 128;
  } else {
    abase = (size_t)m0 * K;
  }

  const int sm = tid >> 3;
  const int sk4 = (tid & 7) * 4;
  const int bn = tid >> 2;
  const int bk8 = (tid & 3) * 8;

  for (int k0 = 0; k0 < K; k0 += 32){
    #pragma unroll
    for (int p=0;p<4;p++){
      int m = p*32 + sm;
      const float* A = (const float*)Av;
      float4 v;
      if constexpr(MODE==0){
        v = *(const float4*)(A + abase + (size_t)m*128 + k0 + sk4);
      } else {
        float4 x4 = *(const float4*)(A + abase + (size_t)m*K + k0 + sk4);
        float4 w4 = *(const float4*)(nwp + k0 + sk4);
        float s = rsp[m0 + m];
        v.x = x4.x*s*w4.x; v.y = x4.y*s*w4.y; v.z = x4.z*s*w4.z; v.w = x4.w*s*w4.w;
      }
      bf16x4 o;
      o[0] = (__bf16)v.x; o[1] = (__bf16)v.y; o[2] = (__bf16)v.z; o[3] = (__bf16)v.w;
      *(bf16x4*)&As[m][sk4] = o;
    }
    #pragma unroll
    for (int p=0;p<2;p++){
      int n = p*64 + bn;
      bf16x8 w = *(const bf16x8*)(Wb + (size_t)(n0+n)*K + k0 + bk8);
      *(bf16x8*)&Bs[n][bk8] = w;
    }
    __syncthreads();
    bf16x8 af[4], bfr[4];
    const int fq = quad*8;
    #pragma unroll
    for (int i=0;i<4;i++) af[i]  = *(const bf16x8*)&As[wm + i*16 + col][fq];
    #pragma unroll
    for (int j=0;j<4;j++) bfr[j] = *(const bf16x8*)&Bs[wn + j*16 + col][fq];
    #pragma unroll
    for (int i=0;i<4;i++)
      #pragma unroll
      for (int j=0;j<4;j++)
        acc[i][j] = __builtin_amdgcn_mfma_f32_16x16x32_bf16(af[i], bfr[j], acc[i][j], 0, 0, 0);
    __syncthreads();
  }

  #pragma unroll
  for (int i=0;i<4;i++){
    #pragma unroll
    for (int j=0;j<4;j++){
      int n_l = wn + j*16 + col;
      #pragma unroll
      for (int r=0;r<4;r++){
        int m = m0 + wm + i*16 + quad*4 + r;
        float c = acc[i][j][r];
        if constexpr(MODE==0){
          int n = n0 + n_l;
          out[(size_t)m*DMODEL + n] = fmaxf(c + bias[n], 0.f);
        } else {
          int n = n0 + n_l;
          if (n < DIN) outb[(size_t)m*DIN + n]        = (__bf16)c;
          else         outz[(size_t)m*DIN + n - DIN]  = (__bf16)siluf(c);
        }
      }
    }
  }
}

// ---------------- fused segment front: dwconv+silu -> MFMA x_proj -> vbc/dt -> scanA summary
__global__ __launch_bounds__(256) void k_seg(const __bf16* __restrict__ xi,
    __bf16* __restrict__ xcg, const __bf16* __restrict__ wpb,
    const float* __restrict__ cw, const float* __restrict__ cb,
    const float* __restrict__ dtw, const float* __restrict__ dtb,
    const float* __restrict__ alog,
    float* __restrict__ vbc, __bf16* __restrict__ dtg,
    float* __restrict__ cseg, float* __restrict__ sdtb){
  __shared__ __bf16 sxc[64][264];
  __shared__ float vls[64][68];
  const int tid = threadIdx.x;
  const size_t m0 = (size_t)blockIdx.x * 64;
  const int b = (int)(m0 >> 11);
  const int g = (int)((m0 >> 6) & (NSEG-1));
  const int seq0 = (int)(m0 & 2047);

  // ---- phase 0: depthwise conv(k=4, bf16 in) + silu -> xcg (bf16) + sxc (bf16 LDS) ----
  {
    const int c4 = (tid & 63) * 4;
    const int tw = tid >> 6;
    float wc[4][4];
    #pragma unroll
    for (int j=0;j<4;j++)
      #pragma unroll
      for (int k=0;k<4;k++) wc[j][k] = cw[(c4+j)*4 + k];
    float4 cb4 = *(const float4*)(cb + c4);
    #pragma unroll
    for (int it=0; it<16; it++){
      int t = it*4 + tw;
      float4 acc = cb4;
      #pragma unroll
      for (int k=0;k<4;k++){
        if (seq0 + t - 3 + k >= 0){
          bf16x4 xv = *(const bf16x4*)(xi + (m0 + t - 3 + k)*DIN + c4);
          acc.x = fmaf(wc[0][k], (float)xv[0], acc.x);
          acc.y = fmaf(wc[1][k], (float)xv[1], acc.y);
          acc.z = fmaf(wc[2][k], (float)xv[2], acc.z);
          acc.w = fmaf(wc[3][k], (float)xv[3], acc.w);
        }
      }
      bf16x4 o;
      o[0]=(__bf16)siluf(acc.x); o[1]=(__bf16)siluf(acc.y);
      o[2]=(__bf16)siluf(acc.z); o[3]=(__bf16)siluf(acc.w);
      *(bf16x4*)(xcg + (m0 + t)*DIN + c4) = o;
      *(bf16x4*)&sxc[t][c4] = o;
    }
  }
  __syncthreads();

  // ---- phase 1: MFMA vls[64][64] = sxc[64x256] @ wpb[64x256]^T ----
  {
    const int wave = tid >> 6, lane = tid & 63;
    const int col = lane & 15, quad = lane >> 4;
    const int wn = wave * 16;
    f32x4 acc[4];
    #pragma unroll
    for (int i=0;i<4;i++) acc[i] = (f32x4){0.f,0.f,0.f,0.f};
    #pragma unroll
    for (int kc=0;kc<8;kc++){
      bf16x8 bfr = *(const bf16x8*)(wpb + (size_t)(wn+col)*256 + kc*32 + quad*8);
      #pragma unroll
      for (int mi=0;mi<4;mi++){
        bf16x8 af = *(const bf16x8*)&sxc[mi*16 + col][kc*32 + quad*8];
        acc[mi] = __builtin_amdgcn_mfma_f32_16x16x32_bf16(af, bfr, acc[mi], 0, 0, 0);
      }
    }
    #pragma unroll
    for (int mi=0;mi<4;mi++)
      #pragma unroll
      for (int r=0;r<4;r++)
        vls[mi*16 + quad*4 + r][wn + col] = acc[mi][r];
  }
  __syncthreads();

  // ---- phase 2: write vbc[t][32] = BC only ----
  #pragma unroll
  for (int p=0;p<8;p++){
    int j = p*256 + tid;           // 2048
    int t = j >> 5, i = j & 31;
    vbc[(m0+t)*32 + i] = vls[t][8+i];
  }

  // ---- phase 3: scanA summary, thread = channel; u from LDS; store dt bf16 ----
  {
    const int d = tid;
    const float a0 = -fast_exp(alog[d*DST]) * L2E;
    bool fast = true;
    for (int s=1;s<16;s++){
      float as = -fast_exp(alog[d*DST + s]) * L2E;
      fast = fast && (fabsf(as - (float)(s+1)*a0) <= 1e-3f*fabsf(as));
    }
    float4 w8a = *(const float4*)(dtw + d*8);
    float4 w8b = *(const float4*)(dtw + d*8 + 4);
    const float bd = dtb[d];
    float h0=0.f,h1=0.f,h2=0.f,h3=0.f,h4=0.f,h5=0.f,h6=0.f,h7=0.f;
    float h8=0.f,h9=0.f,h10=0.f,h11=0.f,h12=0.f,h13=0.f,h14=0.f,h15=0.f;
    float ssum = 0.f;
    if (fast){
      for (int t=0;t<SEG;t++){
        float4 v0 = *(const float4*)&vls[t][0];
        float4 v1 = *(const float4*)&vls[t][4];
        float lin = bd;
        lin = fmaf(v0.x,w8a.x, fmaf(v0.y,w8a.y, fmaf(v0.z,w8a.z, fmaf(v0.w,w8a.w, lin))));
        lin = fmaf(v1.x,w8b.x, fmaf(v1.y,w8b.y, fmaf(v1.z,w8b.z, fmaf(v1.w,w8b.w, lin))));
        float dt = softplusf(lin);
        ssum += dt;
        dtg[(m0+t)*DIN + d] = (__bf16)dt;
        float u = (float)sxc[t][d];
        float du = dt*u;
        float r = fexp2(dt*a0);
        float dA = 1.f;
        float4 q0 = *(const float4*)&vls[t][8];
        float4 q1 = *(const float4*)&vls[t][12];
        float4 q2 = *(const float4*)&vls[t][16];
        float4 q3 = *(const float4*)&vls[t][20];
        float4 q4 = *(const float4*)&vls[t][24];
        float4 q5 = *(const float4*)&vls[t][28];
        float4 q6 = *(const float4*)&vls[t][32];
        float4 q7 = *(const float4*)&vls[t][36];
        SPF(h0,h1,q0)  SPF(h2,h3,q1)  SPF(h4,h5,q2)  SPF(h6,h7,q3)
        SPF(h8,h9,q4)  SPF(h10,h11,q5) SPF(h12,h13,q6) SPF(h14,h15,q7)
      }
    } else {
      for (int t=0;t<SEG;t++){
        float4 v0 = *(const float4*)&vls[t][0];
        float4 v1 = *(const float4*)&vls[t][4];
        float lin = bd;
        lin = fmaf(v0.x,w8a.x, fmaf(v0.y,w8a.y, fmaf(v0.z,w8a.z, fmaf(v0.w,w8a.w, lin))));
        lin = fmaf(v1.x,w8b.x, fmaf(v1.y,w8b.y, fmaf(v1.z,w8b.z, fmaf(v1.w,w8b.w, lin))));
        float dt = softplusf(lin);
        ssum += dt;
        dtg[(m0+t)*DIN + d] = (__bf16)dt;
        float u = (float)sxc[t][d];
        float du = dt*u;
        float4 q0 = *(const float4*)&vls[t][8];
        float4 q1 = *(const float4*)&vls[t][12];
        float4 q2 = *(const float4*)&vls[t][16];
        float4 q3 = *(const float4*)&vls[t][20];
        float4 q4 = *(const float4*)&vls[t][24];
        float4 q5 = *(const float4*)&vls[t][28];
        float4 q6 = *(const float4*)&vls[t][32];
        float4 q7 = *(const float4*)&vls[t][36];
        SPSA(h0,h1,q0,0,1)   SPSA(h2,h3,q1,2,3)   SPSA(h4,h5,q2,4,5)   SPSA(h6,h7,q3,6,7)
        SPSA(h8,h9,q4,8,9)   SPSA(h10,h11,q5,10,11) SPSA(h12,h13,q6,12,13) SPSA(h14,h15,q7,14,15)
      }
    }
    size_t base = (((size_t)b*NSEG + g)*DIN + d)*DST;
    float4 o;
    o.x=h0; o.y=h1; o.z=h2; o.w=h3;     *(float4*)(cseg + base     ) = o;
    o.x=h4; o.y=h5; o.z=h6; o.w=h7;     *(float4*)(cseg + base +  4) = o;
    o.x=h8; o.y=h9; o.z=h10; o.w=h11;   *(float4*)(cseg + base +  8) = o;
    o.x=h12; o.y=h13; o.z=h14; o.w=h15; *(float4*)(cseg + base + 12) = o;
    sdtb[((size_t)b*NSEG + g)*DIN + d] = ssum;
  }
}

// ---------------- scanB: serial combine over segments ----------------
__global__ __launch_bounds__(256) void k_scanB(float* __restrict__ cseg,
    const float* __restrict__ sdtb, const float* __restrict__ alog){
  int gl = blockIdx.x*256 + threadIdx.x;
  int b   = gl >> 12;
  int rem = gl & 4095;
  int d = rem >> 4, s = rem & 15;
  const float a = -fast_exp(alog[d*DST + s]) * L2E;
  float h = 0.f;
  for (int g=0; g<NSEG; g++){
    size_t base = ((size_t)b*NSEG + g)*DIN;
    float sd = sdtb[base + d];
    size_t ci = (base + d)*DST + s;
    float c = cseg[ci];
    cseg[ci] = h;
    h = fmaf(fexp2(a*sd), h, c);
  }
}

// ---------------- scanC3: scan + gate + out_proj MFMA + residual + next-layer rms ------
__global__ __launch_bounds__(256) void k_scanC3(float* __restrict__ xres,
    const __bf16* __restrict__ ub, const float* __restrict__ vbc,
    const __bf16* __restrict__ gzb, const __bf16* __restrict__ dtg,
    const float* __restrict__ alog, const float* __restrict__ Dpar,
    const float* __restrict__ cseg, const __bf16* __restrict__ wout,
    float* __restrict__ rs){
  __shared__ __bf16 sy[64][264];        // gated y (bf16); later aliased as sx fp32 [64][132]
  __shared__ float svbc[64][32];
  float* sx = (float*)sy;
  const int tid = threadIdx.x;
  const size_t m0 = (size_t)blockIdx.x * 64;
  const int b = (int)(m0 >> 11);
  const int g = (int)((m0 >> 6) & (NSEG-1));

  #pragma unroll
  for (int p=0;p<8;p++){
    int j = p*256 + tid;           // 2048
    int t = j >> 5, i = j & 31;
    svbc[t][i] = vbc[(m0+t)*32 + i];
  }

  // ---- scan phase (thread = channel) ----
  {
    const int d = tid;
    const float a0 = -fast_exp(alog[d*DST]) * L2E;
    bool fast = true;
    for (int s=1;s<16;s++){
      float as = -fast_exp(alog[d*DST + s]) * L2E;
      fast = fast && (fabsf(as - (float)(s+1)*a0) <= 1e-3f*fabsf(as));
    }
    const float Dv = Dpar[d];
    size_t base = (((size_t)b*NSEG + g)*DIN + d)*DST;
    float4 hv0 = *(const float4*)(cseg + base);
    float4 hv1 = *(const float4*)(cseg + base + 4);
    float4 hv2 = *(const float4*)(cseg + base + 8);
    float4 hv3 = *(const float4*)(cseg + base + 12);
    float h0=hv0.x,h1=hv0.y,h2=hv0.z,h3=hv0.w;
    float h4=hv1.x,h5=hv1.y,h6=hv1.z,h7=hv1.w;
    float h8=hv2.x,h9=hv2.y,h10=hv2.z,h11=hv2.w;
    float h12=hv3.x,h13=hv3.y,h14=hv3.z,h15=hv3.w;
    __syncthreads();   // svbc staged

    if (fast){
      for (int t=0;t<SEG;t++){
        float dt = (float)dtg[(m0+t)*DIN + d];
        float u  = (float)ub[(m0+t)*DIN + d];
        float du = dt*u;
        float r = fexp2(dt*a0);
        float dA = 1.f, y = 0.f;
        float4 q0 = *(const float4*)&svbc[t][0];
        float4 q1 = *(const float4*)&svbc[t][4];
        float4 q2 = *(const float4*)&svbc[t][8];
        float4 q3 = *(const float4*)&svbc[t][12];
        float4 q4 = *(const float4*)&svbc[t][16];
        float4 q5 = *(const float4*)&svbc[t][20];
        float4 q6 = *(const float4*)&svbc[t][24];
        float4 q7 = *(const float4*)&svbc[t][28];
        SPFY(h0,h1,q0)  SPFY(h2,h3,q1)  SPFY(h4,h5,q2)  SPFY(h6,h7,q3)
        SPFY(h8,h9,q4)  SPFY(h10,h11,q5) SPFY(h12,h13,q6) SPFY(h14,h15,q7)
        float gz = (float)gzb[(m0+t)*DIN + d];
        sy[t][d] = (__bf16)((y + u*Dv) * gz);
      }
    } else {
      for (int t=0;t<SEG;t++){
        float dt = (float)dtg[(m0+t)*DIN + d];
        float u  = (float)ub[(m0+t)*DIN + d];
        float du = dt*u;
        float y = 0.f;
        float4 q0 = *(const float4*)&svbc[t][0];
        float4 q1 = *(const float4*)&svbc[t][4];
        float4 q2 = *(const float4*)&svbc[t][8];
        float4 q3 = *(const float4*)&svbc[t][12];
        float4 q4 = *(const float4*)&svbc[t][16];
        float4 q5 = *(const float4*)&svbc[t][20];
        float4 q6 = *(const float4*)&svbc[t][24];
        float4 q7 = *(const float4*)&svbc[t][28];
        SPSY(h0,h1,q0,0,1)   SPSY(h2,h3,q1,2,3)   SPSY(h4,h5,q2,4,5)   SPSY(h6,h7,q3,6,7)
        SPSY(h8,h9,q4,8,9)   SPSY(h10,h11,q5,10,11) SPSY(h12,h13,q6,12,13) SPSY(h14,h15,q7,14,15)
        float gz = (float)gzb[(m0+t)*DIN + d];
        sy[t][d] = (__bf16)((y + u*Dv) * gz);
      }
    }
  }
  __syncthreads();   // sy complete

  // ---- out_proj MFMA: newx[64][128] = sy[64x256] @ wout[128x256]^T + xres ----
  const int wave = tid >> 6, lane = tid & 63;
  const int col = lane & 15, quad = lane >> 4;
  const int wn = wave * 32;
  f32x4 acc[4][2];
  #pragma unroll
  for (int i=0;i<4;i++)
    #pragma unroll
    for (int j=0;j<2;j++) acc[i][j] = (f32x4){0.f,0.f,0.f,0.f};
  #pragma unroll
  for (int kc=0;kc<8;kc++){
    bf16x8 bfr0 = *(const bf16x8*)(wout + (size_t)(wn +      col)*256 + kc*32 + quad*8);
    bf16x8 bfr1 = *(const bf16x8*)(wout + (size_t)(wn + 16 + col)*256 + kc*32 + quad*8);
    #pragma unroll
    for (int mi=0;mi<4;mi++){
      bf16x8 af = *(const bf16x8*)&sy[mi*16 + col][kc*32 + quad*8];
      acc[mi][0] = __builtin_amdgcn_mfma_f32_16x16x32_bf16(af, bfr0, acc[mi][0], 0, 0, 0);
      acc[mi][1] = __builtin_amdgcn_mfma_f32_16x16x32_bf16(af, bfr1, acc[mi][1], 0, 0, 0);
    }
  }
  __syncthreads();   // sy reads done; sx may now overwrite

  // ---- epilogue: residual add -> global + LDS(sx); then rms for next layer ----
  #pragma unroll
  for (int mi=0;mi<4;mi++){
    #pragma unroll
    for (int j=0;j<2;j++){
      int n = wn + j*16 + col;
      #pragma unroll
      for (int r=0;r<4;r++){
        int ml = mi*16 + quad*4 + r;
        size_t go = (m0 + ml)*DMODEL + n;
        float nx = xres[go] + acc[mi][j][r];
        xres[go] = nx;
        sx[ml*132 + n] = nx;
      }
    }
  }
  __syncthreads();
  {
    int row = tid >> 2, q = tid & 3;
    const float* pr = sx + row*132 + q*32;
    float ss = 0.f;
    #pragma unroll
    for (int i=0;i<32;i+=4){
      float4 v = *(const float4*)(pr + i);
      ss += v.x*v.x + v.y*v.y + v.z*v.z + v.w*v.w;
    }
    ss += __shfl_xor(ss, 1);
    ss += __shfl_xor(ss, 2);
    if (q == 0) rs[m0 + row] = rsqrtf(ss*(1.f/128.f) + 1e-5f);
  }
}

// ---------------- masked mean pool over a chunk ----------------
__global__ __launch_bounds__(256) void k_pool1(const float* __restrict__ x,
    const float* __restrict__ mask, float* __restrict__ part, float* __restrict__ pmask){
  int b = blockIdx.y, seg = blockIdx.x;
  int d = threadIdx.x & 127, half = threadIdx.x >> 7;
  int t0 = seg*128 + half*64;
  float acc = 0.f, macc = 0.f;
  for (int i=0;i<64;i++){
    int t = t0 + i;
    float mv = mask[(size_t)b*SL + t];
    acc = fmaf(x[((size_t)b*SL + t)*DMODEL + d], mv, acc);
    macc += mv;
  }
  __shared__ float sm[256];
  __shared__ float smm[2];
  sm[threadIdx.x] = acc;
  if (d == 0) smm[half] = macc;
  __syncthreads();
  if (half == 0){
    part[((size_t)b*16 + seg)*128 + d] = sm[d] + sm[128+d];
    if (d == 0) pmask[b*16 + seg] = smm[0] + smm[1];
  }
}

__global__ void k_pool2(const float* __restrict__ part, const float* __restrict__ pmask,
                        float* __restrict__ pooled){
  int b = blockIdx.x, d = threadIdx.x;
  float acc = 0.f, ms = 0.f;
  for (int s=0;s<16;s++){ acc += part[((size_t)b*16+s)*128 + d]; ms += pmask[b*16+s]; }
  pooled[(size_t)b*128 + d] = acc / fmaxf(ms, 1e-9f);
}

// ---------------- tiny MLP ----------------
__global__ void k_mlp_a(const float* __restrict__ in, const float* __restrict__ w,
                        const float* __restrict__ bias, float* __restrict__ out, int K){
  int b = blockIdx.y;
  int n = blockIdx.x*128 + threadIdx.x;
  const float4* pw = (const float4*)(w + (size_t)n*K);
  const float4* pi = (const float4*)(in + (size_t)b*K);
  float acc = 0.f;
  for (int k=0;k<K/4;k++){
    float4 a = pi[k], ww = pw[k];
    acc = fmaf(a.x,ww.x, fmaf(a.y,ww.y, fmaf(a.z,ww.z, fmaf(a.w,ww.w, acc))));
  }
  out[(size_t)b*512 + n] = fmaxf(acc + bias[n], 0.f);
}

__global__ void k_mlp3(const float* __restrict__ h, const float* __restrict__ w,
                       const float* __restrict__ bias, float* __restrict__ out){
  int b = blockIdx.x;
  int n = threadIdx.x >> 6, lane = threadIdx.x & 63;
  if (n >= 3) return;
  float acc = 0.f;
  for (int k=lane; k<512; k+=64) acc = fmaf(h[(size_t)b*512+k], w[(size_t)n*512+k], acc);
  #pragma unroll
  for (int m=1;m<64;m<<=1) acc += __shfl_xor(acc, m);
  if (lane == 0) out[(size_t)b*3 + n] = acc + bias[n];
}

// ---------------- launch ----------------
extern "C" void kernel_launch(void* const* d_in, const int* in_sizes, int n_in,
                              void* d_out, int out_size, void* d_ws, size_t ws_size,
                              hipStream_t stream){
  const int*   tokens = (const int*)  d_in[0];
  const float* mask   = (const float*)d_in[1];
  const float* emb    = (const float*)d_in[2];
  const float* bn_w   = (const float*)d_in[3];
  const float* bn_b   = (const float*)d_in[4];
  const float* conv_w = (const float*)d_in[5];
  const float* conv_b = (const float*)d_in[6];
  const float* in_w   = (const float*)d_in[7];
  const float* c1_w   = (const float*)d_in[8];
  const float* c1_b   = (const float*)d_in[9];
  const float* xp_w   = (const float*)d_in[10];
  const float* dtp_w  = (const float*)d_in[11];
  const float* dtp_b  = (const float*)d_in[12];
  const float* A_log  = (const float*)d_in[13];
  const float* D_par  = (const float*)d_in[14];
  const float* out_w  = (const float*)d_in[15];
  const float* nrm_w  = (const float*)d_in[16];
  const float* l1w = (const float*)d_in[17]; const float* l1b = (const float*)d_in[18];
  const float* l2w = (const float*)d_in[19]; const float* l2b = (const float*)d_in[20];
  const float* l3w = (const float*)d_in[21]; const float* l3b = (const float*)d_in[22];
  float* dout = (float*)d_out;

  // per-token floats: x 128 + rs 1 + xi(bf16) 128 + xc(bf16) 128 + vbc 32 + cseg 64
  //                   + sdt 4 + gz(bf16) 128 + dt(bf16) 128 = 741
  int CB = 64;
  while (CB > 1 && ((size_t)CB*SL*741 + FIX_END)*4 > ws_size) CB >>= 1;
  if (((size_t)CB*SL*741 + FIX_END)*4 > ws_size) return;
  const size_t CTOK = (size_t)CB*SL;

  float* ws  = (float*)d_ws;
  float* pl  = ws + FIX_PL;
  float* pm  = ws + FIX_PM;
  float* pd  = ws + FIX_PD;
  float* h1  = ws + FIX_H1;
  float* h2  = ws + FIX_H2;
  __bf16* wpb   = (__bf16*)(ws + FIX_WP);
  __bf16* w2b   = (__bf16*)(ws + FIX_W2B);
  __bf16* winb  = (__bf16*)(ws + FIX_WINB);
  __bf16* woutb = (__bf16*)(ws + FIX_WOUTB);
  float* xcb = ws + FIX_END;                 // CTOK*128 fp32 residual x
  float* rs  = xcb + CTOK*128;               // CTOK
  __bf16* xib = (__bf16*)(rs + CTOK);        // CTOK*256 bf16 (x-branch)
  __bf16* xcc = xib + CTOK*256;              // CTOK*256 bf16 (conv out u)
  float* pad = (float*)xib;                  // fp32 embed-pad scratch (aliases xib+xcc)
  float* vbc = (float*)(xcc + CTOK*256);     // CTOK*32 fp32 (interleaved BC)
  float* csg = vbc + CTOK*32;                // CTOK*64
  float* sdt = csg + CTOK*64;                // CTOK*4
  __bf16* zb  = (__bf16*)(sdt + CTOK*4);     // CTOK*256 bf16 (gz)
  __bf16* dtg = zb + CTOK*256;               // CTOK*256 bf16 (dt)

  k_w2b<<<192, 256, 0, stream>>>(conv_w, w2b);
  k_cvt<<<1024, 256, 0, stream>>>(in_w,  winb,  4*512*128);
  k_cvt<<<512,  256, 0, stream>>>(out_w, woutb, 4*128*256);
  k_wprep<<<256, 256, 0, stream>>>(xp_w, wpb);

  const int nchunks = NB / CB;
  for (int c = 0; c < nchunks; c++){
    const int* tok_c = tokens + (size_t)c*CTOK;

    k_embed<<<CB*2050, 128, 0, stream>>>(tok_c, emb, bn_w, bn_b, pad);
    k_mgemm<0,384,128><<<dim3(1, CTOK/128), 256, 0, stream>>>(
        pad, w2b, conv_b, nullptr, nullptr, xcb, nullptr, nullptr);
    k_rmsscale<<<CTOK/4, 256, 0, stream>>>(xcb, rs);

    for (int layer = 0; layer < NLAYER; layer++){
      const __bf16* lin = winb  + (size_t)layer*512*128;
      const float* lcw  = c1_w  + (size_t)layer*DIN*4;
      const float* lcb  = c1_b  + (size_t)layer*DIN;
      const float* ldw  = dtp_w + (size_t)layer*DIN*8;
      const float* ldb  = dtp_b + (size_t)layer*DIN;
      const float* lal  = A_log + (size_t)layer*DIN*DST;
      const float* lD   = D_par + (size_t)layer*DIN;
      const __bf16* low = woutb + (size_t)layer*128*256;
      const float* lnw  = nrm_w + (size_t)layer*128;

      k_mgemm<1,128,512><<<dim3(4, CTOK/128), 256, 0, stream>>>(
          xcb, lin, nullptr, rs, lnw, nullptr, xib, zb);
      k_seg<<<(int)(CTOK/64), 256, 0, stream>>>(
          xib, xcc, wpb + (size_t)layer*64*256, lcw, lcb, ldw, ldb, lal, vbc, dtg, csg, sdt);
      k_scanB<<<CB*16, 256, 0, stream>>>(csg, sdt, lal);
      k_scanC3<<<(int)(CTOK/64), 256, 0, stream>>>(
          xcb, xcc, vbc, zb, dtg, lal, lD, csg, low, rs);
    }

    k_pool1<<<dim3(16, CB), 256, 0, stream>>>(
        xcb, mask + (size_t)c*CTOK, pl + (size_t)c*CB*16*128, pm + (size_t)c*CB*16);
  }

  k_pool2<<<NB, 128, 0, stream>>>(pl, pm, pd);
  k_mlp_a<<<dim3(4, NB), 128, 0, stream>>>(pd, l1w, l1b, h1, 128);
  k_mlp_a<<<dim3(4, NB), 128, 0, stream>>>(h1, l2w, l2b, h2, 512);
  k_mlp3<<<NB, 256, 0, stream>>>(h2, l3w, l3b, dout);
}

// Round 15
// 1588.082 us; speedup vs baseline: 11.1288x; 1.0274x over previous
//
#include <hip/hip_runtime.h>
#include <math.h>

// ---------------- problem constants ----------------
#define NB     64
#define SL     2048
#define NTOK   (NB*SL)
#define EMB_D  128
#define DMODEL 128
#define DIN    256
#define DST    16
#define NLAYER 4
#define SEG    64
#define NSEG   (SL/SEG)        // 32
#define L2E    1.4426950408889634f
#define LN2    0.6931471805599453f

typedef __bf16 bf16x8 __attribute__((ext_vector_type(8)));
typedef __bf16 bf16x4 __attribute__((ext_vector_type(4)));
typedef float  f32x4  __attribute__((ext_vector_type(4)));

// fixed small region (floats)
#define FIX_PL   ((size_t)0)
#define FIX_PM   (FIX_PL + 131072)
#define FIX_PD   (FIX_PM + 1024)
#define FIX_H1   (FIX_PD + 8192)
#define FIX_H2   (FIX_H1 + 32768)
#define FIX_WP   (FIX_H2 + 32768)
#define FIX_W2B  (FIX_WP + 65536)
#define FIX_WINB (FIX_W2B + 24576)
#define FIX_WOUTB (FIX_WINB + 131072)
#define FIX_END  (FIX_WOUTB + 65536)

// raw-instruction transcendentals
__device__ __forceinline__ float fexp2(float x){ return __builtin_amdgcn_exp2f(x); }
__device__ __forceinline__ float flog2(float x){ return __builtin_amdgcn_logf(x); }
__device__ __forceinline__ float frcp (float x){ return __builtin_amdgcn_rcpf(x); }
__device__ __forceinline__ float fast_exp(float x){ return fexp2(x*L2E); }
__device__ __forceinline__ float siluf(float v){ return v * frcp(1.f + fast_exp(-v)); }
__device__ __forceinline__ float softplusf(float a){
  return fmaxf(a,0.f) + flog2(1.f + fexp2(-fabsf(a)*L2E)) * LN2;
}
__device__ __forceinline__ unsigned short bfbits(float x){
  __bf16 b = (__bf16)x; return __builtin_bit_cast(unsigned short, b);
}
__device__ __forceinline__ unsigned int packdu(float dt, float u){
  return ((unsigned int)bfbits(u) << 16) | (unsigned int)bfbits(dt);
}

// exact-path state-pair macros (fallback only)
#define SPSA(hA,hB,q,s0,s1) { float eA=fexp2(dt*(-fast_exp(alog[d*DST+s0])*L2E)); \
                              hA=fmaf(eA,hA,du*q.x); \
                              float eB=fexp2(dt*(-fast_exp(alog[d*DST+s1])*L2E)); \
                              hB=fmaf(eB,hB,du*q.z); }
#define SPSY(hA,hB,q,s0,s1) { float eA=fexp2(dt*(-fast_exp(alog[d*DST+s0])*L2E)); \
                              hA=fmaf(eA,hA,du*q.x); y=fmaf(hA,q.y,y); \
                              float eB=fexp2(dt*(-fast_exp(alog[d*DST+s1])*L2E)); \
                              hB=fmaf(eB,hB,du*q.z); y=fmaf(hB,q.w,y); }

// power tree r^1..r^16 from r (depth 4)
#define POWTREE(r) \
  float r2=(r)*(r), r4=r2*r2, r8=r4*r4; \
  float r3=r2*(r), r5=r4*(r), r6=r4*r2, r7=r4*r3; \
  float r9=r8*(r), r10=r8*r2, r11=r8*r3, r12=r8*r4; \
  float r13=r8*r5, r14=r8*r6, r15=r8*r7, r16=r8*r8;

// ---------------- weight prep ----------------
__global__ void k_w2b(const float* __restrict__ cw, __bf16* __restrict__ w2){
  int g = blockIdx.x*256 + threadIdx.x;
  if (g >= 128*384) return;
  int d = g / 384, j = g % 384;
  int k = j >> 7, e = j & 127;
  w2[d*384 + k*128 + e] = (__bf16)cw[d*384 + e*3 + k];
}

__global__ void k_cvt(const float* __restrict__ src, __bf16* __restrict__ dst, int n){
  int i = blockIdx.x*256 + threadIdx.x;
  if (i < n) dst[i] = (__bf16)src[i];
}

__global__ void k_wprep(const float* __restrict__ xpw, __bf16* __restrict__ wp){
  int g = blockIdx.x*256 + threadIdx.x;      // 65536
  int l = g >> 14, rem = g & 16383;
  int n = rem >> 8, k = rem & 255;
  float v = 0.f;
  if (n < 8){
    v = xpw[(size_t)l*40*256 + n*256 + k];
  } else if (n < 40){
    int i = n - 8;
    int row = 8 + ((i&1)<<4) + (i>>1);
    v = xpw[(size_t)l*40*256 + row*256 + k];
  }
  wp[g] = (__bf16)v;
}

// ---------------- embed + BN into padded chunk buffer (fp32 scratch) ----------------
__global__ void k_embed(const int* __restrict__ tok, const float* __restrict__ emb,
                        const float* __restrict__ bnw, const float* __restrict__ bnb,
                        float* __restrict__ xp){
  int r = blockIdx.x;                 // CB*2050 rows
  int e = threadIdx.x;                // 128
  int b = r / 2050, tp = r % 2050;
  float v = 0.f;
  if (tp != 0 && tp != 2049){
    int t = tp - 1;
    int id = tok[(size_t)b*SL + t];
    float s = bnw[e] * rsqrtf(1.0f + 1e-5f);
    v = emb[(size_t)id*EMB_D + e] * s + bnb[e];
  }
  xp[(size_t)r*EMB_D + e] = v;
}

// ---------------- rmsnorm scale only (after front conv) ----------------
__global__ __launch_bounds__(256) void k_rmsscale(const float* __restrict__ x,
                                                  float* __restrict__ rs){
  int wv = threadIdx.x>>6, lane = threadIdx.x&63;
  size_t tok = (size_t)blockIdx.x*4 + wv;
  float2 v = *(const float2*)(x + tok*128 + lane*2);
  float ss = v.x*v.x + v.y*v.y;
  #pragma unroll
  for (int m=1;m<64;m<<=1) ss += __shfl_xor(ss, m);
  float r = rsqrtf(ss*(1.f/128.f) + 1e-5f);
  if (lane == 0) rs[tok] = r;
}

// ---------------- bf16 MFMA GEMM ----------------
// MODE 0: A fp32 (padded im2col rows), epi relu(+bias) -> out fp32
// MODE 1: A fp32 (x), staged *rs*nw; epi n<256 -> outb (xi bf16), else outz (gz bf16)
template<int MODE, int K, int N>
__global__ __launch_bounds__(256) void k_mgemm(
    const void* __restrict__ Av, const __bf16* __restrict__ Wb,
    const float* __restrict__ bias, const float* __restrict__ rsp,
    const float* __restrict__ nwp,
    float* __restrict__ out, __bf16* __restrict__ outb, __bf16* __restrict__ outz){
  __shared__ __bf16 As[128][40];
  __shared__ __bf16 Bs[128][40];
  const int tid  = threadIdx.x;
  const int wave = tid >> 6;
  const int lane = tid & 63;
  const int col  = lane & 15;
  const int quad = lane >> 4;
  const int wm = (wave & 1) * 64;
  const int wn = (wave >> 1) * 64;
  const int m0 = blockIdx.y * 128;
  const int n0 = blockIdx.x * 128;

  f32x4 acc[4][4];
  #pragma unroll
  for (int i=0;i<4;i++)
    #pragma unroll
    for (int j=0;j<4;j++) acc[i][j] = (f32x4){0.f,0.f,0.f,0.f};

  size_t abase;
  if constexpr(MODE==0){
    int bb = m0 >> 11, tloc = m0 & 2047;
    abase = ((size_t)bb*2050 + tloc) * 128;
  } else {
    abase = (size_t)m0 * K;
  }

  const int sm = tid >> 3;
  const int sk4 = (tid & 7) * 4;
  const int bn = tid >> 2;
  const int bk8 = (tid & 3) * 8;

  for (int k0 = 0; k0 < K; k0 += 32){
    #pragma unroll
    for (int p=0;p<4;p++){
      int m = p*32 + sm;
      const float* A = (const float*)Av;
      float4 v;
      if constexpr(MODE==0){
        v = *(const float4*)(A + abase + (size_t)m*128 + k0 + sk4);
      } else {
        float4 x4 = *(const float4*)(A + abase + (size_t)m*K + k0 + sk4);
        float4 w4 = *(const float4*)(nwp + k0 + sk4);
        float s = rsp[m0 + m];
        v.x = x4.x*s*w4.x; v.y = x4.y*s*w4.y; v.z = x4.z*s*w4.z; v.w = x4.w*s*w4.w;
      }
      bf16x4 o;
      o[0] = (__bf16)v.x; o[1] = (__bf16)v.y; o[2] = (__bf16)v.z; o[3] = (__bf16)v.w;
      *(bf16x4*)&As[m][sk4] = o;
    }
    #pragma unroll
    for (int p=0;p<2;p++){
      int n = p*64 + bn;
      bf16x8 w = *(const bf16x8*)(Wb + (size_t)(n0+n)*K + k0 + bk8);
      *(bf16x8*)&Bs[n][bk8] = w;
    }
    __syncthreads();
    bf16x8 af[4], bfr[4];
    const int fq = quad*8;
    #pragma unroll
    for (int i=0;i<4;i++) af[i]  = *(const bf16x8*)&As[wm + i*16 + col][fq];
    #pragma unroll
    for (int j=0;j<4;j++) bfr[j] = *(const bf16x8*)&Bs[wn + j*16 + col][fq];
    #pragma unroll
    for (int i=0;i<4;i++)
      #pragma unroll
      for (int j=0;j<4;j++)
        acc[i][j] = __builtin_amdgcn_mfma_f32_16x16x32_bf16(af[i], bfr[j], acc[i][j], 0, 0, 0);
    __syncthreads();
  }

  #pragma unroll
  for (int i=0;i<4;i++){
    #pragma unroll
    for (int j=0;j<4;j++){
      int n_l = wn + j*16 + col;
      #pragma unroll
      for (int r=0;r<4;r++){
        int m = m0 + wm + i*16 + quad*4 + r;
        float c = acc[i][j][r];
        if constexpr(MODE==0){
          int n = n0 + n_l;
          out[(size_t)m*DMODEL + n] = fmaxf(c + bias[n], 0.f);
        } else {
          int n = n0 + n_l;
          if (n < DIN) outb[(size_t)m*DIN + n]        = (__bf16)c;
          else         outz[(size_t)m*DIN + n - DIN]  = (__bf16)siluf(c);
        }
      }
    }
  }
}

// ---------------- fused segment front: dwconv+silu -> MFMA x_proj -> vbc/dub -> scanA ----
__global__ __launch_bounds__(256) void k_seg(const __bf16* __restrict__ xi,
    const __bf16* __restrict__ wpb,
    const float* __restrict__ cw, const float* __restrict__ cb,
    const float* __restrict__ dtw, const float* __restrict__ dtb,
    const float* __restrict__ alog,
    float* __restrict__ vbc, unsigned int* __restrict__ dub,
    float* __restrict__ cseg, float* __restrict__ sdtb){
  __shared__ __bf16 sxc[64][264];
  __shared__ float vls[64][68];
  const int tid = threadIdx.x;
  const size_t m0 = (size_t)blockIdx.x * 64;
  const int b = (int)(m0 >> 11);
  const int g = (int)((m0 >> 6) & (NSEG-1));
  const int seq0 = (int)(m0 & 2047);

  // ---- phase 0: depthwise conv(k=4, bf16 in) + silu -> sxc (bf16 LDS only) ----
  {
    const int c4 = (tid & 63) * 4;
    const int tw = tid >> 6;
    float wc[4][4];
    #pragma unroll
    for (int j=0;j<4;j++)
      #pragma unroll
      for (int k=0;k<4;k++) wc[j][k] = cw[(c4+j)*4 + k];
    float4 cb4 = *(const float4*)(cb + c4);
    #pragma unroll
    for (int it=0; it<16; it++){
      int t = it*4 + tw;
      float4 acc = cb4;
      #pragma unroll
      for (int k=0;k<4;k++){
        if (seq0 + t - 3 + k >= 0){
          bf16x4 xv = *(const bf16x4*)(xi + (m0 + t - 3 + k)*DIN + c4);
          acc.x = fmaf(wc[0][k], (float)xv[0], acc.x);
          acc.y = fmaf(wc[1][k], (float)xv[1], acc.y);
          acc.z = fmaf(wc[2][k], (float)xv[2], acc.z);
          acc.w = fmaf(wc[3][k], (float)xv[3], acc.w);
        }
      }
      bf16x4 o;
      o[0]=(__bf16)siluf(acc.x); o[1]=(__bf16)siluf(acc.y);
      o[2]=(__bf16)siluf(acc.z); o[3]=(__bf16)siluf(acc.w);
      *(bf16x4*)&sxc[t][c4] = o;
    }
  }
  __syncthreads();

  // ---- phase 1: MFMA vls[64][64] = sxc[64x256] @ wpb[64x256]^T ----
  {
    const int wave = tid >> 6, lane = tid & 63;
    const int col = lane & 15, quad = lane >> 4;
    const int wn = wave * 16;
    f32x4 acc[4];
    #pragma unroll
    for (int i=0;i<4;i++) acc[i] = (f32x4){0.f,0.f,0.f,0.f};
    #pragma unroll
    for (int kc=0;kc<8;kc++){
      bf16x8 bfr = *(const bf16x8*)(wpb + (size_t)(wn+col)*256 + kc*32 + quad*8);
      #pragma unroll
      for (int mi=0;mi<4;mi++){
        bf16x8 af = *(const bf16x8*)&sxc[mi*16 + col][kc*32 + quad*8];
        acc[mi] = __builtin_amdgcn_mfma_f32_16x16x32_bf16(af, bfr, acc[mi], 0, 0, 0);
      }
    }
    #pragma unroll
    for (int mi=0;mi<4;mi++)
      #pragma unroll
      for (int r=0;r<4;r++)
        vls[mi*16 + quad*4 + r][wn + col] = acc[mi][r];
  }
  __syncthreads();

  // ---- phase 2: write vbc[t][32] = BC only ----
  #pragma unroll
  for (int p=0;p<8;p++){
    int j = p*256 + tid;           // 2048
    int t = j >> 5, i = j & 31;
    vbc[(m0+t)*32 + i] = vls[t][8+i];
  }

  // ---- phase 3: scanA summary; write packed (dt,u) ----
  {
    const int d = tid;
    const float a0 = -fast_exp(alog[d*DST]) * L2E;
    bool fast = true;
    for (int s=1;s<16;s++){
      float as = -fast_exp(alog[d*DST + s]) * L2E;
      fast = fast && (fabsf(as - (float)(s+1)*a0) <= 1e-3f*fabsf(as));
    }
    float4 w8a = *(const float4*)(dtw + d*8);
    float4 w8b = *(const float4*)(dtw + d*8 + 4);
    const float bd = dtb[d];
    float h0=0.f,h1=0.f,h2=0.f,h3=0.f,h4=0.f,h5=0.f,h6=0.f,h7=0.f;
    float h8=0.f,h9=0.f,h10=0.f,h11=0.f,h12=0.f,h13=0.f,h14=0.f,h15=0.f;
    float ssum = 0.f;
    if (fast){
      for (int t=0;t<SEG;t++){
        float4 v0 = *(const float4*)&vls[t][0];
        float4 v1 = *(const float4*)&vls[t][4];
        float lin = bd;
        lin = fmaf(v0.x,w8a.x, fmaf(v0.y,w8a.y, fmaf(v0.z,w8a.z, fmaf(v0.w,w8a.w, lin))));
        lin = fmaf(v1.x,w8b.x, fmaf(v1.y,w8b.y, fmaf(v1.z,w8b.z, fmaf(v1.w,w8b.w, lin))));
        float dt = softplusf(lin);
        ssum += dt;
        float u = (float)sxc[t][d];
        dub[(m0+t)*DIN + d] = packdu(dt, u);
        float du = dt*u;
        float r1 = fexp2(dt*a0);
        POWTREE(r1)
        float4 q0 = *(const float4*)&vls[t][8];
        float4 q1 = *(const float4*)&vls[t][12];
        float4 q2 = *(const float4*)&vls[t][16];
        float4 q3 = *(const float4*)&vls[t][20];
        float4 q4 = *(const float4*)&vls[t][24];
        float4 q5 = *(const float4*)&vls[t][28];
        float4 q6 = *(const float4*)&vls[t][32];
        float4 q7 = *(const float4*)&vls[t][36];
        h0 =fmaf(r1 ,h0 ,du*q0.x); h1 =fmaf(r2 ,h1 ,du*q0.z);
        h2 =fmaf(r3 ,h2 ,du*q1.x); h3 =fmaf(r4 ,h3 ,du*q1.z);
        h4 =fmaf(r5 ,h4 ,du*q2.x); h5 =fmaf(r6 ,h5 ,du*q2.z);
        h6 =fmaf(r7 ,h6 ,du*q3.x); h7 =fmaf(r8 ,h7 ,du*q3.z);
        h8 =fmaf(r9 ,h8 ,du*q4.x); h9 =fmaf(r10,h9 ,du*q4.z);
        h10=fmaf(r11,h10,du*q5.x); h11=fmaf(r12,h11,du*q5.z);
        h12=fmaf(r13,h12,du*q6.x); h13=fmaf(r14,h13,du*q6.z);
        h14=fmaf(r15,h14,du*q7.x); h15=fmaf(r16,h15,du*q7.z);
      }
    } else {
      for (int t=0;t<SEG;t++){
        float4 v0 = *(const float4*)&vls[t][0];
        float4 v1 = *(const float4*)&vls[t][4];
        float lin = bd;
        lin = fmaf(v0.x,w8a.x, fmaf(v0.y,w8a.y, fmaf(v0.z,w8a.z, fmaf(v0.w,w8a.w, lin))));
        lin = fmaf(v1.x,w8b.x, fmaf(v1.y,w8b.y, fmaf(v1.z,w8b.z, fmaf(v1.w,w8b.w, lin))));
        float dt = softplusf(lin);
        ssum += dt;
        float u = (float)sxc[t][d];
        dub[(m0+t)*DIN + d] = packdu(dt, u);
        float du = dt*u;
        float4 q0 = *(const float4*)&vls[t][8];
        float4 q1 = *(const float4*)&vls[t][12];
        float4 q2 = *(const float4*)&vls[t][16];
        float4 q3 = *(const float4*)&vls[t][20];
        float4 q4 = *(const float4*)&vls[t][24];
        float4 q5 = *(const float4*)&vls[t][28];
        float4 q6 = *(const float4*)&vls[t][32];
        float4 q7 = *(const float4*)&vls[t][36];
        SPSA(h0,h1,q0,0,1)   SPSA(h2,h3,q1,2,3)   SPSA(h4,h5,q2,4,5)   SPSA(h6,h7,q3,6,7)
        SPSA(h8,h9,q4,8,9)   SPSA(h10,h11,q5,10,11) SPSA(h12,h13,q6,12,13) SPSA(h14,h15,q7,14,15)
      }
    }
    size_t base = (((size_t)b*NSEG + g)*DIN + d)*DST;
    float4 o;
    o.x=h0; o.y=h1; o.z=h2; o.w=h3;     *(float4*)(cseg + base     ) = o;
    o.x=h4; o.y=h5; o.z=h6; o.w=h7;     *(float4*)(cseg + base +  4) = o;
    o.x=h8; o.y=h9; o.z=h10; o.w=h11;   *(float4*)(cseg + base +  8) = o;
    o.x=h12; o.y=h13; o.z=h14; o.w=h15; *(float4*)(cseg + base + 12) = o;
    sdtb[((size_t)b*NSEG + g)*DIN + d] = ssum;
  }
}

// ---------------- scanB: serial combine over segments ----------------
__global__ __launch_bounds__(256) void k_scanB(float* __restrict__ cseg,
    const float* __restrict__ sdtb, const float* __restrict__ alog){
  int gl = blockIdx.x*256 + threadIdx.x;
  int b   = gl >> 12;
  int rem = gl & 4095;
  int d = rem >> 4, s = rem & 15;
  const float a = -fast_exp(alog[d*DST + s]) * L2E;
  float h = 0.f;
  for (int g=0; g<NSEG; g++){
    size_t base = ((size_t)b*NSEG + g)*DIN;
    float sd = sdtb[base + d];
    size_t ci = (base + d)*DST + s;
    float c = cseg[ci];
    cseg[ci] = h;
    h = fmaf(fexp2(a*sd), h, c);
  }
}

// ---------------- scanC3: scan + gate + out_proj MFMA + residual + next-layer rms ------
__global__ __launch_bounds__(256) void k_scanC3(float* __restrict__ xres,
    const unsigned int* __restrict__ dub, const float* __restrict__ vbc,
    const __bf16* __restrict__ gzb,
    const float* __restrict__ alog, const float* __restrict__ Dpar,
    const float* __restrict__ cseg, const __bf16* __restrict__ wout,
    float* __restrict__ rs){
  __shared__ __bf16 sy[64][264];        // gated y (bf16); later aliased as sx fp32
  __shared__ float svbc[64][32];
  float* sx = (float*)sy;
  const int tid = threadIdx.x;
  const size_t m0 = (size_t)blockIdx.x * 64;
  const int b = (int)(m0 >> 11);
  const int g = (int)((m0 >> 6) & (NSEG-1));

  #pragma unroll
  for (int p=0;p<8;p++){
    int j = p*256 + tid;           // 2048
    int t = j >> 5, i = j & 31;
    svbc[t][i] = vbc[(m0+t)*32 + i];
  }

  // ---- scan phase (thread = channel) ----
  {
    const int d = tid;
    const float a0 = -fast_exp(alog[d*DST]) * L2E;
    bool fast = true;
    for (int s=1;s<16;s++){
      float as = -fast_exp(alog[d*DST + s]) * L2E;
      fast = fast && (fabsf(as - (float)(s+1)*a0) <= 1e-3f*fabsf(as));
    }
    const float Dv = Dpar[d];
    size_t base = (((size_t)b*NSEG + g)*DIN + d)*DST;
    float4 hv0 = *(const float4*)(cseg + base);
    float4 hv1 = *(const float4*)(cseg + base + 4);
    float4 hv2 = *(const float4*)(cseg + base + 8);
    float4 hv3 = *(const float4*)(cseg + base + 12);
    float h0=hv0.x,h1=hv0.y,h2=hv0.z,h3=hv0.w;
    float h4=hv1.x,h5=hv1.y,h6=hv1.z,h7=hv1.w;
    float h8=hv2.x,h9=hv2.y,h10=hv2.z,h11=hv2.w;
    float h12=hv3.x,h13=hv3.y,h14=hv3.z,h15=hv3.w;
    __syncthreads();   // svbc staged

    if (fast){
      for (int t=0;t<SEG;t++){
        unsigned int w = dub[(m0+t)*DIN + d];
        float u  = __builtin_bit_cast(float, w & 0xffff0000u);
        float dt = __builtin_bit_cast(float, w << 16);
        float du = dt*u;
        float r1 = fexp2(dt*a0);
        POWTREE(r1)
        float4 q0 = *(const float4*)&svbc[t][0];
        float4 q1 = *(const float4*)&svbc[t][4];
        float4 q2 = *(const float4*)&svbc[t][8];
        float4 q3 = *(const float4*)&svbc[t][12];
        float4 q4 = *(const float4*)&svbc[t][16];
        float4 q5 = *(const float4*)&svbc[t][20];
        float4 q6 = *(const float4*)&svbc[t][24];
        float4 q7 = *(const float4*)&svbc[t][28];
        h0 =fmaf(r1 ,h0 ,du*q0.x); h1 =fmaf(r2 ,h1 ,du*q0.z);
        h2 =fmaf(r3 ,h2 ,du*q1.x); h3 =fmaf(r4 ,h3 ,du*q1.z);
        h4 =fmaf(r5 ,h4 ,du*q2.x); h5 =fmaf(r6 ,h5 ,du*q2.z);
        h6 =fmaf(r7 ,h6 ,du*q3.x); h7 =fmaf(r8 ,h7 ,du*q3.z);
        h8 =fmaf(r9 ,h8 ,du*q4.x); h9 =fmaf(r10,h9 ,du*q4.z);
        h10=fmaf(r11,h10,du*q5.x); h11=fmaf(r12,h11,du*q5.z);
        h12=fmaf(r13,h12,du*q6.x); h13=fmaf(r14,h13,du*q6.z);
        h14=fmaf(r15,h14,du*q7.x); h15=fmaf(r16,h15,du*q7.z);
        float ya = fmaf(h0,q0.y, fmaf(h1,q0.w, fmaf(h2,q1.y, h3*q1.w)));
        float yb = fmaf(h4,q2.y, fmaf(h5,q2.w, fmaf(h6,q3.y, h7*q3.w)));
        float yc = fmaf(h8,q4.y, fmaf(h9,q4.w, fmaf(h10,q5.y, h11*q5.w)));
        float yd = fmaf(h12,q6.y, fmaf(h13,q6.w, fmaf(h14,q7.y, h15*q7.w)));
        float y = (ya+yb)+(yc+yd);
        float gz = (float)gzb[(m0+t)*DIN + d];
        sy[t][d] = (__bf16)((y + u*Dv) * gz);
      }
    } else {
      for (int t=0;t<SEG;t++){
        unsigned int w = dub[(m0+t)*DIN + d];
        float u  = __builtin_bit_cast(float, w & 0xffff0000u);
        float dt = __builtin_bit_cast(float, w << 16);
        float du = dt*u;
        float y = 0.f;
        float4 q0 = *(const float4*)&svbc[t][0];
        float4 q1 = *(const float4*)&svbc[t][4];
        float4 q2 = *(const float4*)&svbc[t][8];
        float4 q3 = *(const float4*)&svbc[t][12];
        float4 q4 = *(const float4*)&svbc[t][16];
        float4 q5 = *(const float4*)&svbc[t][20];
        float4 q6 = *(const float4*)&svbc[t][24];
        float4 q7 = *(const float4*)&svbc[t][28];
        SPSY(h0,h1,q0,0,1)   SPSY(h2,h3,q1,2,3)   SPSY(h4,h5,q2,4,5)   SPSY(h6,h7,q3,6,7)
        SPSY(h8,h9,q4,8,9)   SPSY(h10,h11,q5,10,11) SPSY(h12,h13,q6,12,13) SPSY(h14,h15,q7,14,15)
        float gz = (float)gzb[(m0+t)*DIN + d];
        sy[t][d] = (__bf16)((y + u*Dv) * gz);
      }
    }
  }
  __syncthreads();   // sy complete

  // ---- out_proj MFMA: newx[64][128] = sy[64x256] @ wout[128x256]^T + xres ----
  const int wave = tid >> 6, lane = tid & 63;
  const int col = lane & 15, quad = lane >> 4;
  const int wn = wave * 32;
  f32x4 acc[4][2];
  #pragma unroll
  for (int i=0;i<4;i++)
    #pragma unroll
    for (int j=0;j<2;j++) acc[i][j] = (f32x4){0.f,0.f,0.f,0.f};
  #pragma unroll
  for (int kc=0;kc<8;kc++){
    bf16x8 bfr0 = *(const bf16x8*)(wout + (size_t)(wn +      col)*256 + kc*32 + quad*8);
    bf16x8 bfr1 = *(const bf16x8*)(wout + (size_t)(wn + 16 + col)*256 + kc*32 + quad*8);
    #pragma unroll
    for (int mi=0;mi<4;mi++){
      bf16x8 af = *(const bf16x8*)&sy[mi*16 + col][kc*32 + quad*8];
      acc[mi][0] = __builtin_amdgcn_mfma_f32_16x16x32_bf16(af, bfr0, acc[mi][0], 0, 0, 0);
      acc[mi][1] = __builtin_amdgcn_mfma_f32_16x16x32_bf16(af, bfr1, acc[mi][1], 0, 0, 0);
    }
  }
  __syncthreads();   // sy reads done; sx may now overwrite

  // ---- epilogue: residual add -> global + LDS(sx); then rms for next layer ----
  #pragma unroll
  for (int mi=0;mi<4;mi++){
    #pragma unroll
    for (int j=0;j<2;j++){
      int n = wn + j*16 + col;
      #pragma unroll
      for (int r=0;r<4;r++){
        int ml = mi*16 + quad*4 + r;
        size_t go = (m0 + ml)*DMODEL + n;
        float nx = xres[go] + acc[mi][j][r];
        xres[go] = nx;
        sx[ml*132 + n] = nx;
      }
    }
  }
  __syncthreads();
  {
    int row = tid >> 2, q = tid & 3;
    const float* pr = sx + row*132 + q*32;
    float ss = 0.f;
    #pragma unroll
    for (int i=0;i<32;i+=4){
      float4 v = *(const float4*)(pr + i);
      ss += v.x*v.x + v.y*v.y + v.z*v.z + v.w*v.w;
    }
    ss += __shfl_xor(ss, 1);
    ss += __shfl_xor(ss, 2);
    if (q == 0) rs[m0 + row] = rsqrtf(ss*(1.f/128.f) + 1e-5f);
  }
}

// ---------------- masked mean pool over a chunk ----------------
__global__ __launch_bounds__(256) void k_pool1(const float* __restrict__ x,
    const float* __restrict__ mask, float* __restrict__ part, float* __restrict__ pmask){
  int b = blockIdx.y, seg = blockIdx.x;
  int d = threadIdx.x & 127, half = threadIdx.x >> 7;
  int t0 = seg*128 + half*64;
  float acc = 0.f, macc = 0.f;
  for (int i=0;i<64;i++){
    int t = t0 + i;
    float mv = mask[(size_t)b*SL + t];
    acc = fmaf(x[((size_t)b*SL + t)*DMODEL + d], mv, acc);
    macc += mv;
  }
  __shared__ float sm[256];
  __shared__ float smm[2];
  sm[threadIdx.x] = acc;
  if (d == 0) smm[half] = macc;
  __syncthreads();
  if (half == 0){
    part[((size_t)b*16 + seg)*128 + d] = sm[d] + sm[128+d];
    if (d == 0) pmask[b*16 + seg] = smm[0] + smm[1];
  }
}

__global__ void k_pool2(const float* __restrict__ part, const float* __restrict__ pmask,
                        float* __restrict__ pooled){
  int b = blockIdx.x, d = threadIdx.x;
  float acc = 0.f, ms = 0.f;
  for (int s=0;s<16;s++){ acc += part[((size_t)b*16+s)*128 + d]; ms += pmask[b*16+s]; }
  pooled[(size_t)b*128 + d] = acc / fmaxf(ms, 1e-9f);
}

// ---------------- tiny MLP ----------------
__global__ void k_mlp_a(const float* __restrict__ in, const float* __restrict__ w,
                        const float* __restrict__ bias, float* __restrict__ out, int K){
  int b = blockIdx.y;
  int n = blockIdx.x*128 + threadIdx.x;
  const float4* pw = (const float4*)(w + (size_t)n*K);
  const float4* pi = (const float4*)(in + (size_t)b*K);
  float acc = 0.f;
  for (int k=0;k<K/4;k++){
    float4 a = pi[k], ww = pw[k];
    acc = fmaf(a.x,ww.x, fmaf(a.y,ww.y, fmaf(a.z,ww.z, fmaf(a.w,ww.w, acc))));
  }
  out[(size_t)b*512 + n] = fmaxf(acc + bias[n], 0.f);
}

__global__ void k_mlp3(const float* __restrict__ h, const float* __restrict__ w,
                       const float* __restrict__ bias, float* __restrict__ out){
  int b = blockIdx.x;
  int n = threadIdx.x >> 6, lane = threadIdx.x & 63;
  if (n >= 3) return;
  float acc = 0.f;
  for (int k=lane; k<512; k+=64) acc = fmaf(h[(size_t)b*512+k], w[(size_t)n*512+k], acc);
  #pragma unroll
  for (int m=1;m<64;m<<=1) acc += __shfl_xor(acc, m);
  if (lane == 0) out[(size_t)b*3 + n] = acc + bias[n];
}

// ---------------- launch ----------------
extern "C" void kernel_launch(void* const* d_in, const int* in_sizes, int n_in,
                              void* d_out, int out_size, void* d_ws, size_t ws_size,
                              hipStream_t stream){
  const int*   tokens = (const int*)  d_in[0];
  const float* mask   = (const float*)d_in[1];
  const float* emb    = (const float*)d_in[2];
  const float* bn_w   = (const float*)d_in[3];
  const float* bn_b   = (const float*)d_in[4];
  const float* conv_w = (const float*)d_in[5];
  const float* conv_b = (const float*)d_in[6];
  const float* in_w   = (const float*)d_in[7];
  const float* c1_w   = (const float*)d_in[8];
  const float* c1_b   = (const float*)d_in[9];
  const float* xp_w   = (const float*)d_in[10];
  const float* dtp_w  = (const float*)d_in[11];
  const float* dtp_b  = (const float*)d_in[12];
  const float* A_log  = (const float*)d_in[13];
  const float* D_par  = (const float*)d_in[14];
  const float* out_w  = (const float*)d_in[15];
  const float* nrm_w  = (const float*)d_in[16];
  const float* l1w = (const float*)d_in[17]; const float* l1b = (const float*)d_in[18];
  const float* l2w = (const float*)d_in[19]; const float* l2b = (const float*)d_in[20];
  const float* l3w = (const float*)d_in[21]; const float* l3b = (const float*)d_in[22];
  float* dout = (float*)d_out;

  // per-token floats: x 128 + rs 1 + xi(bf16) 128 + dub(uint) 256 + vbc 32 + cseg 64
  //                   + sdt 4 + gz(bf16) 128 = 741
  int CB = 64;
  while (CB > 1 && ((size_t)CB*SL*741 + FIX_END)*4 > ws_size) CB >>= 1;
  if (((size_t)CB*SL*741 + FIX_END)*4 > ws_size) return;
  const size_t CTOK = (size_t)CB*SL;

  float* ws  = (float*)d_ws;
  float* pl  = ws + FIX_PL;
  float* pm  = ws + FIX_PM;
  float* pd  = ws + FIX_PD;
  float* h1  = ws + FIX_H1;
  float* h2  = ws + FIX_H2;
  __bf16* wpb   = (__bf16*)(ws + FIX_WP);
  __bf16* w2b   = (__bf16*)(ws + FIX_W2B);
  __bf16* winb  = (__bf16*)(ws + FIX_WINB);
  __bf16* woutb = (__bf16*)(ws + FIX_WOUTB);
  float* xcb = ws + FIX_END;                 // CTOK*128 fp32 residual x
  float* rs  = xcb + CTOK*128;               // CTOK
  __bf16* xib = (__bf16*)(rs + CTOK);        // CTOK*256 bf16 (x-branch)
  unsigned int* dub = (unsigned int*)(xib + CTOK*256);   // CTOK*256 uint (packed dt,u)
  float* pad = (float*)xib;                  // fp32 embed-pad scratch (aliases xib+dub)
  float* vbc = (float*)(dub + CTOK*256);     // CTOK*32 fp32 (interleaved BC)
  float* csg = vbc + CTOK*32;                // CTOK*64
  float* sdt = csg + CTOK*64;                // CTOK*4
  __bf16* zb  = (__bf16*)(sdt + CTOK*4);     // CTOK*256 bf16 (gz)

  k_w2b<<<192, 256, 0, stream>>>(conv_w, w2b);
  k_cvt<<<1024, 256, 0, stream>>>(in_w,  winb,  4*512*128);
  k_cvt<<<512,  256, 0, stream>>>(out_w, woutb, 4*128*256);
  k_wprep<<<256, 256, 0, stream>>>(xp_w, wpb);

  const int nchunks = NB / CB;
  for (int c = 0; c < nchunks; c++){
    const int* tok_c = tokens + (size_t)c*CTOK;

    k_embed<<<CB*2050, 128, 0, stream>>>(tok_c, emb, bn_w, bn_b, pad);
    k_mgemm<0,384,128><<<dim3(1, CTOK/128), 256, 0, stream>>>(
        pad, w2b, conv_b, nullptr, nullptr, xcb, nullptr, nullptr);
    k_rmsscale<<<CTOK/4, 256, 0, stream>>>(xcb, rs);

    for (int layer = 0; layer < NLAYER; layer++){
      const __bf16* lin = winb  + (size_t)layer*512*128;
      const float* lcw  = c1_w  + (size_t)layer*DIN*4;
      const float* lcb  = c1_b  + (size_t)layer*DIN;
      const float* ldw  = dtp_w + (size_t)layer*DIN*8;
      const float* ldb  = dtp_b + (size_t)layer*DIN;
      const float* lal  = A_log + (size_t)layer*DIN*DST;
      const float* lD   = D_par + (size_t)layer*DIN;
      const __bf16* low = woutb + (size_t)layer*128*256;
      const float* lnw  = nrm_w + (size_t)layer*128;

      k_mgemm<1,128,512><<<dim3(4, CTOK/128), 256, 0, stream>>>(
          xcb, lin, nullptr, rs, lnw, nullptr, xib, zb);
      k_seg<<<(int)(CTOK/64), 256, 0, stream>>>(
          xib, wpb + (size_t)layer*64*256, lcw, lcb, ldw, ldb, lal, vbc, dub, csg, sdt);
      k_scanB<<<CB*16, 256, 0, stream>>>(csg, sdt, lal);
      k_scanC3<<<(int)(CTOK/64), 256, 0, stream>>>(
          xcb, dub, vbc, zb, lal, lD, csg, low, rs);
    }

    k_pool1<<<dim3(16, CB), 256, 0, stream>>>(
        xcb, mask + (size_t)c*CTOK, pl + (size_t)c*CB*16*128, pm + (size_t)c*CB*16);
  }

  k_pool2<<<NB, 128, 0, stream>>>(pl, pm, pd);
  k_mlp_a<<<dim3(4, NB), 128, 0, stream>>>(pd, l1w, l1b, h1, 128);
  k_mlp_a<<<dim3(4, NB), 128, 0, stream>>>(h1, l2w, l2b, h2, 512);
  k_mlp3<<<NB, 256, 0, stream>>>(h2, l3w, l3b, dout);
}